// Round 1
// 2047.978 us; speedup vs baseline: 1.1603x; 1.1603x over previous
//
#include <hip/hip_runtime.h>
#include <math.h>

// Problem constants: B=1, T=2048, D=1024, H=16, HD=64, STRIDE=8, Tg=256.
// Output 0: weighted [2048][1024]
// Output 1: combined [3][2048][2048] = (s0+s1+s3) * {linear_w, sparse_w, quantum_w}
#define D_MODEL 1024

typedef __attribute__((ext_vector_type(8))) short bf16x8;
typedef __attribute__((ext_vector_type(4))) float f32x4;
typedef __attribute__((ext_vector_type(8))) unsigned short u16x8;

// fp32 -> bf16 RNE, and bf16 -> fp32
__device__ __forceinline__ unsigned short bfr(float f) {
    unsigned u = __float_as_uint(f);
    u += 0x7fffu + ((u >> 16) & 1u);
    return (unsigned short)(u >> 16);
}
__device__ __forceinline__ float bff(unsigned short s) {
    return __uint_as_float(((unsigned)s) << 16);
}
// split x = hi + lo (both bf16); hi*hi+hi*lo+lo*hi captures x*y to ~2^-17 rel
__device__ __forceinline__ void split2(float x, unsigned short &h, unsigned short &l) {
    h = bfr(x);
    l = bfr(x - bff(h));
}
__device__ __forceinline__ f32x4 mfma3(bf16x8 ah, bf16x8 al, bf16x8 bh, bf16x8 bl, f32x4 c) {
    c = __builtin_amdgcn_mfma_f32_16x16x32_bf16(ah, bh, c, 0, 0, 0);
    c = __builtin_amdgcn_mfma_f32_16x16x32_bf16(ah, bl, c, 0, 0, 0);
    c = __builtin_amdgcn_mfma_f32_16x16x32_bf16(al, bh, c, 0, 0, 0);
    return c;
}

// ---------------------------------------------------------------------------
// MFMA GEMM: C[M,N] (+)= scale * (X[M,K] @ W[N,K]^T + bias), split-bf16.
// 64x64 tile, 4 waves (wave = 16-row m-block x 64 cols), K-step 32.
// ---------------------------------------------------------------------------
__global__ __launch_bounds__(256) void gemm_mfma(
    const float* __restrict__ X, int xrstride,
    const float* __restrict__ W, int wrstride,
    const float* __restrict__ bias,
    float* __restrict__ C, int M, int N, int K,
    const float* __restrict__ sptr, int sidx, int accum)
{
    __shared__ unsigned short Xh[64][40], Xl[64][40];
    __shared__ unsigned short Wh[64][40], Wl[64][40];
    const int tid = threadIdx.x;
    const int m0 = blockIdx.x * 64, n0 = blockIdx.y * 64;
    const int lane = tid & 63, wave = tid >> 6;
    const int c = lane & 15, quad = lane >> 4;
    const int mbase = wave * 16;

    f32x4 acc[4];
#pragma unroll
    for (int nt = 0; nt < 4; ++nt) acc[nt] = (f32x4){0.f, 0.f, 0.f, 0.f};

    for (int k0 = 0; k0 < K; k0 += 32) {
        __syncthreads();
#pragma unroll
        for (int it = 0; it < 2; ++it) {
            int idx = tid + it * 256;           // 512 float4 for X
            int r = idx >> 3, d4 = (idx & 7) * 4;
            float4 v = *(const float4*)&X[(size_t)(m0 + r) * xrstride + k0 + d4];
            ushort4 hs, ls;
            split2(v.x, hs.x, ls.x); split2(v.y, hs.y, ls.y);
            split2(v.z, hs.z, ls.z); split2(v.w, hs.w, ls.w);
            *(ushort4*)&Xh[r][d4] = hs; *(ushort4*)&Xl[r][d4] = ls;
        }
#pragma unroll
        for (int it = 0; it < 2; ++it) {
            int idx = tid + it * 256;           // 512 float4 for W
            int r = idx >> 3, d4 = (idx & 7) * 4;
            float4 v = *(const float4*)&W[(size_t)(n0 + r) * wrstride + k0 + d4];
            ushort4 hs, ls;
            split2(v.x, hs.x, ls.x); split2(v.y, hs.y, ls.y);
            split2(v.z, hs.z, ls.z); split2(v.w, hs.w, ls.w);
            *(ushort4*)&Wh[r][d4] = hs; *(ushort4*)&Wl[r][d4] = ls;
        }
        __syncthreads();
        bf16x8 ah = *(const bf16x8*)&Xh[mbase + c][quad * 8];
        bf16x8 al = *(const bf16x8*)&Xl[mbase + c][quad * 8];
#pragma unroll
        for (int nt = 0; nt < 4; ++nt) {
            bf16x8 bh = *(const bf16x8*)&Wh[nt * 16 + c][quad * 8];
            bf16x8 bl = *(const bf16x8*)&Wl[nt * 16 + c][quad * 8];
            acc[nt] = mfma3(ah, al, bh, bl, acc[nt]);
        }
    }
    const float s = (sptr != nullptr) ? sptr[sidx] : 1.0f;
#pragma unroll
    for (int nt = 0; nt < 4; ++nt) {
#pragma unroll
        for (int reg = 0; reg < 4; ++reg) {
            int row = m0 + mbase + quad * 4 + reg;
            int col = n0 + nt * 16 + c;
            float v = acc[nt][reg] + (bias ? bias[col] : 0.0f);
            v *= s;
            size_t gi = (size_t)row * N + col;
            if (accum) v += C[gi];
            C[gi] = v;
        }
    }
}

// ---------------------------------------------------------------------------
// MFMA flash attention, one block = (head, 64 query rows), split-bf16.
//   O (+)= osc * softmax(ascale * Q K^T) V, single O write; m,l emitted.
//   Round-1 rework:
//   - Q fragments loaded directly from global (wave-private) -> no Q LDS.
//   - V^T staged via (d, s8) ownership: coalesced scalar global reads +
//     ds_write_b128 (was scalar u16 writes with 16..32-way bank conflicts).
//   - K/V global loads for tile t+1 issued into registers BEFORE compute(t)
//     (T14 load-early/write-late); only split2+LDS writes sit in the
//     barrier-protected window.
//   - HD=128: K/V double-buffered, ONE barrier per tile (LDS freed by Q).
//     HD=64: single buffer, 2 barriers, keeps 2 blocks/CU.
//   Masked heads (amode 1, gate 0): P==1, l=Tk, m=0 (exact uniform).
// ---------------------------------------------------------------------------
template <int HD>
__global__ __launch_bounds__(256) void flash_mfma(
    const float* __restrict__ Q, const float* __restrict__ K,
    const float* __restrict__ V,
    const float* __restrict__ aparam, int amode,
    float* __restrict__ O,
    const float* __restrict__ strat, int o_sidx, int accum,
    float* __restrict__ mout, float* __restrict__ lout,
    int Tq, int Tk, float inv_scale)
{
    constexpr int ROWS = 64;
    constexpr int STILE = (HD == 64) ? 64 : 32;
    constexpr int NT_S = STILE / 16;   // score n-tiles
    constexpr int KS   = HD / 32;      // QK k-steps
    constexpr int NT_O = HD / 16;      // O n-tiles
    constexpr int KS_PV = STILE / 32;  // PV k-steps
    constexpr int QP = HD + 8;         // padded K row length (u16), 16B-aligned
    constexpr int SP = STILE + 8;
    constexpr bool DBUF = (HD == 128);
    constexpr int NB = DBUF ? 2 : 1;
    constexpr int KITEMS = STILE * HD / 4 / 256;  // float4 per thread (K tile)
    constexpr int VITEMS = HD * STILE / 8 / 256;  // 8-elem cols per thread (V tile)

    __shared__ __align__(16) unsigned short Kh[NB][STILE][QP], Kl[NB][STILE][QP];
    __shared__ __align__(16) unsigned short Vh[NB][HD][SP],  Vl[NB][HD][SP];
    __shared__ __align__(16) unsigned short Ph[ROWS][SP],    Pl[ROWS][SP];

    const int tid = threadIdx.x;
    const int h = blockIdx.y;
    const int r0 = blockIdx.x * ROWS;
    const int lane = tid & 63, wave = tid >> 6;
    const int c = lane & 15, quad = lane >> 4;
    const int mbase = wave * 16;

    float gate = 1.0f;
    if (amode == 1) gate = (aparam[h] > 0.0f) ? 1.0f : 0.0f;
    if (amode == 2) gate = 1.0f / (1.0f + __expf(-aparam[h * 4]));
    const float ascale = gate * inv_scale;
    const bool masked = (amode == 1) && (gate == 0.0f);

    if (masked) {  // uniform P == 1.0 (visible after first barrier)
        for (int idx = tid; idx < ROWS * STILE; idx += 256) {
            int r = idx / STILE, cc = idx % STILE;
            Ph[r][cc] = 0x3F80; Pl[r][cc] = 0;
        }
    }

    // Q A-fragments straight from global (key-loop invariant, wave-private)
    bf16x8 qah[KS], qal[KS];
    if (!masked) {
        const float* qrow = &Q[(size_t)(r0 + mbase + c) * D_MODEL + h * HD];
#pragma unroll
        for (int ks = 0; ks < KS; ++ks) {
            float4 a  = *(const float4*)(qrow + ks * 32 + quad * 8);
            float4 b2 = *(const float4*)(qrow + ks * 32 + quad * 8 + 4);
            unsigned short hh, ll;
            split2(a.x, hh, ll);  qah[ks][0] = (short)hh; qal[ks][0] = (short)ll;
            split2(a.y, hh, ll);  qah[ks][1] = (short)hh; qal[ks][1] = (short)ll;
            split2(a.z, hh, ll);  qah[ks][2] = (short)hh; qal[ks][2] = (short)ll;
            split2(a.w, hh, ll);  qah[ks][3] = (short)hh; qal[ks][3] = (short)ll;
            split2(b2.x, hh, ll); qah[ks][4] = (short)hh; qal[ks][4] = (short)ll;
            split2(b2.y, hh, ll); qah[ks][5] = (short)hh; qal[ks][5] = (short)ll;
            split2(b2.z, hh, ll); qah[ks][6] = (short)hh; qal[ks][6] = (short)ll;
            split2(b2.w, hh, ll); qah[ks][7] = (short)hh; qal[ks][7] = (short)ll;
        }
    }

    float mreg[4], lreg[4];
#pragma unroll
    for (int i = 0; i < 4; ++i) { mreg[i] = -1e30f; lreg[i] = 0.0f; }
    f32x4 oacc[NT_O];
#pragma unroll
    for (int nt = 0; nt < NT_O; ++nt) oacc[nt] = (f32x4){0.f, 0.f, 0.f, 0.f};

    float4 kreg[KITEMS];
    float  vreg[VITEMS][8];

    // issue global loads for tile at key offset s0 into registers
    auto load_regs = [&](int s0) {
        if (!masked) {
#pragma unroll
            for (int it = 0; it < KITEMS; ++it) {
                int idx = tid + it * 256;
                int r = idx / (HD / 4), d4 = (idx % (HD / 4)) * 4;
                kreg[it] = *(const float4*)&K[(size_t)(s0 + r) * D_MODEL + h * HD + d4];
            }
        }
#pragma unroll
        for (int it = 0; it < VITEMS; ++it) {
            int idx = tid + it * 256;
            int d = idx % HD, s8 = (idx / HD) * 8;   // consecutive lanes -> consecutive d
#pragma unroll
            for (int j = 0; j < 8; ++j)
                vreg[it][j] = V[(size_t)(s0 + s8 + j) * D_MODEL + h * HD + d];
        }
    };
    // split and write staged registers into LDS buffer b
    auto write_bufs = [&](int b) {
        if (!masked) {
#pragma unroll
            for (int it = 0; it < KITEMS; ++it) {
                int idx = tid + it * 256;
                int r = idx / (HD / 4), d4 = (idx % (HD / 4)) * 4;
                ushort4 hs, ls;
                split2(kreg[it].x, hs.x, ls.x); split2(kreg[it].y, hs.y, ls.y);
                split2(kreg[it].z, hs.z, ls.z); split2(kreg[it].w, hs.w, ls.w);
                *(ushort4*)&Kh[b][r][d4] = hs; *(ushort4*)&Kl[b][r][d4] = ls;
            }
        }
#pragma unroll
        for (int it = 0; it < VITEMS; ++it) {
            int idx = tid + it * 256;
            int d = idx % HD, s8 = (idx / HD) * 8;
            u16x8 hs, ls;
#pragma unroll
            for (int j = 0; j < 8; ++j) {
                unsigned short hh, ll;
                split2(vreg[it][j], hh, ll);
                hs[j] = hh; ls[j] = ll;
            }
            *(u16x8*)&Vh[b][d][s8] = hs;     // one ds_write_b128 per array
            *(u16x8*)&Vl[b][d][s8] = ls;
        }
    };

    auto compute_tile = [&](int b) {
        float alpha[4] = {1.0f, 1.0f, 1.0f, 1.0f};
        if (!masked) {
            // scores for this wave's 16-row m-block, all STILE keys
            f32x4 sf[NT_S];
#pragma unroll
            for (int nt = 0; nt < NT_S; ++nt) {
                f32x4 s = (f32x4){0.f, 0.f, 0.f, 0.f};
#pragma unroll
                for (int ks = 0; ks < KS; ++ks) {
                    bf16x8 bh = *(const bf16x8*)&Kh[b][nt * 16 + c][ks * 32 + quad * 8];
                    bf16x8 bl = *(const bf16x8*)&Kl[b][nt * 16 + c][ks * 32 + quad * 8];
                    s = mfma3(qah[ks], qal[ks], bh, bl, s);
                }
                sf[nt] = s * ascale;
            }
            // row max (rows quad*4+reg; cols spread over 16 lanes of the quad)
            float tm[4] = {-1e30f, -1e30f, -1e30f, -1e30f};
#pragma unroll
            for (int nt = 0; nt < NT_S; ++nt)
#pragma unroll
                for (int reg = 0; reg < 4; ++reg) tm[reg] = fmaxf(tm[reg], sf[nt][reg]);
#pragma unroll
            for (int off = 1; off < 16; off <<= 1)
#pragma unroll
                for (int reg = 0; reg < 4; ++reg) tm[reg] = fmaxf(tm[reg], __shfl_xor(tm[reg], off));
            float ps[4] = {0.f, 0.f, 0.f, 0.f};
#pragma unroll
            for (int reg = 0; reg < 4; ++reg) {
                float nm = fmaxf(mreg[reg], tm[reg]);
                alpha[reg] = __expf(mreg[reg] - nm);
                mreg[reg] = nm;
            }
            // p = exp(s - m), store to LDS (hi/lo) for PV A-operand
#pragma unroll
            for (int nt = 0; nt < NT_S; ++nt) {
#pragma unroll
                for (int reg = 0; reg < 4; ++reg) {
                    float p = __expf(sf[nt][reg] - mreg[reg]);
                    ps[reg] += p;
                    unsigned short hh, ll;
                    split2(p, hh, ll);
                    int row = mbase + quad * 4 + reg;
                    Ph[row][nt * 16 + c] = hh;
                    Pl[row][nt * 16 + c] = ll;
                }
            }
#pragma unroll
            for (int off = 1; off < 16; off <<= 1)
#pragma unroll
                for (int reg = 0; reg < 4; ++reg) ps[reg] += __shfl_xor(ps[reg], off);
#pragma unroll
            for (int reg = 0; reg < 4; ++reg) lreg[reg] = lreg[reg] * alpha[reg] + ps[reg];
        }
        // PV: P rows of this m-block were written by this same wave (in-order
        // LDS within a wave); V staged before the protecting barrier.
        bf16x8 pah[KS_PV], pal[KS_PV];
#pragma unroll
        for (int ks = 0; ks < KS_PV; ++ks) {
            pah[ks] = *(const bf16x8*)&Ph[mbase + c][ks * 32 + quad * 8];
            pal[ks] = *(const bf16x8*)&Pl[mbase + c][ks * 32 + quad * 8];
        }
#pragma unroll
        for (int nt = 0; nt < NT_O; ++nt) {
            f32x4 o = oacc[nt];
#pragma unroll
            for (int reg = 0; reg < 4; ++reg) o[reg] *= alpha[reg];
#pragma unroll
            for (int ks = 0; ks < KS_PV; ++ks) {
                bf16x8 bh = *(const bf16x8*)&Vh[b][nt * 16 + c][ks * 32 + quad * 8];
                bf16x8 bl = *(const bf16x8*)&Vl[b][nt * 16 + c][ks * 32 + quad * 8];
                o = mfma3(pah[ks], pal[ks], bh, bl, o);
            }
            oacc[nt] = o;
        }
    };

    const int NTL = Tk / STILE;
    if constexpr (DBUF) {
        // double-buffered K/V, ONE barrier per tile
        load_regs(0);
        write_bufs(0);
        __syncthreads();
        for (int t = 0; t < NTL; ++t) {
            const int cur = t & 1;
            if (t + 1 < NTL) load_regs((t + 1) * STILE);   // VMEM in flight
            compute_tile(cur);
            if (t + 1 < NTL) write_bufs(cur ^ 1);          // regs ready by now
            __syncthreads();
        }
    } else {
        // single buffer, 2 barriers; loads for t+1 overlap compute(t)
        load_regs(0);
        for (int t = 0; t < NTL; ++t) {
            __syncthreads();                 // prev tile consumed by all waves
            write_bufs(0);
            __syncthreads();
            if (t + 1 < NTL) load_regs((t + 1) * STILE);
            compute_tile(0);
        }
    }

    // epilogue
    const float osc = (o_sidx >= 0) ? strat[o_sidx] : 1.0f;
#pragma unroll
    for (int reg = 0; reg < 4; ++reg) {
        float lf = masked ? (float)Tk : lreg[reg];
        int row = r0 + mbase + quad * 4 + reg;
        if (c == 0) {
            mout[h * Tq + row] = masked ? 0.0f : mreg[reg];
            lout[h * Tq + row] = lf;
        }
        float sc = osc / lf;
#pragma unroll
        for (int nt = 0; nt < NT_O; ++nt) {
            size_t gi = (size_t)row * D_MODEL + h * HD + nt * 16 + c;
            float v = sc * oacc[nt][reg];
            if (accum) v += O[gi];
            O[gi] = v;
        }
    }
}

// ---------------------------------------------------------------------------
// MFMA comb plane: comb[r][c] = csc * (sum_h exp(ascale_h*q_h.k_h - m)/l + unif/Tk)
// Block = 64 rows x 128 cols, loops 16 heads (HD=64). One store per element.
// ---------------------------------------------------------------------------
__global__ __launch_bounds__(256) void comb_mfma(
    const float* __restrict__ Q, const float* __restrict__ K,
    const float* __restrict__ mrow, const float* __restrict__ lrow,
    const float* __restrict__ aparam, int amode,
    const float* __restrict__ strat,
    float* __restrict__ comb, int Tq, int Tk, int nh, float inv_scale)
{
    __shared__ unsigned short Qh[64][72], Ql[64][72];
    __shared__ unsigned short Kh[128][72], Kl[128][72];
    const int tid = threadIdx.x;
    const int r0 = blockIdx.x * 64, c0 = blockIdx.y * 128;
    const int lane = tid & 63, wave = tid >> 6;
    const int c = lane & 15, quad = lane >> 4;
    const int mbase = wave * 16;

    f32x4 acc[8];
#pragma unroll
    for (int nt = 0; nt < 8; ++nt) acc[nt] = (f32x4){0.f, 0.f, 0.f, 0.f};
    float unif = 0.0f;

    for (int h = 0; h < nh; ++h) {
        float gate = 1.0f;
        if (amode == 1) gate = (aparam[h] > 0.0f) ? 1.0f : 0.0f;
        if (amode == 2) gate = 1.0f / (1.0f + __expf(-aparam[h * 4]));
        if (amode == 1 && gate == 0.0f) { unif += 1.0f; continue; }  // block-uniform
        const float ascale = gate * inv_scale;

        __syncthreads();   // previous head's tiles fully consumed
        for (int idx = tid; idx < 64 * 16; idx += 256) {        // Q 64x64
            int r = idx >> 4, d4 = (idx & 15) * 4;
            float4 v = *(const float4*)&Q[(size_t)(r0 + r) * D_MODEL + h * 64 + d4];
            ushort4 hs, ls;
            split2(v.x, hs.x, ls.x); split2(v.y, hs.y, ls.y);
            split2(v.z, hs.z, ls.z); split2(v.w, hs.w, ls.w);
            *(ushort4*)&Qh[r][d4] = hs; *(ushort4*)&Ql[r][d4] = ls;
        }
        for (int idx = tid; idx < 128 * 16; idx += 256) {       // K 128x64
            int r = idx >> 4, d4 = (idx & 15) * 4;
            float4 v = *(const float4*)&K[(size_t)(c0 + r) * D_MODEL + h * 64 + d4];
            ushort4 hs, ls;
            split2(v.x, hs.x, ls.x); split2(v.y, hs.y, ls.y);
            split2(v.z, hs.z, ls.z); split2(v.w, hs.w, ls.w);
            *(ushort4*)&Kh[r][d4] = hs; *(ushort4*)&Kl[r][d4] = ls;
        }
        __syncthreads();

        float mr[4], li[4];
#pragma unroll
        for (int reg = 0; reg < 4; ++reg) {
            int row = r0 + mbase + quad * 4 + reg;
            mr[reg] = mrow[h * Tq + row];
            li[reg] = 1.0f / lrow[h * Tq + row];
        }
        bf16x8 qah[2], qal[2];
#pragma unroll
        for (int ks = 0; ks < 2; ++ks) {
            qah[ks] = *(const bf16x8*)&Qh[mbase + c][ks * 32 + quad * 8];
            qal[ks] = *(const bf16x8*)&Ql[mbase + c][ks * 32 + quad * 8];
        }
#pragma unroll
        for (int nt = 0; nt < 8; ++nt) {
            f32x4 s = (f32x4){0.f, 0.f, 0.f, 0.f};
#pragma unroll
            for (int ks = 0; ks < 2; ++ks) {
                bf16x8 bh = *(const bf16x8*)&Kh[nt * 16 + c][ks * 32 + quad * 8];
                bf16x8 bl = *(const bf16x8*)&Kl[nt * 16 + c][ks * 32 + quad * 8];
                s = mfma3(qah[ks], qal[ks], bh, bl, s);
            }
#pragma unroll
            for (int reg = 0; reg < 4; ++reg)
                acc[nt][reg] += __expf(s[reg] * ascale - mr[reg]) * li[reg];
        }
    }
    const float csc = (strat[0] + strat[1] + strat[3]) / (float)nh;
    const float uadd = unif / (float)Tk;
#pragma unroll
    for (int nt = 0; nt < 8; ++nt) {
#pragma unroll
        for (int reg = 0; reg < 4; ++reg) {
            int row = r0 + mbase + quad * 4 + reg;
            comb[(size_t)row * Tk + c0 + nt * 16 + c] = csc * (acc[nt][reg] + uadd);
        }
    }
}

// ---------------------------------------------------------------------------
// Per-head 64x64 rotation (fp32, small): Y[t][h*64+e] = sum_d X[t][h*64+d]*R[h][d][e]
// ---------------------------------------------------------------------------
__global__ __launch_bounds__(256) void rotate_heads(
    const float* __restrict__ X, const float* __restrict__ R,
    float* __restrict__ Y)
{
    __shared__ float Rt[64][68];
    __shared__ float xs[64][68];
    const int tid = threadIdx.x;
    const int h = blockIdx.y;
    const int t0 = blockIdx.x * 64;
    for (int idx = tid; idx < 4096; idx += 256) {
        int d = idx >> 6, e = idx & 63;
        Rt[e][d] = R[h * 4096 + idx];
        xs[d][e] = X[(size_t)(t0 + d) * D_MODEL + h * 64 + e];
    }
    __syncthreads();
    const int ty = tid >> 4, tx = tid & 15;
    float acc[4][4] = {};
#pragma unroll 4
    for (int d0 = 0; d0 < 64; d0 += 4) {
        float4 rv[4];
#pragma unroll
        for (int j = 0; j < 4; ++j) rv[j] = *(const float4*)&Rt[tx * 4 + j][d0];
#pragma unroll
        for (int i = 0; i < 4; ++i) {
            float4 a = *(const float4*)&xs[ty * 4 + i][d0];
#pragma unroll
            for (int j = 0; j < 4; ++j)
                acc[i][j] += a.x * rv[j].x + a.y * rv[j].y + a.z * rv[j].z + a.w * rv[j].w;
        }
    }
#pragma unroll
    for (int i = 0; i < 4; ++i)
#pragma unroll
        for (int j = 0; j < 4; ++j)
            Y[(size_t)(t0 + ty * 4 + i) * D_MODEL + h * 64 + tx * 4 + j] = acc[i][j];
}

// ---------------------------------------------------------------------------
// F.interpolate(mode='linear', align_corners=False): [256,1024] -> [2048,1024]
// ---------------------------------------------------------------------------
__global__ __launch_bounds__(256) void interp_lin(
    const float* __restrict__ G, float* __restrict__ out)
{
    const int t = blockIdx.x;
    float src = (t + 0.5f) * 0.125f - 0.5f;
    src = fminf(fmaxf(src, 0.0f), 255.0f);
    float fl = floorf(src);
    int i0 = (int)fl;
    int i1 = min(i0 + 1, 255);
    float w = src - fl;
    const float4* g0 = (const float4*)(G + (size_t)i0 * D_MODEL);
    const float4* g1 = (const float4*)(G + (size_t)i1 * D_MODEL);
    float4* o = (float4*)(out + (size_t)t * D_MODEL);
    int c = threadIdx.x;
    float4 a = g0[c], b = g1[c];
    float4 r;
    r.x = a.x * (1.0f - w) + b.x * w;
    r.y = a.y * (1.0f - w) + b.y * w;
    r.z = a.z * (1.0f - w) + b.z * w;
    r.w = a.w * (1.0f - w) + b.w * w;
    o[c] = r;
}

// ---------------------------------------------------------------------------
extern "C" void kernel_launch(void* const* d_in, const int* in_sizes, int n_in,
                              void* d_out, int out_size, void* d_ws, size_t ws_size,
                              hipStream_t stream)
{
    (void)in_sizes; (void)n_in; (void)ws_size; (void)out_size;
    const float* query    = (const float*)d_in[0];
    const float* key      = (const float*)d_in[1];
    const float* value    = (const float*)d_in[2];
    const float* strat    = (const float*)d_in[3];
    const float* Wqkv_lin = (const float*)d_in[4];
    const float* b_lin    = (const float*)d_in[5];
    const float* Wo_lin   = (const float*)d_in[6];
    const float* bo_lin   = (const float*)d_in[7];
    const float* spars    = (const float*)d_in[8];
    const float* Wqkv_loc = (const float*)d_in[9];
    const float* b_loc    = (const float*)d_in[10];
    const float* Wo_loc   = (const float*)d_in[11];
    const float* bo_loc   = (const float*)d_in[12];
    const float* Wqkv_glb = (const float*)d_in[13];
    const float* b_glb    = (const float*)d_in[14];
    const float* Wo_glb   = (const float*)d_in[15];
    const float* bo_glb   = (const float*)d_in[16];
    const float* Wf       = (const float*)d_in[17];
    const float* bf       = (const float*)d_in[18];
    const float* Rq       = (const float*)d_in[19];
    const float* ent      = (const float*)d_in[20];

    float* out = (float*)d_out;
    float* weighted = out;                        // [2048][1024]
    float* combined = out + (size_t)2048 * 1024;  // [3][2048][2048]
    const size_t PLANE = (size_t)2048 * 2048;

    float* ws   = (float*)d_ws;
    float* qkv  = ws;                   // 3 x 2048x1024
    float* AO   = qkv + 6291456;
    float* LO   = AO + 2097152;
    float* gqkv = LO + 2097152;
    float* gAO  = gqkv + 786432;
    float* gOUT = gAO + 262144;
    float* GI   = gOUT + 262144;
    float* mb   = GI + 2097152;
    float* lb   = mb + 32768;
    float* qrot = qkv;                  // alias: lin qkv dead by then
    float* krot = qkv + 2097152;

    const float inv8   = 0.125f;
    const float inv128 = 1.0f / sqrtf(128.0f);
    const float* srcs[3] = {query, key, value};

    hipMemsetAsync(weighted, 0, (size_t)2097152 * sizeof(float), stream);

    // ---- LINEAR (proj'd MHA, 16 heads; combined plane 0) ----
    for (int sl = 0; sl < 3; ++sl)
        gemm_mfma<<<dim3(32, 16), 256, 0, stream>>>(
            srcs[sl], 1024, Wqkv_lin + (size_t)sl * 1048576, 1024, b_lin + sl * 1024,
            qkv + (size_t)sl * 2097152, 2048, 1024, 1024, nullptr, 0, 0);
    flash_mfma<64><<<dim3(32, 16), 256, 0, stream>>>(
        qkv, qkv + 2097152, qkv + 4194304, nullptr, 0,
        AO, strat, -1, 0, mb, lb, 2048, 2048, inv8);
    comb_mfma<<<dim3(32, 16), 256, 0, stream>>>(
        qkv, qkv + 2097152, mb, lb, nullptr, 0, strat,
        combined + 0 * PLANE, 2048, 2048, 16, inv8);
    gemm_mfma<<<dim3(32, 16), 256, 0, stream>>>(
        AO, 1024, Wo_lin, 1024, bo_lin, weighted, 2048, 1024, 1024, strat, 0, 1);

    // ---- SPARSE (raw heads, per-head mask; combined plane 1) ----
    flash_mfma<64><<<dim3(32, 16), 256, 0, stream>>>(
        query, key, value, spars, 1,
        weighted, strat, 1, 1, mb, lb, 2048, 2048, inv8);
    comb_mfma<<<dim3(32, 16), 256, 0, stream>>>(
        query, key, mb, lb, spars, 1, strat,
        combined + 1 * PLANE, 2048, 2048, 16, inv8);

    // ---- QUANTUM (rotated raw heads, per-head gate; combined plane 2) ----
    rotate_heads<<<dim3(32, 16), 256, 0, stream>>>(query, Rq, qrot);
    rotate_heads<<<dim3(32, 16), 256, 0, stream>>>(key, Rq, krot);
    flash_mfma<64><<<dim3(32, 16), 256, 0, stream>>>(
        qrot, krot, value, ent, 2,
        weighted, strat, 3, 1, mb, lb, 2048, 2048, inv8);
    comb_mfma<<<dim3(32, 16), 256, 0, stream>>>(
        qrot, krot, mb, lb, ent, 2, strat,
        combined + 2 * PLANE, 2048, 2048, 16, inv8);

    // ---- LOCAL (proj'd MHA, 8 heads x 128) ----
    for (int sl = 0; sl < 3; ++sl)
        gemm_mfma<<<dim3(32, 16), 256, 0, stream>>>(
            srcs[sl], 1024, Wqkv_loc + (size_t)sl * 1048576, 1024, b_loc + sl * 1024,
            qkv + (size_t)sl * 2097152, 2048, 1024, 1024, nullptr, 0, 0);
    flash_mfma<128><<<dim3(32, 8), 256, 0, stream>>>(
        qkv, qkv + 2097152, qkv + 4194304, nullptr, 0,
        AO, strat, -1, 0, mb, lb, 2048, 2048, inv128);
    gemm_mfma<<<dim3(32, 16), 256, 0, stream>>>(
        AO, 1024, Wo_loc, 1024, bo_loc, LO, 2048, 1024, 1024, nullptr, 0, 0);

    // ---- GLOBAL (strided pool to 256 tokens, 8 heads x 128, interp back) ----
    for (int sl = 0; sl < 3; ++sl)
        gemm_mfma<<<dim3(4, 16), 256, 0, stream>>>(
            srcs[sl], 8192, Wqkv_glb + (size_t)sl * 1048576, 1024, b_glb + sl * 1024,
            gqkv + (size_t)sl * 262144, 256, 1024, 1024, nullptr, 0, 0);
    flash_mfma<128><<<dim3(4, 8), 256, 0, stream>>>(
        gqkv, gqkv + 262144, gqkv + 524288, nullptr, 0,
        gAO, strat, -1, 0, mb, lb, 256, 256, inv128);
    gemm_mfma<<<dim3(4, 16), 256, 0, stream>>>(
        gAO, 1024, Wo_glb, 1024, bo_glb, gOUT, 256, 1024, 1024, nullptr, 0, 0);
    interp_lin<<<dim3(2048), 256, 0, stream>>>(gOUT, GI);

    // ---- HIER: weighted += s2 * (LO @ WfL^T + GI @ WfR^T + bf) ----
    gemm_mfma<<<dim3(32, 16), 256, 0, stream>>>(
        LO, 1024, Wf, 2048, bf, weighted, 2048, 1024, 1024, strat, 2, 1);
    gemm_mfma<<<dim3(32, 16), 256, 0, stream>>>(
        GI, 1024, Wf + 1024, 2048, nullptr, weighted, 2048, 1024, 1024, strat, 2, 1);
}

// Round 2
// 1836.484 us; speedup vs baseline: 1.2939x; 1.1152x over previous
//
#include <hip/hip_runtime.h>
#include <math.h>

// Problem constants: B=1, T=2048, D=1024, H=16, HD=64, STRIDE=8, Tg=256.
// Output 0: weighted [2048][1024]
// Output 1: combined [3][2048][2048] = (s0+s1+s3) * {linear_w, sparse_w, quantum_w}
#define D_MODEL 1024

typedef __attribute__((ext_vector_type(8))) short bf16x8;
typedef __attribute__((ext_vector_type(4))) float f32x4;
typedef __attribute__((ext_vector_type(8))) unsigned short u16x8;

// fp32 -> bf16 RNE, and bf16 -> fp32
__device__ __forceinline__ unsigned short bfr(float f) {
    unsigned u = __float_as_uint(f);
    u += 0x7fffu + ((u >> 16) & 1u);
    return (unsigned short)(u >> 16);
}
__device__ __forceinline__ float bff(unsigned short s) {
    return __uint_as_float(((unsigned)s) << 16);
}
// split x = hi + lo (both bf16); hi*hi+hi*lo+lo*hi captures x*y to ~2^-17 rel
__device__ __forceinline__ void split2(float x, unsigned short &h, unsigned short &l) {
    h = bfr(x);
    l = bfr(x - bff(h));
}
__device__ __forceinline__ f32x4 mfma3(bf16x8 ah, bf16x8 al, bf16x8 bh, bf16x8 bl, f32x4 c) {
    c = __builtin_amdgcn_mfma_f32_16x16x32_bf16(ah, bh, c, 0, 0, 0);
    c = __builtin_amdgcn_mfma_f32_16x16x32_bf16(ah, bl, c, 0, 0, 0);
    c = __builtin_amdgcn_mfma_f32_16x16x32_bf16(al, bh, c, 0, 0, 0);
    return c;
}

// ---------------------------------------------------------------------------
// Pre-split kernels: fp32 -> bf16 hi/lo (computed ONCE, reused by every
// flash/comb block+tile instead of per-tile split2 on the critical path).
// ---------------------------------------------------------------------------
// Row-major split: hi/lo same layout as input [*][D].
__global__ __launch_bounds__(256) void split_rm(
    const float* __restrict__ in, unsigned short* __restrict__ hi,
    unsigned short* __restrict__ lo, int n4)
{
    int idx = blockIdx.x * 256 + threadIdx.x;
    if (idx >= n4) return;
    float4 v = ((const float4*)in)[idx];
    ushort4 hs, ls;
    split2(v.x, hs.x, ls.x); split2(v.y, hs.y, ls.y);
    split2(v.z, hs.z, ls.z); split2(v.w, hs.w, ls.w);
    ((ushort4*)hi)[idx] = hs;
    ((ushort4*)lo)[idx] = ls;
}

// Transposed split: in [T][1024] fp32 -> hi/lo [1024][T] u16 (row = global d).
__global__ __launch_bounds__(256) void split_tr(
    const float* __restrict__ in, unsigned short* __restrict__ hi,
    unsigned short* __restrict__ lo, int T)
{
    __shared__ float xs[64][65];   // [t][d]
    const int t0 = blockIdx.x * 64, d0 = blockIdx.y * 64;
    for (int idx = threadIdx.x; idx < 64 * 16; idx += 256) {
        int r = idx >> 4, c4 = (idx & 15) * 4;
        float4 v = *(const float4*)&in[(size_t)(t0 + r) * D_MODEL + d0 + c4];
        xs[r][c4] = v.x; xs[r][c4 + 1] = v.y; xs[r][c4 + 2] = v.z; xs[r][c4 + 3] = v.w;
    }
    __syncthreads();
    for (int idx = threadIdx.x; idx < 64 * 8; idx += 256) {
        int dd = idx >> 3, t8 = (idx & 7) * 8;
        u16x8 hs, ls;
#pragma unroll
        for (int j = 0; j < 8; ++j) {
            unsigned short hh, ll;
            split2(xs[t8 + j][dd], hh, ll);
            hs[j] = hh; ls[j] = ll;
        }
        *(u16x8*)&hi[(size_t)(d0 + dd) * T + t0 + t8] = hs;
        *(u16x8*)&lo[(size_t)(d0 + dd) * T + t0 + t8] = ls;
    }
}

// ---------------------------------------------------------------------------
// MFMA GEMM: C[M,N] (+)= scale * (X[M,K] @ W[N,K]^T + bias), split-bf16.
// 64x64 tile, 4 waves (wave = 16-row m-block x 64 cols), K-step 32.
// ---------------------------------------------------------------------------
__global__ __launch_bounds__(256) void gemm_mfma(
    const float* __restrict__ X, int xrstride,
    const float* __restrict__ W, int wrstride,
    const float* __restrict__ bias,
    float* __restrict__ C, int M, int N, int K,
    const float* __restrict__ sptr, int sidx, int accum)
{
    __shared__ unsigned short Xh[64][40], Xl[64][40];
    __shared__ unsigned short Wh[64][40], Wl[64][40];
    const int tid = threadIdx.x;
    const int m0 = blockIdx.x * 64, n0 = blockIdx.y * 64;
    const int lane = tid & 63, wave = tid >> 6;
    const int c = lane & 15, quad = lane >> 4;
    const int mbase = wave * 16;

    f32x4 acc[4];
#pragma unroll
    for (int nt = 0; nt < 4; ++nt) acc[nt] = (f32x4){0.f, 0.f, 0.f, 0.f};

    for (int k0 = 0; k0 < K; k0 += 32) {
        __syncthreads();
#pragma unroll
        for (int it = 0; it < 2; ++it) {
            int idx = tid + it * 256;           // 512 float4 for X
            int r = idx >> 3, d4 = (idx & 7) * 4;
            float4 v = *(const float4*)&X[(size_t)(m0 + r) * xrstride + k0 + d4];
            ushort4 hs, ls;
            split2(v.x, hs.x, ls.x); split2(v.y, hs.y, ls.y);
            split2(v.z, hs.z, ls.z); split2(v.w, hs.w, ls.w);
            *(ushort4*)&Xh[r][d4] = hs; *(ushort4*)&Xl[r][d4] = ls;
        }
#pragma unroll
        for (int it = 0; it < 2; ++it) {
            int idx = tid + it * 256;           // 512 float4 for W
            int r = idx >> 3, d4 = (idx & 7) * 4;
            float4 v = *(const float4*)&W[(size_t)(n0 + r) * wrstride + k0 + d4];
            ushort4 hs, ls;
            split2(v.x, hs.x, ls.x); split2(v.y, hs.y, ls.y);
            split2(v.z, hs.z, ls.z); split2(v.w, hs.w, ls.w);
            *(ushort4*)&Wh[r][d4] = hs; *(ushort4*)&Wl[r][d4] = ls;
        }
        __syncthreads();
        bf16x8 ah = *(const bf16x8*)&Xh[mbase + c][quad * 8];
        bf16x8 al = *(const bf16x8*)&Xl[mbase + c][quad * 8];
#pragma unroll
        for (int nt = 0; nt < 4; ++nt) {
            bf16x8 bh = *(const bf16x8*)&Wh[nt * 16 + c][quad * 8];
            bf16x8 bl = *(const bf16x8*)&Wl[nt * 16 + c][quad * 8];
            acc[nt] = mfma3(ah, al, bh, bl, acc[nt]);
        }
    }
    const float s = (sptr != nullptr) ? sptr[sidx] : 1.0f;
#pragma unroll
    for (int nt = 0; nt < 4; ++nt) {
#pragma unroll
        for (int reg = 0; reg < 4; ++reg) {
            int row = m0 + mbase + quad * 4 + reg;
            int col = n0 + nt * 16 + c;
            float v = acc[nt][reg] + (bias ? bias[col] : 0.0f);
            v *= s;
            size_t gi = (size_t)row * N + col;
            if (accum) v += C[gi];
            C[gi] = v;
        }
    }
}

// ---------------------------------------------------------------------------
// MFMA flash attention, one block = (head, 64 query rows), split-bf16.
//   O (+)= osc * softmax(ascale * Q K^T) V, single O write; m,l emitted.
//   Round-2 rework:
//   - K and V come PRE-SPLIT from global: Khi/Klo row-major [T][1024],
//     Vthi/Vtlo transposed [1024][Tk] (row = h*HD+d). Staging is now pure
//     u16x8 load -> ds_write_b128 copy: no split2, no scalar V loads.
//   - Q still fp32 (loaded once per kernel into wave-private fragments).
//   - HD=128: K/V double-buffered, ONE barrier per tile.
//     HD=64: single buffer, 2 barriers (keeps 2 blocks/CU), loads for t+1
//     issued before compute(t).
//   Masked heads (amode 1, gate 0): P==1, l=Tk, m=0 (exact uniform).
// ---------------------------------------------------------------------------
template <int HD>
__global__ __launch_bounds__(256) void flash_mfma(
    const float* __restrict__ Q,
    const unsigned short* __restrict__ Khi, const unsigned short* __restrict__ Klo,
    const unsigned short* __restrict__ Vthi, const unsigned short* __restrict__ Vtlo,
    const float* __restrict__ aparam, int amode,
    float* __restrict__ O,
    const float* __restrict__ strat, int o_sidx, int accum,
    float* __restrict__ mout, float* __restrict__ lout,
    int Tq, int Tk, float inv_scale)
{
    constexpr int ROWS = 64;
    constexpr int STILE = (HD == 64) ? 64 : 32;
    constexpr int NT_S = STILE / 16;   // score n-tiles
    constexpr int KS   = HD / 32;      // QK k-steps
    constexpr int NT_O = HD / 16;      // O n-tiles
    constexpr int KS_PV = STILE / 32;  // PV k-steps
    constexpr int QP = HD + 8;         // padded K row length (u16), 16B-aligned
    constexpr int SP = STILE + 8;
    constexpr bool DBUF = (HD == 128);
    constexpr int NB = DBUF ? 2 : 1;
    constexpr int KIT = STILE * HD / 8 / 256;   // u16x8 items per thread (K)
    constexpr int VIT = STILE * HD / 8 / 256;   // u16x8 items per thread (V)

    __shared__ __align__(16) unsigned short Kh[NB][STILE][QP], Kl[NB][STILE][QP];
    __shared__ __align__(16) unsigned short Vh[NB][HD][SP],  Vl[NB][HD][SP];
    __shared__ __align__(16) unsigned short Ph[ROWS][SP],    Pl[ROWS][SP];

    const int tid = threadIdx.x;
    const int h = blockIdx.y;
    const int r0 = blockIdx.x * ROWS;
    const int lane = tid & 63, wave = tid >> 6;
    const int c = lane & 15, quad = lane >> 4;
    const int mbase = wave * 16;

    float gate = 1.0f;
    if (amode == 1) gate = (aparam[h] > 0.0f) ? 1.0f : 0.0f;
    if (amode == 2) gate = 1.0f / (1.0f + __expf(-aparam[h * 4]));
    const float ascale = gate * inv_scale;
    const bool masked = (amode == 1) && (gate == 0.0f);

    if (masked) {  // uniform P == 1.0 (visible after first barrier)
        for (int idx = tid; idx < ROWS * STILE; idx += 256) {
            int r = idx / STILE, cc = idx % STILE;
            Ph[r][cc] = 0x3F80; Pl[r][cc] = 0;
        }
    }

    // Q A-fragments straight from global (key-loop invariant, wave-private)
    bf16x8 qah[KS], qal[KS];
    if (!masked) {
        const float* qrow = &Q[(size_t)(r0 + mbase + c) * D_MODEL + h * HD];
#pragma unroll
        for (int ks = 0; ks < KS; ++ks) {
            float4 a  = *(const float4*)(qrow + ks * 32 + quad * 8);
            float4 b2 = *(const float4*)(qrow + ks * 32 + quad * 8 + 4);
            unsigned short hh, ll;
            split2(a.x, hh, ll);  qah[ks][0] = (short)hh; qal[ks][0] = (short)ll;
            split2(a.y, hh, ll);  qah[ks][1] = (short)hh; qal[ks][1] = (short)ll;
            split2(a.z, hh, ll);  qah[ks][2] = (short)hh; qal[ks][2] = (short)ll;
            split2(a.w, hh, ll);  qah[ks][3] = (short)hh; qal[ks][3] = (short)ll;
            split2(b2.x, hh, ll); qah[ks][4] = (short)hh; qal[ks][4] = (short)ll;
            split2(b2.y, hh, ll); qah[ks][5] = (short)hh; qal[ks][5] = (short)ll;
            split2(b2.z, hh, ll); qah[ks][6] = (short)hh; qal[ks][6] = (short)ll;
            split2(b2.w, hh, ll); qah[ks][7] = (short)hh; qal[ks][7] = (short)ll;
        }
    }

    float mreg[4], lreg[4];
#pragma unroll
    for (int i = 0; i < 4; ++i) { mreg[i] = -1e30f; lreg[i] = 0.0f; }
    f32x4 oacc[NT_O];
#pragma unroll
    for (int nt = 0; nt < NT_O; ++nt) oacc[nt] = (f32x4){0.f, 0.f, 0.f, 0.f};

    u16x8 krh[KIT], krl[KIT], vrh[VIT], vrl[VIT];

    // issue global loads for tile at key offset s0 into registers (pure copy)
    auto load_regs = [&](int s0) {
        if (!masked) {
#pragma unroll
            for (int it = 0; it < KIT; ++it) {
                int idx = tid + it * 256;
                int r = idx / (HD / 8), c8 = (idx % (HD / 8)) * 8;
                size_t go = (size_t)(s0 + r) * D_MODEL + h * HD + c8;
                krh[it] = *(const u16x8*)&Khi[go];
                krl[it] = *(const u16x8*)&Klo[go];
            }
        }
#pragma unroll
        for (int it = 0; it < VIT; ++it) {
            int idx = tid + it * 256;
            int d = idx % HD, s8 = (idx / HD) * 8;
            size_t go = (size_t)(h * HD + d) * Tk + s0 + s8;
            vrh[it] = *(const u16x8*)&Vthi[go];
            vrl[it] = *(const u16x8*)&Vtlo[go];
        }
    };
    // write staged registers into LDS buffer b (ds_write_b128 only)
    auto write_bufs = [&](int b) {
        if (!masked) {
#pragma unroll
            for (int it = 0; it < KIT; ++it) {
                int idx = tid + it * 256;
                int r = idx / (HD / 8), c8 = (idx % (HD / 8)) * 8;
                *(u16x8*)&Kh[b][r][c8] = krh[it];
                *(u16x8*)&Kl[b][r][c8] = krl[it];
            }
        }
#pragma unroll
        for (int it = 0; it < VIT; ++it) {
            int idx = tid + it * 256;
            int d = idx % HD, s8 = (idx / HD) * 8;
            *(u16x8*)&Vh[b][d][s8] = vrh[it];
            *(u16x8*)&Vl[b][d][s8] = vrl[it];
        }
    };

    auto compute_tile = [&](int b) {
        float alpha[4] = {1.0f, 1.0f, 1.0f, 1.0f};
        if (!masked) {
            // scores for this wave's 16-row m-block, all STILE keys
            f32x4 sf[NT_S];
#pragma unroll
            for (int nt = 0; nt < NT_S; ++nt) {
                f32x4 s = (f32x4){0.f, 0.f, 0.f, 0.f};
#pragma unroll
                for (int ks = 0; ks < KS; ++ks) {
                    bf16x8 bh = *(const bf16x8*)&Kh[b][nt * 16 + c][ks * 32 + quad * 8];
                    bf16x8 bl = *(const bf16x8*)&Kl[b][nt * 16 + c][ks * 32 + quad * 8];
                    s = mfma3(qah[ks], qal[ks], bh, bl, s);
                }
                sf[nt] = s * ascale;
            }
            // row max (rows quad*4+reg; cols spread over 16 lanes of the quad)
            float tm[4] = {-1e30f, -1e30f, -1e30f, -1e30f};
#pragma unroll
            for (int nt = 0; nt < NT_S; ++nt)
#pragma unroll
                for (int reg = 0; reg < 4; ++reg) tm[reg] = fmaxf(tm[reg], sf[nt][reg]);
#pragma unroll
            for (int off = 1; off < 16; off <<= 1)
#pragma unroll
                for (int reg = 0; reg < 4; ++reg) tm[reg] = fmaxf(tm[reg], __shfl_xor(tm[reg], off));
            float ps[4] = {0.f, 0.f, 0.f, 0.f};
#pragma unroll
            for (int reg = 0; reg < 4; ++reg) {
                float nm = fmaxf(mreg[reg], tm[reg]);
                alpha[reg] = __expf(mreg[reg] - nm);
                mreg[reg] = nm;
            }
            // p = exp(s - m), store to LDS (hi/lo) for PV A-operand
#pragma unroll
            for (int nt = 0; nt < NT_S; ++nt) {
#pragma unroll
                for (int reg = 0; reg < 4; ++reg) {
                    float p = __expf(sf[nt][reg] - mreg[reg]);
                    ps[reg] += p;
                    unsigned short hh, ll;
                    split2(p, hh, ll);
                    int row = mbase + quad * 4 + reg;
                    Ph[row][nt * 16 + c] = hh;
                    Pl[row][nt * 16 + c] = ll;
                }
            }
#pragma unroll
            for (int off = 1; off < 16; off <<= 1)
#pragma unroll
                for (int reg = 0; reg < 4; ++reg) ps[reg] += __shfl_xor(ps[reg], off);
#pragma unroll
            for (int reg = 0; reg < 4; ++reg) lreg[reg] = lreg[reg] * alpha[reg] + ps[reg];
        }
        // PV: P rows of this m-block were written by this same wave (in-order
        // LDS within a wave); V staged before the protecting barrier.
        bf16x8 pah[KS_PV], pal[KS_PV];
#pragma unroll
        for (int ks = 0; ks < KS_PV; ++ks) {
            pah[ks] = *(const bf16x8*)&Ph[mbase + c][ks * 32 + quad * 8];
            pal[ks] = *(const bf16x8*)&Pl[mbase + c][ks * 32 + quad * 8];
        }
#pragma unroll
        for (int nt = 0; nt < NT_O; ++nt) {
            f32x4 o = oacc[nt];
#pragma unroll
            for (int reg = 0; reg < 4; ++reg) o[reg] *= alpha[reg];
#pragma unroll
            for (int ks = 0; ks < KS_PV; ++ks) {
                bf16x8 bh = *(const bf16x8*)&Vh[b][nt * 16 + c][ks * 32 + quad * 8];
                bf16x8 bl = *(const bf16x8*)&Vl[b][nt * 16 + c][ks * 32 + quad * 8];
                o = mfma3(pah[ks], pal[ks], bh, bl, o);
            }
            oacc[nt] = o;
        }
    };

    const int NTL = Tk / STILE;
    if constexpr (DBUF) {
        // double-buffered K/V, ONE barrier per tile
        load_regs(0);
        write_bufs(0);
        __syncthreads();
        for (int t = 0; t < NTL; ++t) {
            const int cur = t & 1;
            if (t + 1 < NTL) load_regs((t + 1) * STILE);   // VMEM in flight
            compute_tile(cur);
            if (t + 1 < NTL) write_bufs(cur ^ 1);          // regs ready by now
            __syncthreads();
        }
    } else {
        // single buffer, 2 barriers; loads for t+1 overlap compute(t)
        load_regs(0);
        for (int t = 0; t < NTL; ++t) {
            __syncthreads();                 // prev tile consumed by all waves
            write_bufs(0);
            __syncthreads();
            if (t + 1 < NTL) load_regs((t + 1) * STILE);
            compute_tile(0);
        }
    }

    // epilogue
    const float osc = (o_sidx >= 0) ? strat[o_sidx] : 1.0f;
#pragma unroll
    for (int reg = 0; reg < 4; ++reg) {
        float lf = masked ? (float)Tk : lreg[reg];
        int row = r0 + mbase + quad * 4 + reg;
        if (c == 0) {
            mout[h * Tq + row] = masked ? 0.0f : mreg[reg];
            lout[h * Tq + row] = lf;
        }
        float sc = osc / lf;
#pragma unroll
        for (int nt = 0; nt < NT_O; ++nt) {
            size_t gi = (size_t)row * D_MODEL + h * HD + nt * 16 + c;
            float v = sc * oacc[nt][reg];
            if (accum) v += O[gi];
            O[gi] = v;
        }
    }
}

// ---------------------------------------------------------------------------
// MFMA comb plane: comb[r][c] = csc * (sum_h exp(ascale_h*q_h.k_h - m)/l + unif/Tk)
// Block = 64 rows x 128 cols, loops active heads (HD=64).
// Round-2: K pre-split (copy staging), Q fragments in-register from fp32,
// next head's K prefetched into registers while current head computes.
// ---------------------------------------------------------------------------
__global__ __launch_bounds__(256) void comb_mfma(
    const float* __restrict__ Q,
    const unsigned short* __restrict__ Khi, const unsigned short* __restrict__ Klo,
    const float* __restrict__ mrow, const float* __restrict__ lrow,
    const float* __restrict__ aparam, int amode,
    const float* __restrict__ strat,
    float* __restrict__ comb, int Tq, int Tk, int nh, float inv_scale)
{
    __shared__ __align__(16) unsigned short Kh[128][72], Kl[128][72];
    const int tid = threadIdx.x;
    const int r0 = blockIdx.x * 64, c0 = blockIdx.y * 128;
    const int lane = tid & 63, wave = tid >> 6;
    const int c = lane & 15, quad = lane >> 4;
    const int mbase = wave * 16;

    f32x4 acc[8];
#pragma unroll
    for (int nt = 0; nt < 8; ++nt) acc[nt] = (f32x4){0.f, 0.f, 0.f, 0.f};

    // active-head list (uniform across block)
    int hlist[16]; float glist[16]; int nact = 0; float unif = 0.0f;
    for (int h = 0; h < nh; ++h) {
        float gate = 1.0f;
        if (amode == 1) gate = (aparam[h] > 0.0f) ? 1.0f : 0.0f;
        if (amode == 2) gate = 1.0f / (1.0f + __expf(-aparam[h * 4]));
        if (amode == 1 && gate == 0.0f) { unif += 1.0f; continue; }
        hlist[nact] = h; glist[nact] = gate * inv_scale; ++nact;
    }

    u16x8 krh[4], krl[4];
    auto loadK = [&](int h) {
#pragma unroll
        for (int it = 0; it < 4; ++it) {
            int idx = tid + it * 256;
            int r = idx >> 3, c8 = (idx & 7) * 8;
            size_t go = (size_t)(c0 + r) * D_MODEL + h * 64 + c8;
            krh[it] = *(const u16x8*)&Khi[go];
            krl[it] = *(const u16x8*)&Klo[go];
        }
    };
    if (nact > 0) loadK(hlist[0]);

    for (int i = 0; i < nact; ++i) {
        const int h = hlist[i];
        const float ascale = glist[i];
        __syncthreads();   // previous head's K fully consumed
#pragma unroll
        for (int it = 0; it < 4; ++it) {
            int idx = tid + it * 256;
            int r = idx >> 3, c8 = (idx & 7) * 8;
            *(u16x8*)&Kh[r][c8] = krh[it];
            *(u16x8*)&Kl[r][c8] = krl[it];
        }
        __syncthreads();
        if (i + 1 < nact) loadK(hlist[i + 1]);   // prefetch next head

        // Q fragments in-register from fp32 (wave-private rows)
        bf16x8 qah[2], qal[2];
        const float* qrow = &Q[(size_t)(r0 + mbase + c) * D_MODEL + h * 64];
#pragma unroll
        for (int ks = 0; ks < 2; ++ks) {
            float4 a  = *(const float4*)(qrow + ks * 32 + quad * 8);
            float4 b2 = *(const float4*)(qrow + ks * 32 + quad * 8 + 4);
            unsigned short hh, ll;
            split2(a.x, hh, ll);  qah[ks][0] = (short)hh; qal[ks][0] = (short)ll;
            split2(a.y, hh, ll);  qah[ks][1] = (short)hh; qal[ks][1] = (short)ll;
            split2(a.z, hh, ll);  qah[ks][2] = (short)hh; qal[ks][2] = (short)ll;
            split2(a.w, hh, ll);  qah[ks][3] = (short)hh; qal[ks][3] = (short)ll;
            split2(b2.x, hh, ll); qah[ks][4] = (short)hh; qal[ks][4] = (short)ll;
            split2(b2.y, hh, ll); qah[ks][5] = (short)hh; qal[ks][5] = (short)ll;
            split2(b2.z, hh, ll); qah[ks][6] = (short)hh; qal[ks][6] = (short)ll;
            split2(b2.w, hh, ll); qah[ks][7] = (short)hh; qal[ks][7] = (short)ll;
        }

        float mr[4], li[4];
#pragma unroll
        for (int reg = 0; reg < 4; ++reg) {
            int row = r0 + mbase + quad * 4 + reg;
            mr[reg] = mrow[h * Tq + row];
            li[reg] = 1.0f / lrow[h * Tq + row];
        }
#pragma unroll
        for (int nt = 0; nt < 8; ++nt) {
            f32x4 s = (f32x4){0.f, 0.f, 0.f, 0.f};
#pragma unroll
            for (int ks = 0; ks < 2; ++ks) {
                bf16x8 bh = *(const bf16x8*)&Kh[nt * 16 + c][ks * 32 + quad * 8];
                bf16x8 bl = *(const bf16x8*)&Kl[nt * 16 + c][ks * 32 + quad * 8];
                s = mfma3(qah[ks], qal[ks], bh, bl, s);
            }
#pragma unroll
            for (int reg = 0; reg < 4; ++reg)
                acc[nt][reg] += __expf(s[reg] * ascale - mr[reg]) * li[reg];
        }
    }
    const float csc = (strat[0] + strat[1] + strat[3]) / (float)nh;
    const float uadd = unif / (float)Tk;
#pragma unroll
    for (int nt = 0; nt < 8; ++nt) {
#pragma unroll
        for (int reg = 0; reg < 4; ++reg) {
            int row = r0 + mbase + quad * 4 + reg;
            comb[(size_t)row * Tk + c0 + nt * 16 + c] = csc * (acc[nt][reg] + uadd);
        }
    }
}

// ---------------------------------------------------------------------------
// Per-head 64x64 rotation (fp32, small): Y[t][h*64+e] = sum_d X[t][h*64+d]*R[h][d][e]
// ---------------------------------------------------------------------------
__global__ __launch_bounds__(256) void rotate_heads(
    const float* __restrict__ X, const float* __restrict__ R,
    float* __restrict__ Y)
{
    __shared__ float Rt[64][68];
    __shared__ float xs[64][68];
    const int tid = threadIdx.x;
    const int h = blockIdx.y;
    const int t0 = blockIdx.x * 64;
    for (int idx = tid; idx < 4096; idx += 256) {
        int d = idx >> 6, e = idx & 63;
        Rt[e][d] = R[h * 4096 + idx];
        xs[d][e] = X[(size_t)(t0 + d) * D_MODEL + h * 64 + e];
    }
    __syncthreads();
    const int ty = tid >> 4, tx = tid & 15;
    float acc[4][4] = {};
#pragma unroll 4
    for (int d0 = 0; d0 < 64; d0 += 4) {
        float4 rv[4];
#pragma unroll
        for (int j = 0; j < 4; ++j) rv[j] = *(const float4*)&Rt[tx * 4 + j][d0];
#pragma unroll
        for (int i = 0; i < 4; ++i) {
            float4 a = *(const float4*)&xs[ty * 4 + i][d0];
#pragma unroll
            for (int j = 0; j < 4; ++j)
                acc[i][j] += a.x * rv[j].x + a.y * rv[j].y + a.z * rv[j].z + a.w * rv[j].w;
        }
    }
#pragma unroll
    for (int i = 0; i < 4; ++i)
#pragma unroll
        for (int j = 0; j < 4; ++j)
            Y[(size_t)(t0 + ty * 4 + i) * D_MODEL + h * 64 + tx * 4 + j] = acc[i][j];
}

// ---------------------------------------------------------------------------
// F.interpolate(mode='linear', align_corners=False): [256,1024] -> [2048,1024]
// ---------------------------------------------------------------------------
__global__ __launch_bounds__(256) void interp_lin(
    const float* __restrict__ G, float* __restrict__ out)
{
    const int t = blockIdx.x;
    float src = (t + 0.5f) * 0.125f - 0.5f;
    src = fminf(fmaxf(src, 0.0f), 255.0f);
    float fl = floorf(src);
    int i0 = (int)fl;
    int i1 = min(i0 + 1, 255);
    float w = src - fl;
    const float4* g0 = (const float4*)(G + (size_t)i0 * D_MODEL);
    const float4* g1 = (const float4*)(G + (size_t)i1 * D_MODEL);
    float4* o = (float4*)(out + (size_t)t * D_MODEL);
    int c = threadIdx.x;
    float4 a = g0[c], b = g1[c];
    float4 r;
    r.x = a.x * (1.0f - w) + b.x * w;
    r.y = a.y * (1.0f - w) + b.y * w;
    r.z = a.z * (1.0f - w) + b.z * w;
    r.w = a.w * (1.0f - w) + b.w * w;
    o[c] = r;
}

// ---------------------------------------------------------------------------
extern "C" void kernel_launch(void* const* d_in, const int* in_sizes, int n_in,
                              void* d_out, int out_size, void* d_ws, size_t ws_size,
                              hipStream_t stream)
{
    (void)in_sizes; (void)n_in; (void)ws_size; (void)out_size;
    const float* query    = (const float*)d_in[0];
    const float* key      = (const float*)d_in[1];
    const float* value    = (const float*)d_in[2];
    const float* strat    = (const float*)d_in[3];
    const float* Wqkv_lin = (const float*)d_in[4];
    const float* b_lin    = (const float*)d_in[5];
    const float* Wo_lin   = (const float*)d_in[6];
    const float* bo_lin   = (const float*)d_in[7];
    const float* spars    = (const float*)d_in[8];
    const float* Wqkv_loc = (const float*)d_in[9];
    const float* b_loc    = (const float*)d_in[10];
    const float* Wo_loc   = (const float*)d_in[11];
    const float* bo_loc   = (const float*)d_in[12];
    const float* Wqkv_glb = (const float*)d_in[13];
    const float* b_glb    = (const float*)d_in[14];
    const float* Wo_glb   = (const float*)d_in[15];
    const float* bo_glb   = (const float*)d_in[16];
    const float* Wf       = (const float*)d_in[17];
    const float* bf       = (const float*)d_in[18];
    const float* Rq       = (const float*)d_in[19];
    const float* ent      = (const float*)d_in[20];

    float* out = (float*)d_out;
    float* weighted = out;                        // [2048][1024]
    float* combined = out + (size_t)2048 * 1024;  // [3][2048][2048]
    const size_t PLANE = (size_t)2048 * 2048;

    float* ws   = (float*)d_ws;
    float* qkv  = ws;                   // 3 x 2048x1024
    float* AO   = qkv + 6291456;
    float* LO   = AO + 2097152;
    float* gqkv = LO + 2097152;
    float* gAO  = gqkv + 786432;
    float* gOUT = gAO + 262144;
    float* GI   = gOUT + 262144;
    float* mb   = GI + 2097152;
    float* lb   = mb + 32768;
    float* qrot = qkv;                  // alias: lin qkv dead by then
    float* krot = qkv + 2097152;
    // pre-split bf16 hi/lo buffers (u16), after lb
    unsigned short* Ksp_h = (unsigned short*)(lb + 32768);  // [2048][1024]
    unsigned short* Ksp_l = Ksp_h + 2097152;
    unsigned short* Vtp_h = Ksp_l + 2097152;                // [1024][2048]
    unsigned short* Vtp_l = Vtp_h + 2097152;
    unsigned short* gKs_h = Vtp_l + 2097152;                // [256][1024]
    unsigned short* gKs_l = gKs_h + 262144;
    unsigned short* gVt_h = gKs_l + 262144;                 // [1024][256]
    unsigned short* gVt_l = gVt_h + 262144;

    const float inv8   = 0.125f;
    const float inv128 = 1.0f / sqrtf(128.0f);
    const float* srcs[3] = {query, key, value};

    hipMemsetAsync(weighted, 0, (size_t)2097152 * sizeof(float), stream);

    // ---- LINEAR (proj'd MHA, 16 heads; combined plane 0) ----
    for (int sl = 0; sl < 3; ++sl)
        gemm_mfma<<<dim3(32, 16), 256, 0, stream>>>(
            srcs[sl], 1024, Wqkv_lin + (size_t)sl * 1048576, 1024, b_lin + sl * 1024,
            qkv + (size_t)sl * 2097152, 2048, 1024, 1024, nullptr, 0, 0);
    split_rm<<<dim3(2048), 256, 0, stream>>>(qkv + 2097152, Ksp_h, Ksp_l, 524288);
    split_tr<<<dim3(32, 16), 256, 0, stream>>>(qkv + 4194304, Vtp_h, Vtp_l, 2048);
    flash_mfma<64><<<dim3(32, 16), 256, 0, stream>>>(
        qkv, Ksp_h, Ksp_l, Vtp_h, Vtp_l, nullptr, 0,
        AO, strat, -1, 0, mb, lb, 2048, 2048, inv8);
    comb_mfma<<<dim3(32, 16), 256, 0, stream>>>(
        qkv, Ksp_h, Ksp_l, mb, lb, nullptr, 0, strat,
        combined + 0 * PLANE, 2048, 2048, 16, inv8);
    gemm_mfma<<<dim3(32, 16), 256, 0, stream>>>(
        AO, 1024, Wo_lin, 1024, bo_lin, weighted, 2048, 1024, 1024, strat, 0, 1);

    // ---- SPARSE (raw heads, per-head mask; combined plane 1) ----
    split_rm<<<dim3(2048), 256, 0, stream>>>(key, Ksp_h, Ksp_l, 524288);
    split_tr<<<dim3(32, 16), 256, 0, stream>>>(value, Vtp_h, Vtp_l, 2048);
    flash_mfma<64><<<dim3(32, 16), 256, 0, stream>>>(
        query, Ksp_h, Ksp_l, Vtp_h, Vtp_l, spars, 1,
        weighted, strat, 1, 1, mb, lb, 2048, 2048, inv8);
    comb_mfma<<<dim3(32, 16), 256, 0, stream>>>(
        query, Ksp_h, Ksp_l, mb, lb, spars, 1, strat,
        combined + 1 * PLANE, 2048, 2048, 16, inv8);

    // ---- QUANTUM (rotated raw heads, per-head gate; combined plane 2) ----
    // Vtp still holds split raw value (shared with SPARSE).
    rotate_heads<<<dim3(32, 16), 256, 0, stream>>>(query, Rq, qrot);
    rotate_heads<<<dim3(32, 16), 256, 0, stream>>>(key, Rq, krot);
    split_rm<<<dim3(2048), 256, 0, stream>>>(krot, Ksp_h, Ksp_l, 524288);
    flash_mfma<64><<<dim3(32, 16), 256, 0, stream>>>(
        qrot, Ksp_h, Ksp_l, Vtp_h, Vtp_l, ent, 2,
        weighted, strat, 3, 1, mb, lb, 2048, 2048, inv8);
    comb_mfma<<<dim3(32, 16), 256, 0, stream>>>(
        qrot, Ksp_h, Ksp_l, mb, lb, ent, 2, strat,
        combined + 2 * PLANE, 2048, 2048, 16, inv8);

    // ---- LOCAL (proj'd MHA, 8 heads x 128) ----
    for (int sl = 0; sl < 3; ++sl)
        gemm_mfma<<<dim3(32, 16), 256, 0, stream>>>(
            srcs[sl], 1024, Wqkv_loc + (size_t)sl * 1048576, 1024, b_loc + sl * 1024,
            qkv + (size_t)sl * 2097152, 2048, 1024, 1024, nullptr, 0, 0);
    split_rm<<<dim3(2048), 256, 0, stream>>>(qkv + 2097152, Ksp_h, Ksp_l, 524288);
    split_tr<<<dim3(32, 16), 256, 0, stream>>>(qkv + 4194304, Vtp_h, Vtp_l, 2048);
    flash_mfma<128><<<dim3(32, 8), 256, 0, stream>>>(
        qkv, Ksp_h, Ksp_l, Vtp_h, Vtp_l, nullptr, 0,
        AO, strat, -1, 0, mb, lb, 2048, 2048, inv128);
    gemm_mfma<<<dim3(32, 16), 256, 0, stream>>>(
        AO, 1024, Wo_loc, 1024, bo_loc, LO, 2048, 1024, 1024, nullptr, 0, 0);

    // ---- GLOBAL (strided pool to 256 tokens, 8 heads x 128, interp back) ----
    for (int sl = 0; sl < 3; ++sl)
        gemm_mfma<<<dim3(4, 16), 256, 0, stream>>>(
            srcs[sl], 8192, Wqkv_glb + (size_t)sl * 1048576, 1024, b_glb + sl * 1024,
            gqkv + (size_t)sl * 262144, 256, 1024, 1024, nullptr, 0, 0);
    split_rm<<<dim3(256), 256, 0, stream>>>(gqkv + 262144, gKs_h, gKs_l, 65536);
    split_tr<<<dim3(4, 16), 256, 0, stream>>>(gqkv + 524288, gVt_h, gVt_l, 256);
    flash_mfma<128><<<dim3(4, 8), 256, 0, stream>>>(
        gqkv, gKs_h, gKs_l, gVt_h, gVt_l, nullptr, 0,
        gAO, strat, -1, 0, mb, lb, 256, 256, inv128);
    gemm_mfma<<<dim3(4, 16), 256, 0, stream>>>(
        gAO, 1024, Wo_glb, 1024, bo_glb, gOUT, 256, 1024, 1024, nullptr, 0, 0);
    interp_lin<<<dim3(2048), 256, 0, stream>>>(gOUT, GI);

    // ---- HIER: weighted += s2 * (LO @ WfL^T + GI @ WfR^T + bf) ----
    gemm_mfma<<<dim3(32, 16), 256, 0, stream>>>(
        LO, 1024, Wf, 2048, bf, weighted, 2048, 1024, 1024, strat, 2, 1);
    gemm_mfma<<<dim3(32, 16), 256, 0, stream>>>(
        GI, 1024, Wf + 1024, 2048, nullptr, weighted, 2048, 1024, 1024, strat, 2, 1);
}

// Round 3
// 1290.992 us; speedup vs baseline: 1.8406x; 1.4225x over previous
//
#include <hip/hip_runtime.h>
#include <math.h>

// Problem constants: B=1, T=2048, D=1024, H=16, HD=64, STRIDE=8, Tg=256.
// Output 0: weighted [2048][1024]
// Output 1: combined [3][2048][2048] = (s0+s1+s3) * {linear_w, sparse_w, quantum_w}
#define D_MODEL 1024

typedef __attribute__((ext_vector_type(8))) short bf16x8;
typedef __attribute__((ext_vector_type(4))) float f32x4;
typedef __attribute__((ext_vector_type(8))) unsigned short u16x8;

// fp32 -> bf16 RNE, and bf16 -> fp32
__device__ __forceinline__ unsigned short bfr(float f) {
    unsigned u = __float_as_uint(f);
    u += 0x7fffu + ((u >> 16) & 1u);
    return (unsigned short)(u >> 16);
}
__device__ __forceinline__ float bff(unsigned short s) {
    return __uint_as_float(((unsigned)s) << 16);
}
// split x = hi + lo (both bf16); hi*hi+hi*lo+lo*hi captures x*y to ~2^-17 rel
__device__ __forceinline__ void split2(float x, unsigned short &h, unsigned short &l) {
    h = bfr(x);
    l = bfr(x - bff(h));
}
__device__ __forceinline__ f32x4 mfma3(bf16x8 ah, bf16x8 al, bf16x8 bh, bf16x8 bl, f32x4 c) {
    c = __builtin_amdgcn_mfma_f32_16x16x32_bf16(ah, bh, c, 0, 0, 0);
    c = __builtin_amdgcn_mfma_f32_16x16x32_bf16(ah, bl, c, 0, 0, 0);
    c = __builtin_amdgcn_mfma_f32_16x16x32_bf16(al, bh, c, 0, 0, 0);
    return c;
}

// ---------------------------------------------------------------------------
// Pre-split kernels: fp32 -> bf16 hi/lo (computed ONCE, reused by every
// flash/comb block+tile instead of per-tile split2 on the critical path).
// ---------------------------------------------------------------------------
__global__ __launch_bounds__(256) void split_rm(
    const float* __restrict__ in, unsigned short* __restrict__ hi,
    unsigned short* __restrict__ lo, int n4)
{
    int idx = blockIdx.x * 256 + threadIdx.x;
    if (idx >= n4) return;
    float4 v = ((const float4*)in)[idx];
    ushort4 hs, ls;
    split2(v.x, hs.x, ls.x); split2(v.y, hs.y, ls.y);
    split2(v.z, hs.z, ls.z); split2(v.w, hs.w, ls.w);
    ((ushort4*)hi)[idx] = hs;
    ((ushort4*)lo)[idx] = ls;
}

// Transposed split: in [T][1024] fp32 -> hi/lo [1024][T] u16 (row = global d).
__global__ __launch_bounds__(256) void split_tr(
    const float* __restrict__ in, unsigned short* __restrict__ hi,
    unsigned short* __restrict__ lo, int T)
{
    __shared__ float xs[64][65];   // [t][d]
    const int t0 = blockIdx.x * 64, d0 = blockIdx.y * 64;
    for (int idx = threadIdx.x; idx < 64 * 16; idx += 256) {
        int r = idx >> 4, c4 = (idx & 15) * 4;
        float4 v = *(const float4*)&in[(size_t)(t0 + r) * D_MODEL + d0 + c4];
        xs[r][c4] = v.x; xs[r][c4 + 1] = v.y; xs[r][c4 + 2] = v.z; xs[r][c4 + 3] = v.w;
    }
    __syncthreads();
    for (int idx = threadIdx.x; idx < 64 * 8; idx += 256) {
        int dd = idx >> 3, t8 = (idx & 7) * 8;
        u16x8 hs, ls;
#pragma unroll
        for (int j = 0; j < 8; ++j) {
            unsigned short hh, ll;
            split2(xs[t8 + j][dd], hh, ll);
            hs[j] = hh; ls[j] = ll;
        }
        *(u16x8*)&hi[(size_t)(d0 + dd) * T + t0 + t8] = hs;
        *(u16x8*)&lo[(size_t)(d0 + dd) * T + t0 + t8] = ls;
    }
}

// ---------------------------------------------------------------------------
// MFMA GEMM: C[M,N] (+)= scale * (X[M,K] @ W[N,K]^T + bias), split-bf16.
// 64x64 tile, 4 waves. Round-3: register prefetch of next k-step so global
// latency is not exposed between the two barriers.
// ---------------------------------------------------------------------------
__global__ __launch_bounds__(256) void gemm_mfma(
    const float* __restrict__ X, int xrstride,
    const float* __restrict__ W, int wrstride,
    const float* __restrict__ bias,
    float* __restrict__ C, int M, int N, int K,
    const float* __restrict__ sptr, int sidx, int accum)
{
    __shared__ unsigned short Xh[64][40], Xl[64][40];
    __shared__ unsigned short Wh[64][40], Wl[64][40];
    const int tid = threadIdx.x;
    const int m0 = blockIdx.x * 64, n0 = blockIdx.y * 64;
    const int lane = tid & 63, wave = tid >> 6;
    const int c = lane & 15, quad = lane >> 4;
    const int mbase = wave * 16;

    f32x4 acc[4];
#pragma unroll
    for (int nt = 0; nt < 4; ++nt) acc[nt] = (f32x4){0.f, 0.f, 0.f, 0.f};

    float4 xr[2], wr[2];
    const int r_ = tid >> 3, d4_ = (tid & 7) * 4;
    const int r2_ = (tid + 256) >> 3, d42_ = ((tid + 256) & 7) * 4;
    auto ldXW = [&](int k0) {
        xr[0] = *(const float4*)&X[(size_t)(m0 + r_) * xrstride + k0 + d4_];
        xr[1] = *(const float4*)&X[(size_t)(m0 + r2_) * xrstride + k0 + d42_];
        wr[0] = *(const float4*)&W[(size_t)(n0 + r_) * wrstride + k0 + d4_];
        wr[1] = *(const float4*)&W[(size_t)(n0 + r2_) * wrstride + k0 + d42_];
    };
    ldXW(0);

    for (int k0 = 0; k0 < K; k0 += 32) {
        __syncthreads();
        {
            ushort4 hs, ls;
            split2(xr[0].x, hs.x, ls.x); split2(xr[0].y, hs.y, ls.y);
            split2(xr[0].z, hs.z, ls.z); split2(xr[0].w, hs.w, ls.w);
            *(ushort4*)&Xh[r_][d4_] = hs; *(ushort4*)&Xl[r_][d4_] = ls;
            split2(xr[1].x, hs.x, ls.x); split2(xr[1].y, hs.y, ls.y);
            split2(xr[1].z, hs.z, ls.z); split2(xr[1].w, hs.w, ls.w);
            *(ushort4*)&Xh[r2_][d42_] = hs; *(ushort4*)&Xl[r2_][d42_] = ls;
            split2(wr[0].x, hs.x, ls.x); split2(wr[0].y, hs.y, ls.y);
            split2(wr[0].z, hs.z, ls.z); split2(wr[0].w, hs.w, ls.w);
            *(ushort4*)&Wh[r_][d4_] = hs; *(ushort4*)&Wl[r_][d4_] = ls;
            split2(wr[1].x, hs.x, ls.x); split2(wr[1].y, hs.y, ls.y);
            split2(wr[1].z, hs.z, ls.z); split2(wr[1].w, hs.w, ls.w);
            *(ushort4*)&Wh[r2_][d42_] = hs; *(ushort4*)&Wl[r2_][d42_] = ls;
        }
        __syncthreads();
        if (k0 + 32 < K) ldXW(k0 + 32);
        bf16x8 ah = *(const bf16x8*)&Xh[mbase + c][quad * 8];
        bf16x8 al = *(const bf16x8*)&Xl[mbase + c][quad * 8];
#pragma unroll
        for (int nt = 0; nt < 4; ++nt) {
            bf16x8 bh = *(const bf16x8*)&Wh[nt * 16 + c][quad * 8];
            bf16x8 bl = *(const bf16x8*)&Wl[nt * 16 + c][quad * 8];
            acc[nt] = mfma3(ah, al, bh, bl, acc[nt]);
        }
    }
    const float s = (sptr != nullptr) ? sptr[sidx] : 1.0f;
#pragma unroll
    for (int nt = 0; nt < 4; ++nt) {
#pragma unroll
        for (int reg = 0; reg < 4; ++reg) {
            int row = m0 + mbase + quad * 4 + reg;
            int col = n0 + nt * 16 + c;
            float v = acc[nt][reg] + (bias ? bias[col] : 0.0f);
            v *= s;
            size_t gi = (size_t)row * N + col;
            if (accum) v += C[gi];
            C[gi] = v;
        }
    }
}

// ---------------------------------------------------------------------------
// MFMA flash attention, one block = (head, 64 query rows [, key-split z]).
//   Round-3:
//   - Defer-max (THR=8): rescale of oacc/lacc only when a tile max exceeds
//     m+8 (never after tile 0 for these score scales). l accumulated
//     PER-LANE, single cross-lane reduce in epilogue. Invariant
//     l = sum exp(s - m_cur) holds throughout -> (m,l) consistent for comb.
//   - Single K/V buffer for all HD (flash<128> LDS 86->48 KB, 2 blocks/CU).
//   - Optional split-K via gridDim.z: each z writes unnormalized partial O
//     (z==0 -> O, z==1 -> O2) and m,l at [(z*H+h)*Tq+row]; combine2 merges.
//   Masked heads (amode 1, gate 0): P==1, l=Tk_local, m=0 (exact uniform).
// ---------------------------------------------------------------------------
template <int HD>
__global__ __launch_bounds__(256) void flash_mfma(
    const float* __restrict__ Q,
    const unsigned short* __restrict__ Khi, const unsigned short* __restrict__ Klo,
    const unsigned short* __restrict__ Vthi, const unsigned short* __restrict__ Vtlo,
    const float* __restrict__ aparam, int amode,
    float* __restrict__ O, float* __restrict__ O2,
    const float* __restrict__ strat, int o_sidx, int accum,
    float* __restrict__ mout, float* __restrict__ lout,
    int Tq, int Tk, float inv_scale)
{
    constexpr int ROWS = 64;
    constexpr int STILE = (HD == 64) ? 64 : 32;
    constexpr int NT_S = STILE / 16;   // score n-tiles
    constexpr int KS   = HD / 32;      // QK k-steps
    constexpr int NT_O = HD / 16;      // O n-tiles
    constexpr int KS_PV = STILE / 32;  // PV k-steps
    constexpr int QP = HD + 8;         // padded K row length (u16), 16B-aligned
    constexpr int SP = STILE + 8;
    constexpr int KIT = STILE * HD / 8 / 256;   // u16x8 items per thread (K)
    constexpr int VIT = STILE * HD / 8 / 256;   // u16x8 items per thread (V)

    __shared__ __align__(16) unsigned short Kh[STILE][QP], Kl[STILE][QP];
    __shared__ __align__(16) unsigned short Vh[HD][SP],  Vl[HD][SP];
    __shared__ __align__(16) unsigned short Ph[ROWS][SP], Pl[ROWS][SP];

    const int tid = threadIdx.x;
    const int h = blockIdx.y;
    const int r0 = blockIdx.x * ROWS;
    const int lane = tid & 63, wave = tid >> 6;
    const int c = lane & 15, quad = lane >> 4;
    const int mbase = wave * 16;
    const int ZS = gridDim.z;
    const int tkloc = Tk / ZS;
    const int kv0 = blockIdx.z * tkloc;

    float gate = 1.0f;
    if (amode == 1) gate = (aparam[h] > 0.0f) ? 1.0f : 0.0f;
    if (amode == 2) gate = 1.0f / (1.0f + __expf(-aparam[h * 4]));
    const float ascale = gate * inv_scale;
    const bool masked = (amode == 1) && (gate == 0.0f);

    if (masked) {  // uniform P == 1.0 (visible after first barrier)
        for (int idx = tid; idx < ROWS * STILE; idx += 256) {
            int r = idx / STILE, cc = idx % STILE;
            Ph[r][cc] = 0x3F80; Pl[r][cc] = 0;
        }
    }

    // Q A-fragments straight from global (key-loop invariant, wave-private)
    bf16x8 qah[KS], qal[KS];
    if (!masked) {
        const float* qrow = &Q[(size_t)(r0 + mbase + c) * D_MODEL + h * HD];
#pragma unroll
        for (int ks = 0; ks < KS; ++ks) {
            float4 a  = *(const float4*)(qrow + ks * 32 + quad * 8);
            float4 b2 = *(const float4*)(qrow + ks * 32 + quad * 8 + 4);
            unsigned short hh, ll;
            split2(a.x, hh, ll);  qah[ks][0] = (short)hh; qal[ks][0] = (short)ll;
            split2(a.y, hh, ll);  qah[ks][1] = (short)hh; qal[ks][1] = (short)ll;
            split2(a.z, hh, ll);  qah[ks][2] = (short)hh; qal[ks][2] = (short)ll;
            split2(a.w, hh, ll);  qah[ks][3] = (short)hh; qal[ks][3] = (short)ll;
            split2(b2.x, hh, ll); qah[ks][4] = (short)hh; qal[ks][4] = (short)ll;
            split2(b2.y, hh, ll); qah[ks][5] = (short)hh; qal[ks][5] = (short)ll;
            split2(b2.z, hh, ll); qah[ks][6] = (short)hh; qal[ks][6] = (short)ll;
            split2(b2.w, hh, ll); qah[ks][7] = (short)hh; qal[ks][7] = (short)ll;
        }
    }

    float mreg[4], lacc[4];
#pragma unroll
    for (int i = 0; i < 4; ++i) { mreg[i] = -1e30f; lacc[i] = 0.0f; }
    f32x4 oacc[NT_O];
#pragma unroll
    for (int nt = 0; nt < NT_O; ++nt) oacc[nt] = (f32x4){0.f, 0.f, 0.f, 0.f};

    u16x8 krh[KIT], krl[KIT], vrh[VIT], vrl[VIT];

    auto load_regs = [&](int s0) {
        if (!masked) {
#pragma unroll
            for (int it = 0; it < KIT; ++it) {
                int idx = tid + it * 256;
                int r = idx / (HD / 8), c8 = (idx % (HD / 8)) * 8;
                size_t go = (size_t)(s0 + r) * D_MODEL + h * HD + c8;
                krh[it] = *(const u16x8*)&Khi[go];
                krl[it] = *(const u16x8*)&Klo[go];
            }
        }
#pragma unroll
        for (int it = 0; it < VIT; ++it) {
            int idx = tid + it * 256;
            int d = idx % HD, s8 = (idx / HD) * 8;
            size_t go = (size_t)(h * HD + d) * Tk + s0 + s8;
            vrh[it] = *(const u16x8*)&Vthi[go];
            vrl[it] = *(const u16x8*)&Vtlo[go];
        }
    };
    auto write_bufs = [&]() {
        if (!masked) {
#pragma unroll
            for (int it = 0; it < KIT; ++it) {
                int idx = tid + it * 256;
                int r = idx / (HD / 8), c8 = (idx % (HD / 8)) * 8;
                *(u16x8*)&Kh[r][c8] = krh[it];
                *(u16x8*)&Kl[r][c8] = krl[it];
            }
        }
#pragma unroll
        for (int it = 0; it < VIT; ++it) {
            int idx = tid + it * 256;
            int d = idx % HD, s8 = (idx / HD) * 8;
            *(u16x8*)&Vh[d][s8] = vrh[it];
            *(u16x8*)&Vl[d][s8] = vrl[it];
        }
    };

    auto compute_tile = [&]() {
        if (!masked) {
            f32x4 sf[NT_S];
#pragma unroll
            for (int nt = 0; nt < NT_S; ++nt) {
                f32x4 s = (f32x4){0.f, 0.f, 0.f, 0.f};
#pragma unroll
                for (int ks = 0; ks < KS; ++ks) {
                    bf16x8 bh = *(const bf16x8*)&Kh[nt * 16 + c][ks * 32 + quad * 8];
                    bf16x8 bl = *(const bf16x8*)&Kl[nt * 16 + c][ks * 32 + quad * 8];
                    s = mfma3(qah[ks], qal[ks], bh, bl, s);
                }
                sf[nt] = s * ascale;
            }
            // per-lane row max; rescale only if any row grew past m+8
            float tm[4];
#pragma unroll
            for (int reg = 0; reg < 4; ++reg) tm[reg] = sf[0][reg];
#pragma unroll
            for (int nt = 1; nt < NT_S; ++nt)
#pragma unroll
                for (int reg = 0; reg < 4; ++reg) tm[reg] = fmaxf(tm[reg], sf[nt][reg]);
            bool need = (tm[0] > mreg[0] + 8.0f) || (tm[1] > mreg[1] + 8.0f) ||
                        (tm[2] > mreg[2] + 8.0f) || (tm[3] > mreg[3] + 8.0f);
            if (__any(need)) {
#pragma unroll
                for (int off = 1; off < 16; off <<= 1)
#pragma unroll
                    for (int reg = 0; reg < 4; ++reg)
                        tm[reg] = fmaxf(tm[reg], __shfl_xor(tm[reg], off));
#pragma unroll
                for (int reg = 0; reg < 4; ++reg) {
                    float nm = fmaxf(mreg[reg], tm[reg]);
                    float al = __expf(mreg[reg] - nm);
                    mreg[reg] = nm;
                    lacc[reg] *= al;
#pragma unroll
                    for (int nt = 0; nt < NT_O; ++nt) oacc[nt][reg] *= al;
                }
            }
            // p = exp(s - m) (bounded by e^8), per-lane l accumulation
#pragma unroll
            for (int nt = 0; nt < NT_S; ++nt) {
#pragma unroll
                for (int reg = 0; reg < 4; ++reg) {
                    float p = __expf(sf[nt][reg] - mreg[reg]);
                    lacc[reg] += p;
                    unsigned short hh, ll;
                    split2(p, hh, ll);
                    int row = mbase + quad * 4 + reg;
                    Ph[row][nt * 16 + c] = hh;
                    Pl[row][nt * 16 + c] = ll;
                }
            }
        }
        // PV (oacc already rescaled above when needed)
        bf16x8 pah[KS_PV], pal[KS_PV];
#pragma unroll
        for (int ks = 0; ks < KS_PV; ++ks) {
            pah[ks] = *(const bf16x8*)&Ph[mbase + c][ks * 32 + quad * 8];
            pal[ks] = *(const bf16x8*)&Pl[mbase + c][ks * 32 + quad * 8];
        }
#pragma unroll
        for (int nt = 0; nt < NT_O; ++nt) {
            f32x4 o = oacc[nt];
#pragma unroll
            for (int ks = 0; ks < KS_PV; ++ks) {
                bf16x8 bh = *(const bf16x8*)&Vh[nt * 16 + c][ks * 32 + quad * 8];
                bf16x8 bl = *(const bf16x8*)&Vl[nt * 16 + c][ks * 32 + quad * 8];
                o = mfma3(pah[ks], pal[ks], bh, bl, o);
            }
            oacc[nt] = o;
        }
    };

    const int NTL = tkloc / STILE;
    load_regs(kv0);
    for (int t = 0; t < NTL; ++t) {
        __syncthreads();                 // prev tile consumed by all waves
        write_bufs();
        __syncthreads();
        if (t + 1 < NTL) load_regs(kv0 + (t + 1) * STILE);
        compute_tile();
    }

    // cross-lane l reduce (deferred from per-tile)
#pragma unroll
    for (int off = 1; off < 16; off <<= 1)
#pragma unroll
        for (int reg = 0; reg < 4; ++reg) lacc[reg] += __shfl_xor(lacc[reg], off);

    if (ZS == 1) {
        const float osc = (o_sidx >= 0) ? strat[o_sidx] : 1.0f;
#pragma unroll
        for (int reg = 0; reg < 4; ++reg) {
            float lf = masked ? (float)Tk : lacc[reg];
            int row = r0 + mbase + quad * 4 + reg;
            if (c == 0) {
                mout[h * Tq + row] = masked ? 0.0f : mreg[reg];
                lout[h * Tq + row] = lf;
            }
            float sc = osc / lf;
#pragma unroll
            for (int nt = 0; nt < NT_O; ++nt) {
                size_t gi = (size_t)row * D_MODEL + h * HD + nt * 16 + c;
                float v = sc * oacc[nt][reg];
                if (accum) v += O[gi];
                O[gi] = v;
            }
        }
    } else {
        float* Op = (blockIdx.z == 0) ? O : O2;
#pragma unroll
        for (int reg = 0; reg < 4; ++reg) {
            float lf = masked ? (float)tkloc : lacc[reg];
            int row = r0 + mbase + quad * 4 + reg;
            if (c == 0) {
                mout[(blockIdx.z * gridDim.y + h) * Tq + row] = masked ? 0.0f : mreg[reg];
                lout[(blockIdx.z * gridDim.y + h) * Tq + row] = lf;
            }
#pragma unroll
            for (int nt = 0; nt < NT_O; ++nt)
                Op[(size_t)row * D_MODEL + h * HD + nt * 16 + c] = oacc[nt][reg];
        }
    }
}

// ---------------------------------------------------------------------------
// Merge 2 split-K partials (HD=128, H=8): O = osc*(O0*w0+O1*w1)/l (+accum)
// ---------------------------------------------------------------------------
__global__ __launch_bounds__(256) void combine2(
    const float* __restrict__ O0, const float* __restrict__ O1,
    const float* __restrict__ mp, const float* __restrict__ lp,
    float* __restrict__ O, const float* __restrict__ strat,
    int o_sidx, int accum, int Tq)
{
    const int row = blockIdx.x;
    const int c4 = threadIdx.x * 4;
    const int h = c4 >> 7;             // HD=128
    const float m0 = mp[h * Tq + row], m1 = mp[(8 + h) * Tq + row];
    const float l0 = lp[h * Tq + row], l1 = lp[(8 + h) * Tq + row];
    const float m = fmaxf(m0, m1);
    const float w0 = __expf(m0 - m), w1 = __expf(m1 - m);
    const float osc = (o_sidx >= 0) ? strat[o_sidx] : 1.0f;
    const float sc = osc / (l0 * w0 + l1 * w1);
    float4 a = *(const float4*)&O0[(size_t)row * D_MODEL + c4];
    float4 b = *(const float4*)&O1[(size_t)row * D_MODEL + c4];
    size_t gi = (size_t)row * D_MODEL + c4;
    float4 r;
    r.x = sc * (a.x * w0 + b.x * w1);
    r.y = sc * (a.y * w0 + b.y * w1);
    r.z = sc * (a.z * w0 + b.z * w1);
    r.w = sc * (a.w * w0 + b.w * w1);
    if (accum) {
        float4 o = *(const float4*)&O[gi];
        r.x += o.x; r.y += o.y; r.z += o.z; r.w += o.w;
    }
    *(float4*)&O[gi] = r;
}

// ---------------------------------------------------------------------------
// MFMA comb plane: comb[r][c] = csc * (sum_h exp(ascale_h*q_h.k_h - m)/l + unif/Tk)
// Block = 64 rows x 128 cols, loops active heads (HD=64). K pre-split,
// Q fragments in-register, next head's K prefetched.
// ---------------------------------------------------------------------------
__global__ __launch_bounds__(256) void comb_mfma(
    const float* __restrict__ Q,
    const unsigned short* __restrict__ Khi, const unsigned short* __restrict__ Klo,
    const float* __restrict__ mrow, const float* __restrict__ lrow,
    const float* __restrict__ aparam, int amode,
    const float* __restrict__ strat,
    float* __restrict__ comb, int Tq, int Tk, int nh, float inv_scale)
{
    __shared__ __align__(16) unsigned short Kh[128][72], Kl[128][72];
    const int tid = threadIdx.x;
    const int r0 = blockIdx.x * 64, c0 = blockIdx.y * 128;
    const int lane = tid & 63, wave = tid >> 6;
    const int c = lane & 15, quad = lane >> 4;
    const int mbase = wave * 16;

    f32x4 acc[8];
#pragma unroll
    for (int nt = 0; nt < 8; ++nt) acc[nt] = (f32x4){0.f, 0.f, 0.f, 0.f};

    int hlist[16]; float glist[16]; int nact = 0; float unif = 0.0f;
    for (int h = 0; h < nh; ++h) {
        float gate = 1.0f;
        if (amode == 1) gate = (aparam[h] > 0.0f) ? 1.0f : 0.0f;
        if (amode == 2) gate = 1.0f / (1.0f + __expf(-aparam[h * 4]));
        if (amode == 1 && gate == 0.0f) { unif += 1.0f; continue; }
        hlist[nact] = h; glist[nact] = gate * inv_scale; ++nact;
    }

    u16x8 krh[4], krl[4];
    auto loadK = [&](int h) {
#pragma unroll
        for (int it = 0; it < 4; ++it) {
            int idx = tid + it * 256;
            int r = idx >> 3, c8 = (idx & 7) * 8;
            size_t go = (size_t)(c0 + r) * D_MODEL + h * 64 + c8;
            krh[it] = *(const u16x8*)&Khi[go];
            krl[it] = *(const u16x8*)&Klo[go];
        }
    };
    if (nact > 0) loadK(hlist[0]);

    for (int i = 0; i < nact; ++i) {
        const int h = hlist[i];
        const float ascale = glist[i];
        __syncthreads();   // previous head's K fully consumed
#pragma unroll
        for (int it = 0; it < 4; ++it) {
            int idx = tid + it * 256;
            int r = idx >> 3, c8 = (idx & 7) * 8;
            *(u16x8*)&Kh[r][c8] = krh[it];
            *(u16x8*)&Kl[r][c8] = krl[it];
        }
        __syncthreads();
        if (i + 1 < nact) loadK(hlist[i + 1]);   // prefetch next head

        bf16x8 qah[2], qal[2];
        const float* qrow = &Q[(size_t)(r0 + mbase + c) * D_MODEL + h * 64];
#pragma unroll
        for (int ks = 0; ks < 2; ++ks) {
            float4 a  = *(const float4*)(qrow + ks * 32 + quad * 8);
            float4 b2 = *(const float4*)(qrow + ks * 32 + quad * 8 + 4);
            unsigned short hh, ll;
            split2(a.x, hh, ll);  qah[ks][0] = (short)hh; qal[ks][0] = (short)ll;
            split2(a.y, hh, ll);  qah[ks][1] = (short)hh; qal[ks][1] = (short)ll;
            split2(a.z, hh, ll);  qah[ks][2] = (short)hh; qal[ks][2] = (short)ll;
            split2(a.w, hh, ll);  qah[ks][3] = (short)hh; qal[ks][3] = (short)ll;
            split2(b2.x, hh, ll); qah[ks][4] = (short)hh; qal[ks][4] = (short)ll;
            split2(b2.y, hh, ll); qah[ks][5] = (short)hh; qal[ks][5] = (short)ll;
            split2(b2.z, hh, ll); qah[ks][6] = (short)hh; qal[ks][6] = (short)ll;
            split2(b2.w, hh, ll); qah[ks][7] = (short)hh; qal[ks][7] = (short)ll;
        }

        float mr[4], li[4];
#pragma unroll
        for (int reg = 0; reg < 4; ++reg) {
            int row = r0 + mbase + quad * 4 + reg;
            mr[reg] = mrow[h * Tq + row];
            li[reg] = 1.0f / lrow[h * Tq + row];
        }
#pragma unroll
        for (int nt = 0; nt < 8; ++nt) {
            f32x4 s = (f32x4){0.f, 0.f, 0.f, 0.f};
#pragma unroll
            for (int ks = 0; ks < 2; ++ks) {
                bf16x8 bh = *(const bf16x8*)&Kh[nt * 16 + c][ks * 32 + quad * 8];
                bf16x8 bl = *(const bf16x8*)&Kl[nt * 16 + c][ks * 32 + quad * 8];
                s = mfma3(qah[ks], qal[ks], bh, bl, s);
            }
#pragma unroll
            for (int reg = 0; reg < 4; ++reg)
                acc[nt][reg] += __expf(s[reg] * ascale - mr[reg]) * li[reg];
        }
    }
    const float csc = (strat[0] + strat[1] + strat[3]) / (float)nh;
    const float uadd = unif / (float)Tk;
#pragma unroll
    for (int nt = 0; nt < 8; ++nt) {
#pragma unroll
        for (int reg = 0; reg < 4; ++reg) {
            int row = r0 + mbase + quad * 4 + reg;
            comb[(size_t)row * Tk + c0 + nt * 16 + c] = csc * (acc[nt][reg] + uadd);
        }
    }
}

// ---------------------------------------------------------------------------
// Per-head 64x64 rotation (fp32, small): Y[t][h*64+e] = sum_d X[t][h*64+d]*R[h][d][e]
// ---------------------------------------------------------------------------
__global__ __launch_bounds__(256) void rotate_heads(
    const float* __restrict__ X, const float* __restrict__ R,
    float* __restrict__ Y)
{
    __shared__ float Rt[64][68];
    __shared__ float xs[64][68];
    const int tid = threadIdx.x;
    const int h = blockIdx.y;
    const int t0 = blockIdx.x * 64;
    for (int idx = tid; idx < 4096; idx += 256) {
        int d = idx >> 6, e = idx & 63;
        Rt[e][d] = R[h * 4096 + idx];
        xs[d][e] = X[(size_t)(t0 + d) * D_MODEL + h * 64 + e];
    }
    __syncthreads();
    const int ty = tid >> 4, tx = tid & 15;
    float acc[4][4] = {};
#pragma unroll 4
    for (int d0 = 0; d0 < 64; d0 += 4) {
        float4 rv[4];
#pragma unroll
        for (int j = 0; j < 4; ++j) rv[j] = *(const float4*)&Rt[tx * 4 + j][d0];
#pragma unroll
        for (int i = 0; i < 4; ++i) {
            float4 a = *(const float4*)&xs[ty * 4 + i][d0];
#pragma unroll
            for (int j = 0; j < 4; ++j)
                acc[i][j] += a.x * rv[j].x + a.y * rv[j].y + a.z * rv[j].z + a.w * rv[j].w;
        }
    }
#pragma unroll
    for (int i = 0; i < 4; ++i)
#pragma unroll
        for (int j = 0; j < 4; ++j)
            Y[(size_t)(t0 + ty * 4 + i) * D_MODEL + h * 64 + tx * 4 + j] = acc[i][j];
}

// ---------------------------------------------------------------------------
// F.interpolate(mode='linear', align_corners=False): [256,1024] -> [2048,1024]
// ---------------------------------------------------------------------------
__global__ __launch_bounds__(256) void interp_lin(
    const float* __restrict__ G, float* __restrict__ out)
{
    const int t = blockIdx.x;
    float src = (t + 0.5f) * 0.125f - 0.5f;
    src = fminf(fmaxf(src, 0.0f), 255.0f);
    float fl = floorf(src);
    int i0 = (int)fl;
    int i1 = min(i0 + 1, 255);
    float w = src - fl;
    const float4* g0 = (const float4*)(G + (size_t)i0 * D_MODEL);
    const float4* g1 = (const float4*)(G + (size_t)i1 * D_MODEL);
    float4* o = (float4*)(out + (size_t)t * D_MODEL);
    int c = threadIdx.x;
    float4 a = g0[c], b = g1[c];
    float4 r;
    r.x = a.x * (1.0f - w) + b.x * w;
    r.y = a.y * (1.0f - w) + b.y * w;
    r.z = a.z * (1.0f - w) + b.z * w;
    r.w = a.w * (1.0f - w) + b.w * w;
    o[c] = r;
}

// ---------------------------------------------------------------------------
extern "C" void kernel_launch(void* const* d_in, const int* in_sizes, int n_in,
                              void* d_out, int out_size, void* d_ws, size_t ws_size,
                              hipStream_t stream)
{
    (void)in_sizes; (void)n_in; (void)ws_size; (void)out_size;
    const float* query    = (const float*)d_in[0];
    const float* key      = (const float*)d_in[1];
    const float* value    = (const float*)d_in[2];
    const float* strat    = (const float*)d_in[3];
    const float* Wqkv_lin = (const float*)d_in[4];
    const float* b_lin    = (const float*)d_in[5];
    const float* Wo_lin   = (const float*)d_in[6];
    const float* bo_lin   = (const float*)d_in[7];
    const float* spars    = (const float*)d_in[8];
    const float* Wqkv_loc = (const float*)d_in[9];
    const float* b_loc    = (const float*)d_in[10];
    const float* Wo_loc   = (const float*)d_in[11];
    const float* bo_loc   = (const float*)d_in[12];
    const float* Wqkv_glb = (const float*)d_in[13];
    const float* b_glb    = (const float*)d_in[14];
    const float* Wo_glb   = (const float*)d_in[15];
    const float* bo_glb   = (const float*)d_in[16];
    const float* Wf       = (const float*)d_in[17];
    const float* bf       = (const float*)d_in[18];
    const float* Rq       = (const float*)d_in[19];
    const float* ent      = (const float*)d_in[20];

    float* out = (float*)d_out;
    float* weighted = out;                        // [2048][1024]
    float* combined = out + (size_t)2048 * 1024;  // [3][2048][2048]
    const size_t PLANE = (size_t)2048 * 2048;

    float* ws   = (float*)d_ws;
    float* qkv  = ws;                   // 3 x 2048x1024
    float* AO   = qkv + 6291456;
    float* LO   = AO + 2097152;
    float* gqkv = LO + 2097152;
    float* gAO  = gqkv + 786432;
    float* gOUT = gAO + 262144;
    float* GI   = gOUT + 262144;
    float* mb   = GI + 2097152;
    float* lb   = mb + 32768;
    float* qrot = qkv;                  // alias: lin qkv dead by then
    float* krot = qkv + 2097152;
    // pre-split bf16 hi/lo buffers (u16), after lb
    unsigned short* Ksp_h = (unsigned short*)(lb + 32768);  // [2048][1024]
    unsigned short* Ksp_l = Ksp_h + 2097152;
    unsigned short* Vtp_h = Ksp_l + 2097152;                // [1024][2048]
    unsigned short* Vtp_l = Vtp_h + 2097152;
    unsigned short* gKs_h = Vtp_l + 2097152;                // [256][1024]
    unsigned short* gKs_l = gKs_h + 262144;
    unsigned short* gVt_h = gKs_l + 262144;                 // [1024][256]
    unsigned short* gVt_l = gVt_h + 262144;

    const float inv8   = 0.125f;
    const float inv128 = 1.0f / sqrtf(128.0f);
    const float* srcs[3] = {query, key, value};

    hipMemsetAsync(weighted, 0, (size_t)2097152 * sizeof(float), stream);

    // ---- LINEAR (proj'd MHA, 16 heads; combined plane 0) ----
    for (int sl = 0; sl < 3; ++sl)
        gemm_mfma<<<dim3(32, 16), 256, 0, stream>>>(
            srcs[sl], 1024, Wqkv_lin + (size_t)sl * 1048576, 1024, b_lin + sl * 1024,
            qkv + (size_t)sl * 2097152, 2048, 1024, 1024, nullptr, 0, 0);
    split_rm<<<dim3(2048), 256, 0, stream>>>(qkv + 2097152, Ksp_h, Ksp_l, 524288);
    split_tr<<<dim3(32, 16), 256, 0, stream>>>(qkv + 4194304, Vtp_h, Vtp_l, 2048);
    flash_mfma<64><<<dim3(32, 16), 256, 0, stream>>>(
        qkv, Ksp_h, Ksp_l, Vtp_h, Vtp_l, nullptr, 0,
        AO, nullptr, strat, -1, 0, mb, lb, 2048, 2048, inv8);
    comb_mfma<<<dim3(32, 16), 256, 0, stream>>>(
        qkv, Ksp_h, Ksp_l, mb, lb, nullptr, 0, strat,
        combined + 0 * PLANE, 2048, 2048, 16, inv8);
    gemm_mfma<<<dim3(32, 16), 256, 0, stream>>>(
        AO, 1024, Wo_lin, 1024, bo_lin, weighted, 2048, 1024, 1024, strat, 0, 1);

    // ---- SPARSE (raw heads, per-head mask; combined plane 1) ----
    split_rm<<<dim3(2048), 256, 0, stream>>>(key, Ksp_h, Ksp_l, 524288);
    split_tr<<<dim3(32, 16), 256, 0, stream>>>(value, Vtp_h, Vtp_l, 2048);
    flash_mfma<64><<<dim3(32, 16), 256, 0, stream>>>(
        query, Ksp_h, Ksp_l, Vtp_h, Vtp_l, spars, 1,
        weighted, nullptr, strat, 1, 1, mb, lb, 2048, 2048, inv8);
    comb_mfma<<<dim3(32, 16), 256, 0, stream>>>(
        query, Ksp_h, Ksp_l, mb, lb, spars, 1, strat,
        combined + 1 * PLANE, 2048, 2048, 16, inv8);

    // ---- QUANTUM (rotated raw heads, per-head gate; combined plane 2) ----
    // Vtp still holds split raw value (shared with SPARSE).
    rotate_heads<<<dim3(32, 16), 256, 0, stream>>>(query, Rq, qrot);
    rotate_heads<<<dim3(32, 16), 256, 0, stream>>>(key, Rq, krot);
    split_rm<<<dim3(2048), 256, 0, stream>>>(krot, Ksp_h, Ksp_l, 524288);
    flash_mfma<64><<<dim3(32, 16), 256, 0, stream>>>(
        qrot, Ksp_h, Ksp_l, Vtp_h, Vtp_l, ent, 2,
        weighted, nullptr, strat, 3, 1, mb, lb, 2048, 2048, inv8);
    comb_mfma<<<dim3(32, 16), 256, 0, stream>>>(
        qrot, Ksp_h, Ksp_l, mb, lb, ent, 2, strat,
        combined + 2 * PLANE, 2048, 2048, 16, inv8);

    // ---- LOCAL (proj'd MHA, 8 heads x 128), split-K x2 over keys ----
    for (int sl = 0; sl < 3; ++sl)
        gemm_mfma<<<dim3(32, 16), 256, 0, stream>>>(
            srcs[sl], 1024, Wqkv_loc + (size_t)sl * 1048576, 1024, b_loc + sl * 1024,
            qkv + (size_t)sl * 2097152, 2048, 1024, 1024, nullptr, 0, 0);
    split_rm<<<dim3(2048), 256, 0, stream>>>(qkv + 2097152, Ksp_h, Ksp_l, 524288);
    split_tr<<<dim3(32, 16), 256, 0, stream>>>(qkv + 4194304, Vtp_h, Vtp_l, 2048);
    // partials: z=0 -> AO, z=1 -> GI (GI free until GLOBAL interp)
    flash_mfma<128><<<dim3(32, 8, 2), 256, 0, stream>>>(
        qkv, Ksp_h, Ksp_l, Vtp_h, Vtp_l, nullptr, 0,
        AO, GI, strat, -1, 0, mb, lb, 2048, 2048, inv128);
    combine2<<<dim3(2048), 256, 0, stream>>>(
        AO, GI, mb, lb, AO, strat, -1, 0, 2048);
    gemm_mfma<<<dim3(32, 16), 256, 0, stream>>>(
        AO, 1024, Wo_loc, 1024, bo_loc, LO, 2048, 1024, 1024, nullptr, 0, 0);

    // ---- GLOBAL (strided pool to 256 tokens, 8 heads x 128, interp back) ----
    for (int sl = 0; sl < 3; ++sl)
        gemm_mfma<<<dim3(4, 16), 256, 0, stream>>>(
            srcs[sl], 8192, Wqkv_glb + (size_t)sl * 1048576, 1024, b_glb + sl * 1024,
            gqkv + (size_t)sl * 262144, 256, 1024, 1024, nullptr, 0, 0);
    split_rm<<<dim3(256), 256, 0, stream>>>(gqkv + 262144, gKs_h, gKs_l, 65536);
    split_tr<<<dim3(4, 16), 256, 0, stream>>>(gqkv + 524288, gVt_h, gVt_l, 256);
    flash_mfma<128><<<dim3(4, 8), 256, 0, stream>>>(
        gqkv, gKs_h, gKs_l, gVt_h, gVt_l, nullptr, 0,
        gAO, nullptr, strat, -1, 0, mb, lb, 256, 256, inv128);
    gemm_mfma<<<dim3(4, 16), 256, 0, stream>>>(
        gAO, 1024, Wo_glb, 1024, bo_glb, gOUT, 256, 1024, 1024, nullptr, 0, 0);
    interp_lin<<<dim3(2048), 256, 0, stream>>>(gOUT, GI);

    // ---- HIER: weighted += s2 * (LO @ WfL^T + GI @ WfR^T + bf) ----
    gemm_mfma<<<dim3(32, 16), 256, 0, stream>>>(
        LO, 1024, Wf, 2048, bf, weighted, 2048, 1024, 1024, strat, 2, 1);
    gemm_mfma<<<dim3(32, 16), 256, 0, stream>>>(
        GI, 1024, Wf + 1024, 2048, nullptr, weighted, 2048, 1024, 1024, strat, 2, 1);
}

// Round 4
// 1253.181 us; speedup vs baseline: 1.8962x; 1.0302x over previous
//
#include <hip/hip_runtime.h>
#include <math.h>

// Problem constants: B=1, T=2048, D=1024, H=16, HD=64, STRIDE=8, Tg=256.
// Output 0: weighted [2048][1024]
// Output 1: combined [3][2048][2048] = (s0+s1+s3) * {linear_w, sparse_w, quantum_w}
#define D_MODEL 1024

typedef __attribute__((ext_vector_type(8))) short bf16x8;
typedef __attribute__((ext_vector_type(4))) float f32x4;
typedef __attribute__((ext_vector_type(8))) unsigned short u16x8;

// fp32 -> bf16 RNE, and bf16 -> fp32
__device__ __forceinline__ unsigned short bfr(float f) {
    unsigned u = __float_as_uint(f);
    u += 0x7fffu + ((u >> 16) & 1u);
    return (unsigned short)(u >> 16);
}
__device__ __forceinline__ float bff(unsigned short s) {
    return __uint_as_float(((unsigned)s) << 16);
}
// split x = hi + lo (both bf16); hi*hi+hi*lo+lo*hi captures x*y to ~2^-17 rel
__device__ __forceinline__ void split2(float x, unsigned short &h, unsigned short &l) {
    h = bfr(x);
    l = bfr(x - bff(h));
}
// packed RNE f32x2 -> bf16x2 (low16 = a, high16 = b); identical rounding to bfr
__device__ __forceinline__ unsigned cvtpk(float a, float b) {
    unsigned r;
    asm("v_cvt_pk_bf16_f32 %0, %1, %2" : "=v"(r) : "v"(a), "v"(b));
    return r;
}
__device__ __forceinline__ f32x4 mfma3(bf16x8 ah, bf16x8 al, bf16x8 bh, bf16x8 bl, f32x4 c) {
    c = __builtin_amdgcn_mfma_f32_16x16x32_bf16(ah, bh, c, 0, 0, 0);
    c = __builtin_amdgcn_mfma_f32_16x16x32_bf16(ah, bl, c, 0, 0, 0);
    c = __builtin_amdgcn_mfma_f32_16x16x32_bf16(al, bh, c, 0, 0, 0);
    return c;
}

// ---------------------------------------------------------------------------
// Pre-split kernels: fp32 -> bf16 hi/lo (computed ONCE, reused everywhere).
// ---------------------------------------------------------------------------
__global__ __launch_bounds__(256) void split_rm(
    const float* __restrict__ in, unsigned short* __restrict__ hi,
    unsigned short* __restrict__ lo, int n4)
{
    int idx = blockIdx.x * 256 + threadIdx.x;
    if (idx >= n4) return;
    float4 v = ((const float4*)in)[idx];
    ushort4 hs, ls;
    split2(v.x, hs.x, ls.x); split2(v.y, hs.y, ls.y);
    split2(v.z, hs.z, ls.z); split2(v.w, hs.w, ls.w);
    ((ushort4*)hi)[idx] = hs;
    ((ushort4*)lo)[idx] = ls;
}

// Transposed split: in [T][1024] fp32 -> hi/lo [1024][T] u16 (row = global d).
__global__ __launch_bounds__(256) void split_tr(
    const float* __restrict__ in, unsigned short* __restrict__ hi,
    unsigned short* __restrict__ lo, int T)
{
    __shared__ float xs[64][65];   // [t][d]
    const int t0 = blockIdx.x * 64, d0 = blockIdx.y * 64;
    for (int idx = threadIdx.x; idx < 64 * 16; idx += 256) {
        int r = idx >> 4, c4 = (idx & 15) * 4;
        float4 v = *(const float4*)&in[(size_t)(t0 + r) * D_MODEL + d0 + c4];
        xs[r][c4] = v.x; xs[r][c4 + 1] = v.y; xs[r][c4 + 2] = v.z; xs[r][c4 + 3] = v.w;
    }
    __syncthreads();
    for (int idx = threadIdx.x; idx < 64 * 8; idx += 256) {
        int dd = idx >> 3, t8 = (idx & 7) * 8;
        u16x8 hs, ls;
#pragma unroll
        for (int j = 0; j < 8; ++j) {
            unsigned short hh, ll;
            split2(xs[t8 + j][dd], hh, ll);
            hs[j] = hh; ls[j] = ll;
        }
        *(u16x8*)&hi[(size_t)(d0 + dd) * T + t0 + t8] = hs;
        *(u16x8*)&lo[(size_t)(d0 + dd) * T + t0 + t8] = ls;
    }
}

// ---------------------------------------------------------------------------
// MFMA GEMM: C[M,N] (+)= scale * (X[M,K] @ W[N,K]^T + bias), split-bf16.
// 64x64 tile, 4 waves, register prefetch of next k-step.
// ---------------------------------------------------------------------------
__global__ __launch_bounds__(256) void gemm_mfma(
    const float* __restrict__ X, int xrstride,
    const float* __restrict__ W, int wrstride,
    const float* __restrict__ bias,
    float* __restrict__ C, int M, int N, int K,
    const float* __restrict__ sptr, int sidx, int accum)
{
    __shared__ unsigned short Xh[64][40], Xl[64][40];
    __shared__ unsigned short Wh[64][40], Wl[64][40];
    const int tid = threadIdx.x;
    const int m0 = blockIdx.x * 64, n0 = blockIdx.y * 64;
    const int lane = tid & 63, wave = tid >> 6;
    const int c = lane & 15, quad = lane >> 4;
    const int mbase = wave * 16;

    f32x4 acc[4];
#pragma unroll
    for (int nt = 0; nt < 4; ++nt) acc[nt] = (f32x4){0.f, 0.f, 0.f, 0.f};

    float4 xr[2], wr[2];
    const int r_ = tid >> 3, d4_ = (tid & 7) * 4;
    const int r2_ = (tid + 256) >> 3, d42_ = ((tid + 256) & 7) * 4;
    auto ldXW = [&](int k0) {
        xr[0] = *(const float4*)&X[(size_t)(m0 + r_) * xrstride + k0 + d4_];
        xr[1] = *(const float4*)&X[(size_t)(m0 + r2_) * xrstride + k0 + d42_];
        wr[0] = *(const float4*)&W[(size_t)(n0 + r_) * wrstride + k0 + d4_];
        wr[1] = *(const float4*)&W[(size_t)(n0 + r2_) * wrstride + k0 + d42_];
    };
    ldXW(0);

    for (int k0 = 0; k0 < K; k0 += 32) {
        __syncthreads();
        {
            ushort4 hs, ls;
            split2(xr[0].x, hs.x, ls.x); split2(xr[0].y, hs.y, ls.y);
            split2(xr[0].z, hs.z, ls.z); split2(xr[0].w, hs.w, ls.w);
            *(ushort4*)&Xh[r_][d4_] = hs; *(ushort4*)&Xl[r_][d4_] = ls;
            split2(xr[1].x, hs.x, ls.x); split2(xr[1].y, hs.y, ls.y);
            split2(xr[1].z, hs.z, ls.z); split2(xr[1].w, hs.w, ls.w);
            *(ushort4*)&Xh[r2_][d42_] = hs; *(ushort4*)&Xl[r2_][d42_] = ls;
            split2(wr[0].x, hs.x, ls.x); split2(wr[0].y, hs.y, ls.y);
            split2(wr[0].z, hs.z, ls.z); split2(wr[0].w, hs.w, ls.w);
            *(ushort4*)&Wh[r_][d4_] = hs; *(ushort4*)&Wl[r_][d4_] = ls;
            split2(wr[1].x, hs.x, ls.x); split2(wr[1].y, hs.y, ls.y);
            split2(wr[1].z, hs.z, ls.z); split2(wr[1].w, hs.w, ls.w);
            *(ushort4*)&Wh[r2_][d42_] = hs; *(ushort4*)&Wl[r2_][d42_] = ls;
        }
        __syncthreads();
        if (k0 + 32 < K) ldXW(k0 + 32);
        bf16x8 ah = *(const bf16x8*)&Xh[mbase + c][quad * 8];
        bf16x8 al = *(const bf16x8*)&Xl[mbase + c][quad * 8];
#pragma unroll
        for (int nt = 0; nt < 4; ++nt) {
            bf16x8 bh = *(const bf16x8*)&Wh[nt * 16 + c][quad * 8];
            bf16x8 bl = *(const bf16x8*)&Wl[nt * 16 + c][quad * 8];
            acc[nt] = mfma3(ah, al, bh, bl, acc[nt]);
        }
    }
    const float s = (sptr != nullptr) ? sptr[sidx] : 1.0f;
#pragma unroll
    for (int nt = 0; nt < 4; ++nt) {
#pragma unroll
        for (int reg = 0; reg < 4; ++reg) {
            int row = m0 + mbase + quad * 4 + reg;
            int col = n0 + nt * 16 + c;
            float v = acc[nt][reg] + (bias ? bias[col] : 0.0f);
            v *= s;
            size_t gi = (size_t)row * N + col;
            if (accum) v += C[gi];
            C[gi] = v;
        }
    }
}

// ---------------------------------------------------------------------------
// MFMA flash attention, one block = (head, 64 query rows [, key-split z]).
//   Round-4: SWAPPED QK^T (A=K, B=Q; dot products commute, numerics identical):
//   lane holds S[key=quad*4+reg][q=lane&15] -> each lane owns ONE q-row.
//   - P pack: v_cvt_pk_bf16_f32 pairs -> 2x ds_write_b64 per mt (was 32
//     scalar b16 with 4-way conflicts).
//   - Fast path (defer-max holds): ZERO shuffles per tile; l per-lane,
//     cross-quad reduce once in epilogue.
//   - O accumulator comes out in original orientation; epilogue shfl's l.
//   - Masked heads (amode 1, gate 0): P = constant registers, no LDS.
// ---------------------------------------------------------------------------
template <int HD>
__global__ __launch_bounds__(256) void flash_mfma(
    const float* __restrict__ Q,
    const unsigned short* __restrict__ Khi, const unsigned short* __restrict__ Klo,
    const unsigned short* __restrict__ Vthi, const unsigned short* __restrict__ Vtlo,
    const float* __restrict__ aparam, int amode,
    float* __restrict__ O, float* __restrict__ O2,
    const float* __restrict__ strat, int o_sidx, int accum,
    float* __restrict__ mout, float* __restrict__ lout,
    int Tq, int Tk, float inv_scale)
{
    constexpr int ROWS = 64;
    constexpr int STILE = (HD == 64) ? 64 : 32;
    constexpr int MT   = STILE / 16;   // key m-tiles (swapped)
    constexpr int KS   = HD / 32;      // QK k-steps
    constexpr int NT_O = HD / 16;      // O n-tiles
    constexpr int KS_PV = STILE / 32;  // PV k-steps
    constexpr int QP = HD + 8;         // padded K row length (u16), 16B-aligned
    constexpr int SP = STILE + 8;
    constexpr int KIT = STILE * HD / 8 / 256;   // u16x8 items per thread (K)
    constexpr int VIT = STILE * HD / 8 / 256;   // u16x8 items per thread (V)

    __shared__ __align__(16) unsigned short Kh[STILE][QP], Kl[STILE][QP];
    __shared__ __align__(16) unsigned short Vh[HD][SP],  Vl[HD][SP];
    __shared__ __align__(16) unsigned short Ph[ROWS][SP], Pl[ROWS][SP];

    const int tid = threadIdx.x;
    const int h = blockIdx.y;
    const int r0 = blockIdx.x * ROWS;
    const int lane = tid & 63, wave = tid >> 6;
    const int c = lane & 15, quad = lane >> 4;
    const int mbase = wave * 16;
    const int ZS = gridDim.z;
    const int tkloc = Tk / ZS;
    const int kv0 = blockIdx.z * tkloc;

    float gate = 1.0f;
    if (amode == 1) gate = (aparam[h] > 0.0f) ? 1.0f : 0.0f;
    if (amode == 2) gate = 1.0f / (1.0f + __expf(-aparam[h * 4]));
    const float ascale = gate * inv_scale;
    const bool masked = (amode == 1) && (gate == 0.0f);

    // Q B-fragments straight from global (key-loop invariant, wave-private)
    bf16x8 qah[KS], qal[KS];
    if (!masked) {
        const float* qrow = &Q[(size_t)(r0 + mbase + c) * D_MODEL + h * HD];
#pragma unroll
        for (int ks = 0; ks < KS; ++ks) {
            float4 a  = *(const float4*)(qrow + ks * 32 + quad * 8);
            float4 b2 = *(const float4*)(qrow + ks * 32 + quad * 8 + 4);
            unsigned short hh, ll;
            split2(a.x, hh, ll);  qah[ks][0] = (short)hh; qal[ks][0] = (short)ll;
            split2(a.y, hh, ll);  qah[ks][1] = (short)hh; qal[ks][1] = (short)ll;
            split2(a.z, hh, ll);  qah[ks][2] = (short)hh; qal[ks][2] = (short)ll;
            split2(a.w, hh, ll);  qah[ks][3] = (short)hh; qal[ks][3] = (short)ll;
            split2(b2.x, hh, ll); qah[ks][4] = (short)hh; qal[ks][4] = (short)ll;
            split2(b2.y, hh, ll); qah[ks][5] = (short)hh; qal[ks][5] = (short)ll;
            split2(b2.z, hh, ll); qah[ks][6] = (short)hh; qal[ks][6] = (short)ll;
            split2(b2.w, hh, ll); qah[ks][7] = (short)hh; qal[ks][7] = (short)ll;
        }
    }

    float mreg = -1e30f, lacc = 0.0f;   // per-lane: row q = mbase + c
    f32x4 oacc[NT_O];
#pragma unroll
    for (int nt = 0; nt < NT_O; ++nt) oacc[nt] = (f32x4){0.f, 0.f, 0.f, 0.f};

    // masked: P == 1.0 uniform, in registers only
    bf16x8 pone, pzero;
#pragma unroll
    for (int j = 0; j < 8; ++j) { pone[j] = (short)0x3F80; pzero[j] = 0; }

    u16x8 krh[KIT], krl[KIT], vrh[VIT], vrl[VIT];

    auto load_regs = [&](int s0) {
        if (!masked) {
#pragma unroll
            for (int it = 0; it < KIT; ++it) {
                int idx = tid + it * 256;
                int r = idx / (HD / 8), c8 = (idx % (HD / 8)) * 8;
                size_t go = (size_t)(s0 + r) * D_MODEL + h * HD + c8;
                krh[it] = *(const u16x8*)&Khi[go];
                krl[it] = *(const u16x8*)&Klo[go];
            }
        }
#pragma unroll
        for (int it = 0; it < VIT; ++it) {
            int idx = tid + it * 256;
            int d = idx % HD, s8 = (idx / HD) * 8;
            size_t go = (size_t)(h * HD + d) * Tk + s0 + s8;
            vrh[it] = *(const u16x8*)&Vthi[go];
            vrl[it] = *(const u16x8*)&Vtlo[go];
        }
    };
    auto write_bufs = [&]() {
        if (!masked) {
#pragma unroll
            for (int it = 0; it < KIT; ++it) {
                int idx = tid + it * 256;
                int r = idx / (HD / 8), c8 = (idx % (HD / 8)) * 8;
                *(u16x8*)&Kh[r][c8] = krh[it];
                *(u16x8*)&Kl[r][c8] = krl[it];
            }
        }
#pragma unroll
        for (int it = 0; it < VIT; ++it) {
            int idx = tid + it * 256;
            int d = idx % HD, s8 = (idx / HD) * 8;
            *(u16x8*)&Vh[d][s8] = vrh[it];
            *(u16x8*)&Vl[d][s8] = vrl[it];
        }
    };

    auto compute_tile = [&]() {
        if (!masked) {
            // swapped scores: sf[mt][reg] = S[key=mt*16+quad*4+reg][q=mbase+c]
            f32x4 sf[MT];
#pragma unroll
            for (int mt = 0; mt < MT; ++mt) {
                f32x4 s = (f32x4){0.f, 0.f, 0.f, 0.f};
#pragma unroll
                for (int ks = 0; ks < KS; ++ks) {
                    bf16x8 kh = *(const bf16x8*)&Kh[mt * 16 + c][ks * 32 + quad * 8];
                    bf16x8 kl = *(const bf16x8*)&Kl[mt * 16 + c][ks * 32 + quad * 8];
                    s = mfma3(kh, kl, qah[ks], qal[ks], s);
                }
                sf[mt] = s * ascale;
            }
            // per-lane local max over this quad's keys; rescale only on growth
            float tm = sf[0][0];
#pragma unroll
            for (int mt = 0; mt < MT; ++mt)
#pragma unroll
                for (int reg = 0; reg < 4; ++reg) tm = fmaxf(tm, sf[mt][reg]);
            if (__any(tm > mreg + 8.0f)) {
                tm = fmaxf(tm, __shfl_xor(tm, 16));
                tm = fmaxf(tm, __shfl_xor(tm, 32));
                float nm = fmaxf(mreg, tm);
                float al = __expf(mreg - nm);
                mreg = nm;
                lacc *= al;
                float ar[4];
#pragma unroll
                for (int reg = 0; reg < 4; ++reg)
                    ar[reg] = __shfl(al, (lane & 48) | (quad * 4 + reg));
#pragma unroll
                for (int nt = 0; nt < NT_O; ++nt)
#pragma unroll
                    for (int reg = 0; reg < 4; ++reg) oacc[nt][reg] *= ar[reg];
            }
            // p = exp(s - m) (bounded e^8); pack pairs, b64 write per mt
#pragma unroll
            for (int mt = 0; mt < MT; ++mt) {
                float p0 = __expf(sf[mt][0] - mreg);
                float p1 = __expf(sf[mt][1] - mreg);
                float p2 = __expf(sf[mt][2] - mreg);
                float p3 = __expf(sf[mt][3] - mreg);
                lacc += (p0 + p1) + (p2 + p3);
                unsigned h01 = cvtpk(p0, p1), h23 = cvtpk(p2, p3);
                float b0 = __uint_as_float(h01 << 16);
                float b1 = __uint_as_float(h01 & 0xffff0000u);
                float b2 = __uint_as_float(h23 << 16);
                float b3 = __uint_as_float(h23 & 0xffff0000u);
                unsigned l01 = cvtpk(p0 - b0, p1 - b1);
                unsigned l23 = cvtpk(p2 - b2, p3 - b3);
                uint2 hw; hw.x = h01; hw.y = h23;
                uint2 lw; lw.x = l01; lw.y = l23;
                *(uint2*)&Ph[mbase + c][mt * 16 + quad * 4] = hw;
                *(uint2*)&Pl[mbase + c][mt * 16 + quad * 4] = lw;
            }
        }
        // PV: A[m=q=lane&15][k=key=quad*8+j] = Ph[mbase+c][...] (same-wave LDS)
        bf16x8 pah[KS_PV], pal[KS_PV];
#pragma unroll
        for (int ks = 0; ks < KS_PV; ++ks) {
            if (masked) { pah[ks] = pone; pal[ks] = pzero; }
            else {
                pah[ks] = *(const bf16x8*)&Ph[mbase + c][ks * 32 + quad * 8];
                pal[ks] = *(const bf16x8*)&Pl[mbase + c][ks * 32 + quad * 8];
            }
        }
#pragma unroll
        for (int nt = 0; nt < NT_O; ++nt) {
            f32x4 o = oacc[nt];
#pragma unroll
            for (int ks = 0; ks < KS_PV; ++ks) {
                bf16x8 bh = *(const bf16x8*)&Vh[nt * 16 + c][ks * 32 + quad * 8];
                bf16x8 bl = *(const bf16x8*)&Vl[nt * 16 + c][ks * 32 + quad * 8];
                o = mfma3(pah[ks], pal[ks], bh, bl, o);
            }
            oacc[nt] = o;
        }
    };

    const int NTL = tkloc / STILE;
    load_regs(kv0);
    for (int t = 0; t < NTL; ++t) {
        __syncthreads();                 // prev tile consumed by all waves
        write_bufs();
        __syncthreads();
        if (t + 1 < NTL) load_regs(kv0 + (t + 1) * STILE);
        compute_tile();
    }

    // cross-quad l reduce (deferred from per-tile); row q = mbase + c
    lacc += __shfl_xor(lacc, 16);
    lacc += __shfl_xor(lacc, 32);

    if (ZS == 1) {
        const float osc = (o_sidx >= 0) ? strat[o_sidx] : 1.0f;
        if (quad == 0) {
            int row = r0 + mbase + c;
            mout[h * Tq + row] = masked ? 0.0f : mreg;
            lout[h * Tq + row] = masked ? (float)Tk : lacc;
        }
        float sc[4];
#pragma unroll
        for (int reg = 0; reg < 4; ++reg) {
            float lf = masked ? (float)Tk
                              : __shfl(lacc, (lane & 48) | (quad * 4 + reg));
            sc[reg] = osc / lf;
        }
#pragma unroll
        for (int reg = 0; reg < 4; ++reg) {
            int row = r0 + mbase + quad * 4 + reg;
#pragma unroll
            for (int nt = 0; nt < NT_O; ++nt) {
                size_t gi = (size_t)row * D_MODEL + h * HD + nt * 16 + c;
                float v = sc[reg] * oacc[nt][reg];
                if (accum) v += O[gi];
                O[gi] = v;
            }
        }
    } else {
        float* Op = (blockIdx.z == 0) ? O : O2;
        if (quad == 0) {
            int row = r0 + mbase + c;
            mout[(blockIdx.z * gridDim.y + h) * Tq + row] = masked ? 0.0f : mreg;
            lout[(blockIdx.z * gridDim.y + h) * Tq + row] = masked ? (float)tkloc : lacc;
        }
#pragma unroll
        for (int reg = 0; reg < 4; ++reg) {
            int row = r0 + mbase + quad * 4 + reg;
#pragma unroll
            for (int nt = 0; nt < NT_O; ++nt)
                Op[(size_t)row * D_MODEL + h * HD + nt * 16 + c] = oacc[nt][reg];
        }
    }
}

// ---------------------------------------------------------------------------
// Merge 2 split-K partials (HD=128, H=8): O = osc*(O0*w0+O1*w1)/l (+accum)
// ---------------------------------------------------------------------------
__global__ __launch_bounds__(256) void combine2(
    const float* __restrict__ O0, const float* __restrict__ O1,
    const float* __restrict__ mp, const float* __restrict__ lp,
    float* __restrict__ O, const float* __restrict__ strat,
    int o_sidx, int accum, int Tq)
{
    const int row = blockIdx.x;
    const int c4 = threadIdx.x * 4;
    const int h = c4 >> 7;             // HD=128
    const float m0 = mp[h * Tq + row], m1 = mp[(8 + h) * Tq + row];
    const float l0 = lp[h * Tq + row], l1 = lp[(8 + h) * Tq + row];
    const float m = fmaxf(m0, m1);
    const float w0 = __expf(m0 - m), w1 = __expf(m1 - m);
    const float osc = (o_sidx >= 0) ? strat[o_sidx] : 1.0f;
    const float sc = osc / (l0 * w0 + l1 * w1);
    float4 a = *(const float4*)&O0[(size_t)row * D_MODEL + c4];
    float4 b = *(const float4*)&O1[(size_t)row * D_MODEL + c4];
    size_t gi = (size_t)row * D_MODEL + c4;
    float4 r;
    r.x = sc * (a.x * w0 + b.x * w1);
    r.y = sc * (a.y * w0 + b.y * w1);
    r.z = sc * (a.z * w0 + b.z * w1);
    r.w = sc * (a.w * w0 + b.w * w1);
    if (accum) {
        float4 o = *(const float4*)&O[gi];
        r.x += o.x; r.y += o.y; r.z += o.z; r.w += o.w;
    }
    *(float4*)&O[gi] = r;
}

// ---------------------------------------------------------------------------
// MFMA comb plane: comb[r][c] = csc * (sum_h exp(ascale_h*q_h.k_h - m)/l + unif/Tk)
// Block = 64 rows x 128 cols, loops active heads (HD=64). K and Q pre-split
// (staging and fragments are pure copies); next head's K prefetched.
// ---------------------------------------------------------------------------
__global__ __launch_bounds__(256) void comb_mfma(
    const unsigned short* __restrict__ Qhi, const unsigned short* __restrict__ Qlo,
    const unsigned short* __restrict__ Khi, const unsigned short* __restrict__ Klo,
    const float* __restrict__ mrow, const float* __restrict__ lrow,
    const float* __restrict__ aparam, int amode,
    const float* __restrict__ strat,
    float* __restrict__ comb, int Tq, int Tk, int nh, float inv_scale)
{
    __shared__ __align__(16) unsigned short Kh[128][72], Kl[128][72];
    const int tid = threadIdx.x;
    const int r0 = blockIdx.x * 64, c0 = blockIdx.y * 128;
    const int lane = tid & 63, wave = tid >> 6;
    const int c = lane & 15, quad = lane >> 4;
    const int mbase = wave * 16;

    f32x4 acc[8];
#pragma unroll
    for (int nt = 0; nt < 8; ++nt) acc[nt] = (f32x4){0.f, 0.f, 0.f, 0.f};

    int hlist[16]; float glist[16]; int nact = 0; float unif = 0.0f;
    for (int h = 0; h < nh; ++h) {
        float gate = 1.0f;
        if (amode == 1) gate = (aparam[h] > 0.0f) ? 1.0f : 0.0f;
        if (amode == 2) gate = 1.0f / (1.0f + __expf(-aparam[h * 4]));
        if (amode == 1 && gate == 0.0f) { unif += 1.0f; continue; }
        hlist[nact] = h; glist[nact] = gate * inv_scale; ++nact;
    }

    u16x8 krh[4], krl[4];
    auto loadK = [&](int h) {
#pragma unroll
        for (int it = 0; it < 4; ++it) {
            int idx = tid + it * 256;
            int r = idx >> 3, c8 = (idx & 7) * 8;
            size_t go = (size_t)(c0 + r) * D_MODEL + h * 64 + c8;
            krh[it] = *(const u16x8*)&Khi[go];
            krl[it] = *(const u16x8*)&Klo[go];
        }
    };
    if (nact > 0) loadK(hlist[0]);

    for (int i = 0; i < nact; ++i) {
        const int h = hlist[i];
        const float ascale = glist[i];
        __syncthreads();   // previous head's K fully consumed
#pragma unroll
        for (int it = 0; it < 4; ++it) {
            int idx = tid + it * 256;
            int r = idx >> 3, c8 = (idx & 7) * 8;
            *(u16x8*)&Kh[r][c8] = krh[it];
            *(u16x8*)&Kl[r][c8] = krl[it];
        }
        __syncthreads();
        if (i + 1 < nact) loadK(hlist[i + 1]);   // prefetch next head

        // Q fragments: pure vector loads from pre-split
        bf16x8 qah[2], qal[2];
        const unsigned short* qh = &Qhi[(size_t)(r0 + mbase + c) * D_MODEL + h * 64];
        const unsigned short* ql = &Qlo[(size_t)(r0 + mbase + c) * D_MODEL + h * 64];
#pragma unroll
        for (int ks = 0; ks < 2; ++ks) {
            qah[ks] = *(const bf16x8*)(qh + ks * 32 + quad * 8);
            qal[ks] = *(const bf16x8*)(ql + ks * 32 + quad * 8);
        }

        float mr[4], li[4];
#pragma unroll
        for (int reg = 0; reg < 4; ++reg) {
            int row = r0 + mbase + quad * 4 + reg;
            mr[reg] = mrow[h * Tq + row];
            li[reg] = 1.0f / lrow[h * Tq + row];
        }
#pragma unroll
        for (int nt = 0; nt < 8; ++nt) {
            f32x4 s = (f32x4){0.f, 0.f, 0.f, 0.f};
#pragma unroll
            for (int ks = 0; ks < 2; ++ks) {
                bf16x8 bh = *(const bf16x8*)&Kh[nt * 16 + c][ks * 32 + quad * 8];
                bf16x8 bl = *(const bf16x8*)&Kl[nt * 16 + c][ks * 32 + quad * 8];
                s = mfma3(qah[ks], qal[ks], bh, bl, s);
            }
#pragma unroll
            for (int reg = 0; reg < 4; ++reg)
                acc[nt][reg] += __expf(s[reg] * ascale - mr[reg]) * li[reg];
        }
    }
    const float csc = (strat[0] + strat[1] + strat[3]) / (float)nh;
    const float uadd = unif / (float)Tk;
#pragma unroll
    for (int nt = 0; nt < 8; ++nt) {
#pragma unroll
        for (int reg = 0; reg < 4; ++reg) {
            int row = r0 + mbase + quad * 4 + reg;
            comb[(size_t)row * Tk + c0 + nt * 16 + c] = csc * (acc[nt][reg] + uadd);
        }
    }
}

// ---------------------------------------------------------------------------
// Per-head 64x64 rotation (fp32, small): Y[t][h*64+e] = sum_d X[t][h*64+d]*R[h][d][e]
// ---------------------------------------------------------------------------
__global__ __launch_bounds__(256) void rotate_heads(
    const float* __restrict__ X, const float* __restrict__ R,
    float* __restrict__ Y)
{
    __shared__ float Rt[64][68];
    __shared__ float xs[64][68];
    const int tid = threadIdx.x;
    const int h = blockIdx.y;
    const int t0 = blockIdx.x * 64;
    for (int idx = tid; idx < 4096; idx += 256) {
        int d = idx >> 6, e = idx & 63;
        Rt[e][d] = R[h * 4096 + idx];
        xs[d][e] = X[(size_t)(t0 + d) * D_MODEL + h * 64 + e];
    }
    __syncthreads();
    const int ty = tid >> 4, tx = tid & 15;
    float acc[4][4] = {};
#pragma unroll 4
    for (int d0 = 0; d0 < 64; d0 += 4) {
        float4 rv[4];
#pragma unroll
        for (int j = 0; j < 4; ++j) rv[j] = *(const float4*)&Rt[tx * 4 + j][d0];
#pragma unroll
        for (int i = 0; i < 4; ++i) {
            float4 a = *(const float4*)&xs[ty * 4 + i][d0];
#pragma unroll
            for (int j = 0; j < 4; ++j)
                acc[i][j] += a.x * rv[j].x + a.y * rv[j].y + a.z * rv[j].z + a.w * rv[j].w;
        }
    }
#pragma unroll
    for (int i = 0; i < 4; ++i)
#pragma unroll
        for (int j = 0; j < 4; ++j)
            Y[(size_t)(t0 + ty * 4 + i) * D_MODEL + h * 64 + tx * 4 + j] = acc[i][j];
}

// ---------------------------------------------------------------------------
// F.interpolate(mode='linear', align_corners=False): [256,1024] -> [2048,1024]
// ---------------------------------------------------------------------------
__global__ __launch_bounds__(256) void interp_lin(
    const float* __restrict__ G, float* __restrict__ out)
{
    const int t = blockIdx.x;
    float src = (t + 0.5f) * 0.125f - 0.5f;
    src = fminf(fmaxf(src, 0.0f), 255.0f);
    float fl = floorf(src);
    int i0 = (int)fl;
    int i1 = min(i0 + 1, 255);
    float w = src - fl;
    const float4* g0 = (const float4*)(G + (size_t)i0 * D_MODEL);
    const float4* g1 = (const float4*)(G + (size_t)i1 * D_MODEL);
    float4* o = (float4*)(out + (size_t)t * D_MODEL);
    int c = threadIdx.x;
    float4 a = g0[c], b = g1[c];
    float4 r;
    r.x = a.x * (1.0f - w) + b.x * w;
    r.y = a.y * (1.0f - w) + b.y * w;
    r.z = a.z * (1.0f - w) + b.z * w;
    r.w = a.w * (1.0f - w) + b.w * w;
    o[c] = r;
}

// ---------------------------------------------------------------------------
extern "C" void kernel_launch(void* const* d_in, const int* in_sizes, int n_in,
                              void* d_out, int out_size, void* d_ws, size_t ws_size,
                              hipStream_t stream)
{
    (void)in_sizes; (void)n_in; (void)ws_size; (void)out_size;
    const float* query    = (const float*)d_in[0];
    const float* key      = (const float*)d_in[1];
    const float* value    = (const float*)d_in[2];
    const float* strat    = (const float*)d_in[3];
    const float* Wqkv_lin = (const float*)d_in[4];
    const float* b_lin    = (const float*)d_in[5];
    const float* Wo_lin   = (const float*)d_in[6];
    const float* bo_lin   = (const float*)d_in[7];
    const float* spars    = (const float*)d_in[8];
    const float* Wqkv_loc = (const float*)d_in[9];
    const float* b_loc    = (const float*)d_in[10];
    const float* Wo_loc   = (const float*)d_in[11];
    const float* bo_loc   = (const float*)d_in[12];
    const float* Wqkv_glb = (const float*)d_in[13];
    const float* b_glb    = (const float*)d_in[14];
    const float* Wo_glb   = (const float*)d_in[15];
    const float* bo_glb   = (const float*)d_in[16];
    const float* Wf       = (const float*)d_in[17];
    const float* bf       = (const float*)d_in[18];
    const float* Rq       = (const float*)d_in[19];
    const float* ent      = (const float*)d_in[20];

    float* out = (float*)d_out;
    float* weighted = out;                        // [2048][1024]
    float* combined = out + (size_t)2048 * 1024;  // [3][2048][2048]
    const size_t PLANE = (size_t)2048 * 2048;

    float* ws   = (float*)d_ws;
    float* qkv  = ws;                   // 3 x 2048x1024
    float* AO   = qkv + 6291456;
    float* LO   = AO + 2097152;
    float* gqkv = LO + 2097152;
    float* gAO  = gqkv + 786432;
    float* gOUT = gAO + 262144;
    float* GI   = gOUT + 262144;
    float* mb   = GI + 2097152;
    float* lb   = mb + 32768;
    float* qrot = qkv;                  // alias: lin qkv dead by then
    float* krot = qkv + 2097152;
    // pre-split bf16 hi/lo buffers (u16), after lb
    unsigned short* Ksp_h = (unsigned short*)(lb + 32768);  // [2048][1024]
    unsigned short* Ksp_l = Ksp_h + 2097152;
    unsigned short* Vtp_h = Ksp_l + 2097152;                // [1024][2048]
    unsigned short* Vtp_l = Vtp_h + 2097152;
    unsigned short* gKs_h = Vtp_l + 2097152;                // [256][1024]
    unsigned short* gKs_l = gKs_h + 262144;
    unsigned short* gVt_h = gKs_l + 262144;                 // [1024][256]
    unsigned short* gVt_l = gVt_h + 262144;
    // Q pre-split for comb lives in GI (free until LOCAL's O2 partial)
    unsigned short* Qsp_h = (unsigned short*)GI;            // [2048][1024]
    unsigned short* Qsp_l = Qsp_h + 2097152;

    const float inv8   = 0.125f;
    const float inv128 = 1.0f / sqrtf(128.0f);
    const float* srcs[3] = {query, key, value};

    hipMemsetAsync(weighted, 0, (size_t)2097152 * sizeof(float), stream);

    // ---- LINEAR (proj'd MHA, 16 heads; combined plane 0) ----
    for (int sl = 0; sl < 3; ++sl)
        gemm_mfma<<<dim3(32, 16), 256, 0, stream>>>(
            srcs[sl], 1024, Wqkv_lin + (size_t)sl * 1048576, 1024, b_lin + sl * 1024,
            qkv + (size_t)sl * 2097152, 2048, 1024, 1024, nullptr, 0, 0);
    split_rm<<<dim3(2048), 256, 0, stream>>>(qkv + 2097152, Ksp_h, Ksp_l, 524288);
    split_tr<<<dim3(32, 16), 256, 0, stream>>>(qkv + 4194304, Vtp_h, Vtp_l, 2048);
    flash_mfma<64><<<dim3(32, 16), 256, 0, stream>>>(
        qkv, Ksp_h, Ksp_l, Vtp_h, Vtp_l, nullptr, 0,
        AO, nullptr, strat, -1, 0, mb, lb, 2048, 2048, inv8);
    split_rm<<<dim3(2048), 256, 0, stream>>>(qkv, Qsp_h, Qsp_l, 524288);
    comb_mfma<<<dim3(32, 16), 256, 0, stream>>>(
        Qsp_h, Qsp_l, Ksp_h, Ksp_l, mb, lb, nullptr, 0, strat,
        combined + 0 * PLANE, 2048, 2048, 16, inv8);
    gemm_mfma<<<dim3(32, 16), 256, 0, stream>>>(
        AO, 1024, Wo_lin, 1024, bo_lin, weighted, 2048, 1024, 1024, strat, 0, 1);

    // ---- SPARSE (raw heads, per-head mask; combined plane 1) ----
    split_rm<<<dim3(2048), 256, 0, stream>>>(key, Ksp_h, Ksp_l, 524288);
    split_tr<<<dim3(32, 16), 256, 0, stream>>>(value, Vtp_h, Vtp_l, 2048);
    flash_mfma<64><<<dim3(32, 16), 256, 0, stream>>>(
        query, Ksp_h, Ksp_l, Vtp_h, Vtp_l, spars, 1,
        weighted, nullptr, strat, 1, 1, mb, lb, 2048, 2048, inv8);
    split_rm<<<dim3(2048), 256, 0, stream>>>(query, Qsp_h, Qsp_l, 524288);
    comb_mfma<<<dim3(32, 16), 256, 0, stream>>>(
        Qsp_h, Qsp_l, Ksp_h, Ksp_l, mb, lb, spars, 1, strat,
        combined + 1 * PLANE, 2048, 2048, 16, inv8);

    // ---- QUANTUM (rotated raw heads, per-head gate; combined plane 2) ----
    // Vtp still holds split raw value (shared with SPARSE).
    rotate_heads<<<dim3(32, 16), 256, 0, stream>>>(query, Rq, qrot);
    rotate_heads<<<dim3(32, 16), 256, 0, stream>>>(key, Rq, krot);
    split_rm<<<dim3(2048), 256, 0, stream>>>(krot, Ksp_h, Ksp_l, 524288);
    flash_mfma<64><<<dim3(32, 16), 256, 0, stream>>>(
        qrot, Ksp_h, Ksp_l, Vtp_h, Vtp_l, ent, 2,
        weighted, nullptr, strat, 3, 1, mb, lb, 2048, 2048, inv8);
    split_rm<<<dim3(2048), 256, 0, stream>>>(qrot, Qsp_h, Qsp_l, 524288);
    comb_mfma<<<dim3(32, 16), 256, 0, stream>>>(
        Qsp_h, Qsp_l, Ksp_h, Ksp_l, mb, lb, ent, 2, strat,
        combined + 2 * PLANE, 2048, 2048, 16, inv8);

    // ---- LOCAL (proj'd MHA, 8 heads x 128), split-K x2 over keys ----
    for (int sl = 0; sl < 3; ++sl)
        gemm_mfma<<<dim3(32, 16), 256, 0, stream>>>(
            srcs[sl], 1024, Wqkv_loc + (size_t)sl * 1048576, 1024, b_loc + sl * 1024,
            qkv + (size_t)sl * 2097152, 2048, 1024, 1024, nullptr, 0, 0);
    split_rm<<<dim3(2048), 256, 0, stream>>>(qkv + 2097152, Ksp_h, Ksp_l, 524288);
    split_tr<<<dim3(32, 16), 256, 0, stream>>>(qkv + 4194304, Vtp_h, Vtp_l, 2048);
    // partials: z=0 -> AO, z=1 -> GI (GI free: comb done, interp not yet)
    flash_mfma<128><<<dim3(32, 8, 2), 256, 0, stream>>>(
        qkv, Ksp_h, Ksp_l, Vtp_h, Vtp_l, nullptr, 0,
        AO, GI, strat, -1, 0, mb, lb, 2048, 2048, inv128);
    combine2<<<dim3(2048), 256, 0, stream>>>(
        AO, GI, mb, lb, AO, strat, -1, 0, 2048);
    gemm_mfma<<<dim3(32, 16), 256, 0, stream>>>(
        AO, 1024, Wo_loc, 1024, bo_loc, LO, 2048, 1024, 1024, nullptr, 0, 0);

    // ---- GLOBAL (strided pool to 256 tokens, 8 heads x 128, interp back) ----
    for (int sl = 0; sl < 3; ++sl)
        gemm_mfma<<<dim3(4, 16), 256, 0, stream>>>(
            srcs[sl], 8192, Wqkv_glb + (size_t)sl * 1048576, 1024, b_glb + sl * 1024,
            gqkv + (size_t)sl * 262144, 256, 1024, 1024, nullptr, 0, 0);
    split_rm<<<dim3(256), 256, 0, stream>>>(gqkv + 262144, gKs_h, gKs_l, 65536);
    split_tr<<<dim3(4, 16), 256, 0, stream>>>(gqkv + 524288, gVt_h, gVt_l, 256);
    flash_mfma<128><<<dim3(4, 8), 256, 0, stream>>>(
        gqkv, gKs_h, gKs_l, gVt_h, gVt_l, nullptr, 0,
        gAO, nullptr, strat, -1, 0, mb, lb, 256, 256, inv128);
    gemm_mfma<<<dim3(4, 16), 256, 0, stream>>>(
        gAO, 1024, Wo_glb, 1024, bo_glb, gOUT, 256, 1024, 1024, nullptr, 0, 0);
    interp_lin<<<dim3(2048), 256, 0, stream>>>(gOUT, GI);

    // ---- HIER: weighted += s2 * (LO @ WfL^T + GI @ WfR^T + bf) ----
    gemm_mfma<<<dim3(32, 16), 256, 0, stream>>>(
        LO, 1024, Wf, 2048, bf, weighted, 2048, 1024, 1024, strat, 2, 1);
    gemm_mfma<<<dim3(32, 16), 256, 0, stream>>>(
        GI, 1024, Wf + 1024, 2048, nullptr, weighted, 2048, 1024, 1024, strat, 2, 1);
}

// Round 5
// 1077.565 us; speedup vs baseline: 2.2052x; 1.1630x over previous
//
#include <hip/hip_runtime.h>
#include <math.h>

// Problem constants: B=1, T=2048, D=1024, H=16, HD=64, STRIDE=8, Tg=256.
// Output 0: weighted [2048][1024]
// Output 1: combined [3][2048][2048] = (s0+s1+s3) * {linear_w, sparse_w, quantum_w}
#define D_MODEL 1024

typedef __attribute__((ext_vector_type(8))) short bf16x8;
typedef __attribute__((ext_vector_type(4))) float f32x4;
typedef __attribute__((ext_vector_type(8))) unsigned short u16x8;

// fp32 -> bf16 RNE, and bf16 -> fp32
__device__ __forceinline__ unsigned short bfr(float f) {
    unsigned u = __float_as_uint(f);
    u += 0x7fffu + ((u >> 16) & 1u);
    return (unsigned short)(u >> 16);
}
__device__ __forceinline__ float bff(unsigned short s) {
    return __uint_as_float(((unsigned)s) << 16);
}
// split x = hi + lo (both bf16); hi*hi+hi*lo+lo*hi captures x*y to ~2^-17 rel
__device__ __forceinline__ void split2(float x, unsigned short &h, unsigned short &l) {
    h = bfr(x);
    l = bfr(x - bff(h));
}
// packed RNE f32x2 -> bf16x2 (low16 = a, high16 = b); identical rounding to bfr
__device__ __forceinline__ unsigned cvtpk(float a, float b) {
    unsigned r;
    asm("v_cvt_pk_bf16_f32 %0, %1, %2" : "=v"(r) : "v"(a), "v"(b));
    return r;
}
__device__ __forceinline__ f32x4 mfma3(bf16x8 ah, bf16x8 al, bf16x8 bh, bf16x8 bl, f32x4 c) {
    c = __builtin_amdgcn_mfma_f32_16x16x32_bf16(ah, bh, c, 0, 0, 0);
    c = __builtin_amdgcn_mfma_f32_16x16x32_bf16(ah, bl, c, 0, 0, 0);
    c = __builtin_amdgcn_mfma_f32_16x16x32_bf16(al, bh, c, 0, 0, 0);
    return c;
}

// ---------------------------------------------------------------------------
// Pre-split kernels: fp32 -> bf16 hi/lo (computed ONCE, reused everywhere).
// ---------------------------------------------------------------------------
__global__ __launch_bounds__(256) void split_rm(
    const float* __restrict__ in, unsigned short* __restrict__ hi,
    unsigned short* __restrict__ lo, int n4)
{
    int idx = blockIdx.x * 256 + threadIdx.x;
    if (idx >= n4) return;
    float4 v = ((const float4*)in)[idx];
    ushort4 hs, ls;
    split2(v.x, hs.x, ls.x); split2(v.y, hs.y, ls.y);
    split2(v.z, hs.z, ls.z); split2(v.w, hs.w, ls.w);
    ((ushort4*)hi)[idx] = hs;
    ((ushort4*)lo)[idx] = ls;
}

// Transposed split: in [T][1024] fp32 -> hi/lo [1024][T] u16 (row = global d).
__global__ __launch_bounds__(256) void split_tr(
    const float* __restrict__ in, unsigned short* __restrict__ hi,
    unsigned short* __restrict__ lo, int T)
{
    __shared__ float xs[64][65];   // [t][d]
    const int t0 = blockIdx.x * 64, d0 = blockIdx.y * 64;
    for (int idx = threadIdx.x; idx < 64 * 16; idx += 256) {
        int r = idx >> 4, c4 = (idx & 15) * 4;
        float4 v = *(const float4*)&in[(size_t)(t0 + r) * D_MODEL + d0 + c4];
        xs[r][c4] = v.x; xs[r][c4 + 1] = v.y; xs[r][c4 + 2] = v.z; xs[r][c4 + 3] = v.w;
    }
    __syncthreads();
    for (int idx = threadIdx.x; idx < 64 * 8; idx += 256) {
        int dd = idx >> 3, t8 = (idx & 7) * 8;
        u16x8 hs, ls;
#pragma unroll
        for (int j = 0; j < 8; ++j) {
            unsigned short hh, ll;
            split2(xs[t8 + j][dd], hh, ll);
            hs[j] = hh; ls[j] = ll;
        }
        *(u16x8*)&hi[(size_t)(d0 + dd) * T + t0 + t8] = hs;
        *(u16x8*)&lo[(size_t)(d0 + dd) * T + t0 + t8] = ls;
    }
}

// ---------------------------------------------------------------------------
// MFMA GEMM: C[M,N] (+)= scale * (X[M,K] @ W[N,K]^T + bias), split-bf16.
// 64x64 tile, 4 waves, register prefetch of next k-step.
// Round-5: z-batched over up to 3 independent (X, W-slice, bias, C-slice)
// problems to raise blocks-in-flight (QKV projections).
// ---------------------------------------------------------------------------
__global__ __launch_bounds__(256) void gemm_mfma(
    const float* __restrict__ X0, const float* __restrict__ X1,
    const float* __restrict__ X2, int xrstride,
    const float* __restrict__ W, size_t wz, int wrstride,
    const float* __restrict__ bias, int bz,
    float* __restrict__ C, size_t cz, int M, int N, int K,
    const float* __restrict__ sptr, int sidx, int accum)
{
    const int z = blockIdx.z;
    const float* X = (z == 0) ? X0 : (z == 1 ? X1 : X2);
    W += (size_t)z * wz;
    if (bias) bias += z * bz;
    C += (size_t)z * cz;

    __shared__ unsigned short Xh[64][40], Xl[64][40];
    __shared__ unsigned short Wh[64][40], Wl[64][40];
    const int tid = threadIdx.x;
    const int m0 = blockIdx.x * 64, n0 = blockIdx.y * 64;
    const int lane = tid & 63, wave = tid >> 6;
    const int c = lane & 15, quad = lane >> 4;
    const int mbase = wave * 16;

    f32x4 acc[4];
#pragma unroll
    for (int nt = 0; nt < 4; ++nt) acc[nt] = (f32x4){0.f, 0.f, 0.f, 0.f};

    float4 xr[2], wr[2];
    const int r_ = tid >> 3, d4_ = (tid & 7) * 4;
    const int r2_ = (tid + 256) >> 3, d42_ = ((tid + 256) & 7) * 4;
    auto ldXW = [&](int k0) {
        xr[0] = *(const float4*)&X[(size_t)(m0 + r_) * xrstride + k0 + d4_];
        xr[1] = *(const float4*)&X[(size_t)(m0 + r2_) * xrstride + k0 + d42_];
        wr[0] = *(const float4*)&W[(size_t)(n0 + r_) * wrstride + k0 + d4_];
        wr[1] = *(const float4*)&W[(size_t)(n0 + r2_) * wrstride + k0 + d42_];
    };
    ldXW(0);

    for (int k0 = 0; k0 < K; k0 += 32) {
        __syncthreads();
        {
            ushort4 hs, ls;
            split2(xr[0].x, hs.x, ls.x); split2(xr[0].y, hs.y, ls.y);
            split2(xr[0].z, hs.z, ls.z); split2(xr[0].w, hs.w, ls.w);
            *(ushort4*)&Xh[r_][d4_] = hs; *(ushort4*)&Xl[r_][d4_] = ls;
            split2(xr[1].x, hs.x, ls.x); split2(xr[1].y, hs.y, ls.y);
            split2(xr[1].z, hs.z, ls.z); split2(xr[1].w, hs.w, ls.w);
            *(ushort4*)&Xh[r2_][d42_] = hs; *(ushort4*)&Xl[r2_][d42_] = ls;
            split2(wr[0].x, hs.x, ls.x); split2(wr[0].y, hs.y, ls.y);
            split2(wr[0].z, hs.z, ls.z); split2(wr[0].w, hs.w, ls.w);
            *(ushort4*)&Wh[r_][d4_] = hs; *(ushort4*)&Wl[r_][d4_] = ls;
            split2(wr[1].x, hs.x, ls.x); split2(wr[1].y, hs.y, ls.y);
            split2(wr[1].z, hs.z, ls.z); split2(wr[1].w, hs.w, ls.w);
            *(ushort4*)&Wh[r2_][d42_] = hs; *(ushort4*)&Wl[r2_][d42_] = ls;
        }
        __syncthreads();
        if (k0 + 32 < K) ldXW(k0 + 32);
        bf16x8 ah = *(const bf16x8*)&Xh[mbase + c][quad * 8];
        bf16x8 al = *(const bf16x8*)&Xl[mbase + c][quad * 8];
#pragma unroll
        for (int nt = 0; nt < 4; ++nt) {
            bf16x8 bh = *(const bf16x8*)&Wh[nt * 16 + c][quad * 8];
            bf16x8 bl = *(const bf16x8*)&Wl[nt * 16 + c][quad * 8];
            acc[nt] = mfma3(ah, al, bh, bl, acc[nt]);
        }
    }
    const float s = (sptr != nullptr) ? sptr[sidx] : 1.0f;
#pragma unroll
    for (int nt = 0; nt < 4; ++nt) {
#pragma unroll
        for (int reg = 0; reg < 4; ++reg) {
            int row = m0 + mbase + quad * 4 + reg;
            int col = n0 + nt * 16 + c;
            float v = acc[nt][reg] + (bias ? bias[col] : 0.0f);
            v *= s;
            size_t gi = (size_t)row * N + col;
            if (accum) v += C[gi];
            C[gi] = v;
        }
    }
}

// ---------------------------------------------------------------------------
// MFMA flash attention, one block = (head, 64 query rows [, key-split z]).
//   Round-5: HD=64 path uses unpadded XOR-swizzled LDS (16B-chunk index ^=
//   row&7): bank behavior ~= padded (2-way worst) but 49,152 B -> 3 blocks/CU.
//   Split-K (gridDim.z) now used for HD=64 too; partials unnormalized,
//   (m,l) at [(z*NH+h)*Tq+row], merged by combineK.
//   Swapped QK^T (A=K, B=Q); lane owns one q-row; defer-max; cvt_pk P-pack.
//   Masked heads (amode 1, gate 0): P = constant registers, no LDS P.
// ---------------------------------------------------------------------------
template <int HD>
__global__ __launch_bounds__(256) void flash_mfma(
    const float* __restrict__ Q,
    const unsigned short* __restrict__ Khi, const unsigned short* __restrict__ Klo,
    const unsigned short* __restrict__ Vthi, const unsigned short* __restrict__ Vtlo,
    const float* __restrict__ aparam, int amode,
    float* __restrict__ O, float* __restrict__ O2,
    const float* __restrict__ strat, int o_sidx, int accum,
    float* __restrict__ mout, float* __restrict__ lout,
    int Tq, int Tk, float inv_scale)
{
    constexpr int ROWS = 64;
    constexpr int STILE = (HD == 64) ? 64 : 32;
    constexpr int MT   = STILE / 16;   // key m-tiles (swapped)
    constexpr int KS   = HD / 32;      // QK k-steps
    constexpr int NT_O = HD / 16;      // O n-tiles
    constexpr int KS_PV = STILE / 32;  // PV k-steps
    constexpr bool SWZ = (HD == 64);   // swizzled unpadded LDS
    constexpr int KPITCH = SWZ ? HD : HD + 8;
    constexpr int VPITCH = SWZ ? STILE : STILE + 8;
    constexpr int KIT = STILE * HD / 8 / 256;   // u16x8 items per thread (K)
    constexpr int VIT = STILE * HD / 8 / 256;   // u16x8 items per thread (V)

    __shared__ __align__(16) unsigned short Kh[STILE * KPITCH], Kl[STILE * KPITCH];
    __shared__ __align__(16) unsigned short Vh[HD * VPITCH],  Vl[HD * VPITCH];
    __shared__ __align__(16) unsigned short Ph[ROWS * VPITCH], Pl[ROWS * VPITCH];

    // index helpers: 16B-chunk XOR swizzle when SWZ (row length 64 u16, 8 chunks)
    auto KIX = [](int r, int cc) {
        return SWZ ? r * HD + ((cc & 7) | ((((cc >> 3) ^ r) & 7) << 3))
                   : r * KPITCH + cc;
    };
    auto VIX = [](int d, int s) {
        return SWZ ? d * STILE + ((s & 7) | ((((s >> 3) ^ d) & 7) << 3))
                   : d * VPITCH + s;
    };
    auto PIX = [](int r, int cc) {
        return SWZ ? r * STILE + ((cc & 7) | ((((cc >> 3) ^ r) & 7) << 3))
                   : r * VPITCH + cc;
    };

    const int tid = threadIdx.x;
    const int h = blockIdx.y;
    const int r0 = blockIdx.x * ROWS;
    const int lane = tid & 63, wave = tid >> 6;
    const int c = lane & 15, quad = lane >> 4;
    const int mbase = wave * 16;
    const int ZS = gridDim.z;
    const int tkloc = Tk / ZS;
    const int kv0 = blockIdx.z * tkloc;

    float gate = 1.0f;
    if (amode == 1) gate = (aparam[h] > 0.0f) ? 1.0f : 0.0f;
    if (amode == 2) gate = 1.0f / (1.0f + __expf(-aparam[h * 4]));
    const float ascale = gate * inv_scale;
    const bool masked = (amode == 1) && (gate == 0.0f);

    // Q B-fragments straight from global (key-loop invariant, wave-private)
    bf16x8 qah[KS], qal[KS];
    if (!masked) {
        const float* qrow = &Q[(size_t)(r0 + mbase + c) * D_MODEL + h * HD];
#pragma unroll
        for (int ks = 0; ks < KS; ++ks) {
            float4 a  = *(const float4*)(qrow + ks * 32 + quad * 8);
            float4 b2 = *(const float4*)(qrow + ks * 32 + quad * 8 + 4);
            unsigned short hh, ll;
            split2(a.x, hh, ll);  qah[ks][0] = (short)hh; qal[ks][0] = (short)ll;
            split2(a.y, hh, ll);  qah[ks][1] = (short)hh; qal[ks][1] = (short)ll;
            split2(a.z, hh, ll);  qah[ks][2] = (short)hh; qal[ks][2] = (short)ll;
            split2(a.w, hh, ll);  qah[ks][3] = (short)hh; qal[ks][3] = (short)ll;
            split2(b2.x, hh, ll); qah[ks][4] = (short)hh; qal[ks][4] = (short)ll;
            split2(b2.y, hh, ll); qah[ks][5] = (short)hh; qal[ks][5] = (short)ll;
            split2(b2.z, hh, ll); qah[ks][6] = (short)hh; qal[ks][6] = (short)ll;
            split2(b2.w, hh, ll); qah[ks][7] = (short)hh; qal[ks][7] = (short)ll;
        }
    }

    float mreg = -1e30f, lacc = 0.0f;   // per-lane: row q = mbase + c
    f32x4 oacc[NT_O];
#pragma unroll
    for (int nt = 0; nt < NT_O; ++nt) oacc[nt] = (f32x4){0.f, 0.f, 0.f, 0.f};

    // masked: P == 1.0 uniform, in registers only
    bf16x8 pone, pzero;
#pragma unroll
    for (int j = 0; j < 8; ++j) { pone[j] = (short)0x3F80; pzero[j] = 0; }

    u16x8 krh[KIT], krl[KIT], vrh[VIT], vrl[VIT];

    auto load_regs = [&](int s0) {
        if (!masked) {
#pragma unroll
            for (int it = 0; it < KIT; ++it) {
                int idx = tid + it * 256;
                int r = idx / (HD / 8), c8 = (idx % (HD / 8)) * 8;
                size_t go = (size_t)(s0 + r) * D_MODEL + h * HD + c8;
                krh[it] = *(const u16x8*)&Khi[go];
                krl[it] = *(const u16x8*)&Klo[go];
            }
        }
#pragma unroll
        for (int it = 0; it < VIT; ++it) {
            int idx = tid + it * 256;
            int d = idx % HD, s8 = (idx / HD) * 8;
            size_t go = (size_t)(h * HD + d) * Tk + s0 + s8;
            vrh[it] = *(const u16x8*)&Vthi[go];
            vrl[it] = *(const u16x8*)&Vtlo[go];
        }
    };
    auto write_bufs = [&]() {
        if (!masked) {
#pragma unroll
            for (int it = 0; it < KIT; ++it) {
                int idx = tid + it * 256;
                int r = idx / (HD / 8), c8 = (idx % (HD / 8)) * 8;
                *(u16x8*)&Kh[KIX(r, c8)] = krh[it];
                *(u16x8*)&Kl[KIX(r, c8)] = krl[it];
            }
        }
#pragma unroll
        for (int it = 0; it < VIT; ++it) {
            int idx = tid + it * 256;
            int d = idx % HD, s8 = (idx / HD) * 8;
            *(u16x8*)&Vh[VIX(d, s8)] = vrh[it];
            *(u16x8*)&Vl[VIX(d, s8)] = vrl[it];
        }
    };

    auto compute_tile = [&]() {
        if (!masked) {
            // swapped scores: sf[mt][reg] = S[key=mt*16+quad*4+reg][q=mbase+c]
            f32x4 sf[MT];
#pragma unroll
            for (int mt = 0; mt < MT; ++mt) {
                f32x4 s = (f32x4){0.f, 0.f, 0.f, 0.f};
#pragma unroll
                for (int ks = 0; ks < KS; ++ks) {
                    bf16x8 kh = *(const bf16x8*)&Kh[KIX(mt * 16 + c, ks * 32 + quad * 8)];
                    bf16x8 kl = *(const bf16x8*)&Kl[KIX(mt * 16 + c, ks * 32 + quad * 8)];
                    s = mfma3(kh, kl, qah[ks], qal[ks], s);
                }
                sf[mt] = s * ascale;
            }
            // per-lane local max over this quad's keys; rescale only on growth
            float tm = sf[0][0];
#pragma unroll
            for (int mt = 0; mt < MT; ++mt)
#pragma unroll
                for (int reg = 0; reg < 4; ++reg) tm = fmaxf(tm, sf[mt][reg]);
            if (__any(tm > mreg + 8.0f)) {
                tm = fmaxf(tm, __shfl_xor(tm, 16));
                tm = fmaxf(tm, __shfl_xor(tm, 32));
                float nm = fmaxf(mreg, tm);
                float al = __expf(mreg - nm);
                mreg = nm;
                lacc *= al;
                float ar[4];
#pragma unroll
                for (int reg = 0; reg < 4; ++reg)
                    ar[reg] = __shfl(al, (lane & 48) | (quad * 4 + reg));
#pragma unroll
                for (int nt = 0; nt < NT_O; ++nt)
#pragma unroll
                    for (int reg = 0; reg < 4; ++reg) oacc[nt][reg] *= ar[reg];
            }
            // p = exp(s - m) (bounded e^8); pack pairs, b64 write per mt
#pragma unroll
            for (int mt = 0; mt < MT; ++mt) {
                float p0 = __expf(sf[mt][0] - mreg);
                float p1 = __expf(sf[mt][1] - mreg);
                float p2 = __expf(sf[mt][2] - mreg);
                float p3 = __expf(sf[mt][3] - mreg);
                lacc += (p0 + p1) + (p2 + p3);
                unsigned h01 = cvtpk(p0, p1), h23 = cvtpk(p2, p3);
                float b0 = __uint_as_float(h01 << 16);
                float b1 = __uint_as_float(h01 & 0xffff0000u);
                float b2 = __uint_as_float(h23 << 16);
                float b3 = __uint_as_float(h23 & 0xffff0000u);
                unsigned l01 = cvtpk(p0 - b0, p1 - b1);
                unsigned l23 = cvtpk(p2 - b2, p3 - b3);
                uint2 hw; hw.x = h01; hw.y = h23;
                uint2 lw; lw.x = l01; lw.y = l23;
                *(uint2*)&Ph[PIX(mbase + c, mt * 16 + quad * 4)] = hw;
                *(uint2*)&Pl[PIX(mbase + c, mt * 16 + quad * 4)] = lw;
            }
        }
        // PV: A[m=q=lane&15][k=key=quad*8+j] = Ph[mbase+c][...] (same-wave LDS)
        bf16x8 pah[KS_PV], pal[KS_PV];
#pragma unroll
        for (int ks = 0; ks < KS_PV; ++ks) {
            if (masked) { pah[ks] = pone; pal[ks] = pzero; }
            else {
                pah[ks] = *(const bf16x8*)&Ph[PIX(mbase + c, ks * 32 + quad * 8)];
                pal[ks] = *(const bf16x8*)&Pl[PIX(mbase + c, ks * 32 + quad * 8)];
            }
        }
#pragma unroll
        for (int nt = 0; nt < NT_O; ++nt) {
            f32x4 o = oacc[nt];
#pragma unroll
            for (int ks = 0; ks < KS_PV; ++ks) {
                bf16x8 bh = *(const bf16x8*)&Vh[VIX(nt * 16 + c, ks * 32 + quad * 8)];
                bf16x8 bl = *(const bf16x8*)&Vl[VIX(nt * 16 + c, ks * 32 + quad * 8)];
                o = mfma3(pah[ks], pal[ks], bh, bl, o);
            }
            oacc[nt] = o;
        }
    };

    const int NTL = tkloc / STILE;
    load_regs(kv0);
    for (int t = 0; t < NTL; ++t) {
        __syncthreads();                 // prev tile consumed by all waves
        write_bufs();
        __syncthreads();
        if (t + 1 < NTL) load_regs(kv0 + (t + 1) * STILE);
        compute_tile();
    }

    // cross-quad l reduce (deferred from per-tile); row q = mbase + c
    lacc += __shfl_xor(lacc, 16);
    lacc += __shfl_xor(lacc, 32);

    if (ZS == 1) {
        const float osc = (o_sidx >= 0) ? strat[o_sidx] : 1.0f;
        if (quad == 0) {
            int row = r0 + mbase + c;
            mout[h * Tq + row] = masked ? 0.0f : mreg;
            lout[h * Tq + row] = masked ? (float)Tk : lacc;
        }
        float sc[4];
#pragma unroll
        for (int reg = 0; reg < 4; ++reg) {
            float lf = masked ? (float)Tk
                              : __shfl(lacc, (lane & 48) | (quad * 4 + reg));
            sc[reg] = osc / lf;
        }
#pragma unroll
        for (int reg = 0; reg < 4; ++reg) {
            int row = r0 + mbase + quad * 4 + reg;
#pragma unroll
            for (int nt = 0; nt < NT_O; ++nt) {
                size_t gi = (size_t)row * D_MODEL + h * HD + nt * 16 + c;
                float v = sc[reg] * oacc[nt][reg];
                if (accum) v += O[gi];
                O[gi] = v;
            }
        }
    } else {
        float* Op = (blockIdx.z == 0) ? O : O2;
        if (quad == 0) {
            int row = r0 + mbase + c;
            mout[(blockIdx.z * gridDim.y + h) * Tq + row] = masked ? 0.0f : mreg;
            lout[(blockIdx.z * gridDim.y + h) * Tq + row] = masked ? (float)tkloc : lacc;
        }
#pragma unroll
        for (int reg = 0; reg < 4; ++reg) {
            int row = r0 + mbase + quad * 4 + reg;
#pragma unroll
            for (int nt = 0; nt < NT_O; ++nt)
                Op[(size_t)row * D_MODEL + h * HD + nt * 16 + c] = oacc[nt][reg];
        }
    }
}

// ---------------------------------------------------------------------------
// Merge 2 split-K partials: O = osc*(O0*w0+O1*w1)/l (+accum); also emits the
// merged (m,l) per (head,row) for comb. hdshift = log2(HD).
// ---------------------------------------------------------------------------
__global__ __launch_bounds__(256) void combineK(
    const float* __restrict__ O0, const float* __restrict__ O1,
    const float* __restrict__ mp, const float* __restrict__ lp,
    float* __restrict__ O, float* __restrict__ mf, float* __restrict__ lf,
    const float* __restrict__ strat, int o_sidx, int accum, int Tq,
    int hdshift, int NH)
{
    const int row = blockIdx.x;
    const int c4 = threadIdx.x * 4;
    const int h = c4 >> hdshift;
    const float m0 = mp[h * Tq + row], m1 = mp[(NH + h) * Tq + row];
    const float l0 = lp[h * Tq + row], l1 = lp[(NH + h) * Tq + row];
    const float m = fmaxf(m0, m1);
    const float w0 = __expf(m0 - m), w1 = __expf(m1 - m);
    const float lsum = l0 * w0 + l1 * w1;
    if (mf && (c4 & ((1 << hdshift) - 1)) == 0) {
        mf[h * Tq + row] = m;
        lf[h * Tq + row] = lsum;
    }
    const float osc = (o_sidx >= 0) ? strat[o_sidx] : 1.0f;
    const float sc = osc / lsum;
    float4 a = *(const float4*)&O0[(size_t)row * D_MODEL + c4];
    float4 b = *(const float4*)&O1[(size_t)row * D_MODEL + c4];
    size_t gi = (size_t)row * D_MODEL + c4;
    float4 r;
    r.x = sc * (a.x * w0 + b.x * w1);
    r.y = sc * (a.y * w0 + b.y * w1);
    r.z = sc * (a.z * w0 + b.z * w1);
    r.w = sc * (a.w * w0 + b.w * w1);
    if (accum) {
        float4 o = *(const float4*)&O[gi];
        r.x += o.x; r.y += o.y; r.z += o.z; r.w += o.w;
    }
    *(float4*)&O[gi] = r;
}

// ---------------------------------------------------------------------------
// MFMA comb plane: comb[r][c] = csc * (sum_h exp(ascale_h*q_h.k_h - m)/l + unif/Tk)
// Block = 64 rows x 128 cols, loops active heads (HD=64). K and Q pre-split;
// next head's K prefetched; (m, 1/l) staged once in LDS.
// ---------------------------------------------------------------------------
__global__ __launch_bounds__(256) void comb_mfma(
    const unsigned short* __restrict__ Qhi, const unsigned short* __restrict__ Qlo,
    const unsigned short* __restrict__ Khi, const unsigned short* __restrict__ Klo,
    const float* __restrict__ mrow, const float* __restrict__ lrow,
    const float* __restrict__ aparam, int amode,
    const float* __restrict__ strat,
    float* __restrict__ comb, int Tq, int Tk, int nh, float inv_scale)
{
    __shared__ __align__(16) unsigned short Kh[128][72], Kl[128][72];
    __shared__ float msh[16 * 64], lsh[16 * 64];
    const int tid = threadIdx.x;
    const int r0 = blockIdx.x * 64, c0 = blockIdx.y * 128;
    const int lane = tid & 63, wave = tid >> 6;
    const int c = lane & 15, quad = lane >> 4;
    const int mbase = wave * 16;

    for (int idx = tid; idx < nh * 64; idx += 256) {
        int hh = idx >> 6, rr = idx & 63;
        msh[idx] = mrow[hh * Tq + r0 + rr];
        lsh[idx] = 1.0f / lrow[hh * Tq + r0 + rr];
    }

    f32x4 acc[8];
#pragma unroll
    for (int nt = 0; nt < 8; ++nt) acc[nt] = (f32x4){0.f, 0.f, 0.f, 0.f};

    int hlist[16]; float glist[16]; int nact = 0; float unif = 0.0f;
    for (int h = 0; h < nh; ++h) {
        float gate = 1.0f;
        if (amode == 1) gate = (aparam[h] > 0.0f) ? 1.0f : 0.0f;
        if (amode == 2) gate = 1.0f / (1.0f + __expf(-aparam[h * 4]));
        if (amode == 1 && gate == 0.0f) { unif += 1.0f; continue; }
        hlist[nact] = h; glist[nact] = gate * inv_scale; ++nact;
    }

    u16x8 krh[4], krl[4];
    auto loadK = [&](int h) {
#pragma unroll
        for (int it = 0; it < 4; ++it) {
            int idx = tid + it * 256;
            int r = idx >> 3, c8 = (idx & 7) * 8;
            size_t go = (size_t)(c0 + r) * D_MODEL + h * 64 + c8;
            krh[it] = *(const u16x8*)&Khi[go];
            krl[it] = *(const u16x8*)&Klo[go];
        }
    };
    if (nact > 0) loadK(hlist[0]);

    for (int i = 0; i < nact; ++i) {
        const int h = hlist[i];
        const float ascale = glist[i];
        __syncthreads();   // previous head's K fully consumed (+msh/lsh visible)
#pragma unroll
        for (int it = 0; it < 4; ++it) {
            int idx = tid + it * 256;
            int r = idx >> 3, c8 = (idx & 7) * 8;
            *(u16x8*)&Kh[r][c8] = krh[it];
            *(u16x8*)&Kl[r][c8] = krl[it];
        }
        __syncthreads();
        if (i + 1 < nact) loadK(hlist[i + 1]);   // prefetch next head

        // Q fragments: pure vector loads from pre-split
        bf16x8 qah[2], qal[2];
        const unsigned short* qh = &Qhi[(size_t)(r0 + mbase + c) * D_MODEL + h * 64];
        const unsigned short* ql = &Qlo[(size_t)(r0 + mbase + c) * D_MODEL + h * 64];
#pragma unroll
        for (int ks = 0; ks < 2; ++ks) {
            qah[ks] = *(const bf16x8*)(qh + ks * 32 + quad * 8);
            qal[ks] = *(const bf16x8*)(ql + ks * 32 + quad * 8);
        }

        float mr[4], li[4];
#pragma unroll
        for (int reg = 0; reg < 4; ++reg) {
            mr[reg] = msh[h * 64 + mbase + quad * 4 + reg];
            li[reg] = lsh[h * 64 + mbase + quad * 4 + reg];
        }
#pragma unroll
        for (int nt = 0; nt < 8; ++nt) {
            f32x4 s = (f32x4){0.f, 0.f, 0.f, 0.f};
#pragma unroll
            for (int ks = 0; ks < 2; ++ks) {
                bf16x8 bh = *(const bf16x8*)&Kh[nt * 16 + c][ks * 32 + quad * 8];
                bf16x8 bl = *(const bf16x8*)&Kl[nt * 16 + c][ks * 32 + quad * 8];
                s = mfma3(qah[ks], qal[ks], bh, bl, s);
            }
#pragma unroll
            for (int reg = 0; reg < 4; ++reg)
                acc[nt][reg] += __expf(s[reg] * ascale - mr[reg]) * li[reg];
        }
    }
    const float csc = (strat[0] + strat[1] + strat[3]) / (float)nh;
    const float uadd = unif / (float)Tk;
#pragma unroll
    for (int nt = 0; nt < 8; ++nt) {
#pragma unroll
        for (int reg = 0; reg < 4; ++reg) {
            int row = r0 + mbase + quad * 4 + reg;
            comb[(size_t)row * Tk + c0 + nt * 16 + c] = csc * (acc[nt][reg] + uadd);
        }
    }
}

// ---------------------------------------------------------------------------
// Per-head 64x64 rotation, z-batched over two inputs:
// Y[t][h*64+e] = sum_d X[t][h*64+d]*R[h][d][e]
// ---------------------------------------------------------------------------
__global__ __launch_bounds__(256) void rotate_heads(
    const float* __restrict__ X0, const float* __restrict__ X1,
    const float* __restrict__ R,
    float* __restrict__ Y0, float* __restrict__ Y1)
{
    const float* X = blockIdx.z ? X1 : X0;
    float* Y = blockIdx.z ? Y1 : Y0;
    __shared__ float Rt[64][68];
    __shared__ float xs[64][68];
    const int tid = threadIdx.x;
    const int h = blockIdx.y;
    const int t0 = blockIdx.x * 64;
    for (int idx = tid; idx < 4096; idx += 256) {
        int d = idx >> 6, e = idx & 63;
        Rt[e][d] = R[h * 4096 + idx];
        xs[d][e] = X[(size_t)(t0 + d) * D_MODEL + h * 64 + e];
    }
    __syncthreads();
    const int ty = tid >> 4, tx = tid & 15;
    float acc[4][4] = {};
#pragma unroll 4
    for (int d0 = 0; d0 < 64; d0 += 4) {
        float4 rv[4];
#pragma unroll
        for (int j = 0; j < 4; ++j) rv[j] = *(const float4*)&Rt[tx * 4 + j][d0];
#pragma unroll
        for (int i = 0; i < 4; ++i) {
            float4 a = *(const float4*)&xs[ty * 4 + i][d0];
#pragma unroll
            for (int j = 0; j < 4; ++j)
                acc[i][j] += a.x * rv[j].x + a.y * rv[j].y + a.z * rv[j].z + a.w * rv[j].w;
        }
    }
#pragma unroll
    for (int i = 0; i < 4; ++i)
#pragma unroll
        for (int j = 0; j < 4; ++j)
            Y[(size_t)(t0 + ty * 4 + i) * D_MODEL + h * 64 + tx * 4 + j] = acc[i][j];
}

// ---------------------------------------------------------------------------
// F.interpolate(mode='linear', align_corners=False): [256,1024] -> [2048,1024]
// ---------------------------------------------------------------------------
__global__ __launch_bounds__(256) void interp_lin(
    const float* __restrict__ G, float* __restrict__ out)
{
    const int t = blockIdx.x;
    float src = (t + 0.5f) * 0.125f - 0.5f;
    src = fminf(fmaxf(src, 0.0f), 255.0f);
    float fl = floorf(src);
    int i0 = (int)fl;
    int i1 = min(i0 + 1, 255);
    float w = src - fl;
    const float4* g0 = (const float4*)(G + (size_t)i0 * D_MODEL);
    const float4* g1 = (const float4*)(G + (size_t)i1 * D_MODEL);
    float4* o = (float4*)(out + (size_t)t * D_MODEL);
    int c = threadIdx.x;
    float4 a = g0[c], b = g1[c];
    float4 r;
    r.x = a.x * (1.0f - w) + b.x * w;
    r.y = a.y * (1.0f - w) + b.y * w;
    r.z = a.z * (1.0f - w) + b.z * w;
    r.w = a.w * (1.0f - w) + b.w * w;
    o[c] = r;
}

// ---------------------------------------------------------------------------
extern "C" void kernel_launch(void* const* d_in, const int* in_sizes, int n_in,
                              void* d_out, int out_size, void* d_ws, size_t ws_size,
                              hipStream_t stream)
{
    (void)in_sizes; (void)n_in; (void)ws_size; (void)out_size;
    const float* query    = (const float*)d_in[0];
    const float* key      = (const float*)d_in[1];
    const float* value    = (const float*)d_in[2];
    const float* strat    = (const float*)d_in[3];
    const float* Wqkv_lin = (const float*)d_in[4];
    const float* b_lin    = (const float*)d_in[5];
    const float* Wo_lin   = (const float*)d_in[6];
    const float* bo_lin   = (const float*)d_in[7];
    const float* spars    = (const float*)d_in[8];
    const float* Wqkv_loc = (const float*)d_in[9];
    const float* b_loc    = (const float*)d_in[10];
    const float* Wo_loc   = (const float*)d_in[11];
    const float* bo_loc   = (const float*)d_in[12];
    const float* Wqkv_glb = (const float*)d_in[13];
    const float* b_glb    = (const float*)d_in[14];
    const float* Wo_glb   = (const float*)d_in[15];
    const float* bo_glb   = (const float*)d_in[16];
    const float* Wf       = (const float*)d_in[17];
    const float* bf       = (const float*)d_in[18];
    const float* Rq       = (const float*)d_in[19];
    const float* ent      = (const float*)d_in[20];

    float* out = (float*)d_out;
    float* weighted = out;                        // [2048][1024]
    float* combined = out + (size_t)2048 * 1024;  // [3][2048][2048]
    const size_t PLANE = (size_t)2048 * 2048;

    float* ws   = (float*)d_ws;
    float* qkv  = ws;                   // 3 x 2048x1024
    float* AO   = qkv + 6291456;
    float* LO   = AO + 2097152;
    float* gqkv = LO + 2097152;
    float* gAO  = gqkv + 786432;
    float* gOUT = gAO + 262144;
    float* GI   = gOUT + 262144;
    float* mb   = GI + 2097152;         // [32][2048] partial m
    float* lb   = mb + 65536;           // [32][2048] partial l
    float* qrot = qkv;                  // alias: lin qkv dead by then
    float* krot = qkv + 2097152;
    // pre-split bf16 hi/lo buffers (u16)
    unsigned short* Ksp_h = (unsigned short*)(lb + 65536);  // [2048][1024]
    unsigned short* Ksp_l = Ksp_h + 2097152;
    unsigned short* Vtp_h = Ksp_l + 2097152;                // [1024][2048]
    unsigned short* Vtp_l = Vtp_h + 2097152;
    unsigned short* gKs_h = Vtp_l + 2097152;                // [256][1024]
    unsigned short* gKs_l = gKs_h + 262144;
    unsigned short* gVt_h = gKs_l + 262144;                 // [1024][256]
    unsigned short* gVt_l = gVt_h + 262144;
    float* mc = (float*)(gVt_l + 262144);                   // [16][2048] merged m
    float* lc = mc + 32768;                                 // [16][2048] merged l
    // Q pre-split for comb lives in GI (time-shared with flash partial O1)
    unsigned short* Qsp_h = (unsigned short*)GI;            // [2048][1024]
    unsigned short* Qsp_l = Qsp_h + 2097152;

    const float inv8   = 0.125f;
    const float inv128 = 1.0f / sqrtf(128.0f);

    hipMemsetAsync(weighted, 0, (size_t)2097152 * sizeof(float), stream);

    // ---- LINEAR (proj'd MHA, 16 heads; combined plane 0) ----
    gemm_mfma<<<dim3(32, 16, 3), 256, 0, stream>>>(
        query, key, value, 1024, Wqkv_lin, 1048576, 1024, b_lin, 1024,
        qkv, 2097152, 2048, 1024, 1024, nullptr, 0, 0);
    split_rm<<<dim3(2048), 256, 0, stream>>>(qkv + 2097152, Ksp_h, Ksp_l, 524288);
    split_tr<<<dim3(32, 16), 256, 0, stream>>>(qkv + 4194304, Vtp_h, Vtp_l, 2048);
    flash_mfma<64><<<dim3(32, 16, 2), 256, 0, stream>>>(
        qkv, Ksp_h, Ksp_l, Vtp_h, Vtp_l, nullptr, 0,
        AO, GI, strat, -1, 0, mb, lb, 2048, 2048, inv8);
    combineK<<<dim3(2048), 256, 0, stream>>>(
        AO, GI, mb, lb, AO, mc, lc, strat, -1, 0, 2048, 6, 16);
    split_rm<<<dim3(2048), 256, 0, stream>>>(qkv, Qsp_h, Qsp_l, 524288);
    comb_mfma<<<dim3(32, 16), 256, 0, stream>>>(
        Qsp_h, Qsp_l, Ksp_h, Ksp_l, mc, lc, nullptr, 0, strat,
        combined + 0 * PLANE, 2048, 2048, 16, inv8);
    gemm_mfma<<<dim3(32, 16, 1), 256, 0, stream>>>(
        AO, AO, AO, 1024, Wo_lin, 0, 1024, bo_lin, 0,
        weighted, 0, 2048, 1024, 1024, strat, 0, 1);

    // ---- SPARSE (raw heads, per-head mask; combined plane 1) ----
    split_rm<<<dim3(2048), 256, 0, stream>>>(key, Ksp_h, Ksp_l, 524288);
    split_tr<<<dim3(32, 16), 256, 0, stream>>>(value, Vtp_h, Vtp_l, 2048);
    flash_mfma<64><<<dim3(32, 16, 2), 256, 0, stream>>>(
        query, Ksp_h, Ksp_l, Vtp_h, Vtp_l, spars, 1,
        AO, GI, strat, 1, 1, mb, lb, 2048, 2048, inv8);
    combineK<<<dim3(2048), 256, 0, stream>>>(
        AO, GI, mb, lb, weighted, mc, lc, strat, 1, 1, 2048, 6, 16);
    split_rm<<<dim3(2048), 256, 0, stream>>>(query, Qsp_h, Qsp_l, 524288);
    comb_mfma<<<dim3(32, 16), 256, 0, stream>>>(
        Qsp_h, Qsp_l, Ksp_h, Ksp_l, mc, lc, spars, 1, strat,
        combined + 1 * PLANE, 2048, 2048, 16, inv8);

    // ---- QUANTUM (rotated raw heads, per-head gate; combined plane 2) ----
    // Vtp still holds split raw value (shared with SPARSE).
    rotate_heads<<<dim3(32, 16, 2), 256, 0, stream>>>(query, key, Rq, qrot, krot);
    split_rm<<<dim3(2048), 256, 0, stream>>>(krot, Ksp_h, Ksp_l, 524288);
    flash_mfma<64><<<dim3(32, 16, 2), 256, 0, stream>>>(
        qrot, Ksp_h, Ksp_l, Vtp_h, Vtp_l, ent, 2,
        AO, GI, strat, 3, 1, mb, lb, 2048, 2048, inv8);
    combineK<<<dim3(2048), 256, 0, stream>>>(
        AO, GI, mb, lb, weighted, mc, lc, strat, 3, 1, 2048, 6, 16);
    split_rm<<<dim3(2048), 256, 0, stream>>>(qrot, Qsp_h, Qsp_l, 524288);
    comb_mfma<<<dim3(32, 16), 256, 0, stream>>>(
        Qsp_h, Qsp_l, Ksp_h, Ksp_l, mc, lc, ent, 2, strat,
        combined + 2 * PLANE, 2048, 2048, 16, inv8);

    // ---- LOCAL (proj'd MHA, 8 heads x 128), split-K x2 over keys ----
    gemm_mfma<<<dim3(32, 16, 3), 256, 0, stream>>>(
        query, key, value, 1024, Wqkv_loc, 1048576, 1024, b_loc, 1024,
        qkv, 2097152, 2048, 1024, 1024, nullptr, 0, 0);
    split_rm<<<dim3(2048), 256, 0, stream>>>(qkv + 2097152, Ksp_h, Ksp_l, 524288);
    split_tr<<<dim3(32, 16), 256, 0, stream>>>(qkv + 4194304, Vtp_h, Vtp_l, 2048);
    flash_mfma<128><<<dim3(32, 8, 2), 256, 0, stream>>>(
        qkv, Ksp_h, Ksp_l, Vtp_h, Vtp_l, nullptr, 0,
        AO, GI, strat, -1, 0, mb, lb, 2048, 2048, inv128);
    combineK<<<dim3(2048), 256, 0, stream>>>(
        AO, GI, mb, lb, AO, nullptr, nullptr, strat, -1, 0, 2048, 7, 8);
    gemm_mfma<<<dim3(32, 16, 1), 256, 0, stream>>>(
        AO, AO, AO, 1024, Wo_loc, 0, 1024, bo_loc, 0,
        LO, 0, 2048, 1024, 1024, nullptr, 0, 0);

    // ---- GLOBAL (strided pool to 256 tokens, 8 heads x 128, interp back) ----
    gemm_mfma<<<dim3(4, 16, 3), 256, 0, stream>>>(
        query, key, value, 8192, Wqkv_glb, 1048576, 1024, b_glb, 1024,
        gqkv, 262144, 256, 1024, 1024, nullptr, 0, 0);
    split_rm<<<dim3(256), 256, 0, stream>>>(gqkv + 262144, gKs_h, gKs_l, 65536);
    split_tr<<<dim3(4, 16), 256, 0, stream>>>(gqkv + 524288, gVt_h, gVt_l, 256);
    flash_mfma<128><<<dim3(4, 8, 1), 256, 0, stream>>>(
        gqkv, gKs_h, gKs_l, gVt_h, gVt_l, nullptr, 0,
        gAO, nullptr, strat, -1, 0, mb, lb, 256, 256, inv128);
    gemm_mfma<<<dim3(4, 16, 1), 256, 0, stream>>>(
        gAO, gAO, gAO, 1024, Wo_glb, 0, 1024, bo_glb, 0,
        gOUT, 0, 256, 1024, 1024, nullptr, 0, 0);
    interp_lin<<<dim3(2048), 256, 0, stream>>>(gOUT, GI);

    // ---- HIER: weighted += s2 * (LO @ WfL^T + GI @ WfR^T + bf) ----
    gemm_mfma<<<dim3(32, 16, 1), 256, 0, stream>>>(
        LO, LO, LO, 1024, Wf, 0, 2048, bf, 0,
        weighted, 0, 2048, 1024, 1024, strat, 2, 1);
    gemm_mfma<<<dim3(32, 16, 1), 256, 0, stream>>>(
        GI, GI, GI, 1024, Wf + 1024, 0, 2048, nullptr, 0,
        weighted, 0, 2048, 1024, 1024, strat, 2, 1);
}

// Round 7
// 1034.692 us; speedup vs baseline: 2.2966x; 1.0414x over previous
//
#include <hip/hip_runtime.h>
#include <math.h>

// Problem constants: B=1, T=2048, D=1024, H=16, HD=64, STRIDE=8, Tg=256.
// Output 0: weighted [2048][1024]
// Output 1: combined [3][2048][2048] = (s0+s1+s3) * {linear_w, sparse_w, quantum_w}
#define D_MODEL 1024

typedef __attribute__((ext_vector_type(8))) short bf16x8;
typedef __attribute__((ext_vector_type(4))) float f32x4;
typedef __attribute__((ext_vector_type(8))) unsigned short u16x8;

// fp32 -> bf16 RNE, and bf16 -> fp32
__device__ __forceinline__ unsigned short bfr(float f) {
    unsigned u = __float_as_uint(f);
    u += 0x7fffu + ((u >> 16) & 1u);
    return (unsigned short)(u >> 16);
}
__device__ __forceinline__ float bff(unsigned short s) {
    return __uint_as_float(((unsigned)s) << 16);
}
// split x = hi + lo (both bf16); hi*hi+hi*lo+lo*hi captures x*y to ~2^-17 rel
__device__ __forceinline__ void split2(float x, unsigned short &h, unsigned short &l) {
    h = bfr(x);
    l = bfr(x - bff(h));
}
// packed RNE f32x2 -> bf16x2 (low16 = a, high16 = b); identical rounding to bfr
__device__ __forceinline__ unsigned cvtpk(float a, float b) {
    unsigned r;
    asm("v_cvt_pk_bf16_f32 %0, %1, %2" : "=v"(r) : "v"(a), "v"(b));
    return r;
}
__device__ __forceinline__ f32x4 mfma3(bf16x8 ah, bf16x8 al, bf16x8 bh, bf16x8 bl, f32x4 c) {
    c = __builtin_amdgcn_mfma_f32_16x16x32_bf16(ah, bh, c, 0, 0, 0);
    c = __builtin_amdgcn_mfma_f32_16x16x32_bf16(ah, bl, c, 0, 0, 0);
    c = __builtin_amdgcn_mfma_f32_16x16x32_bf16(al, bh, c, 0, 0, 0);
    return c;
}

// ---------------------------------------------------------------------------
// Pre-split kernels: fp32 -> bf16 hi/lo (computed ONCE, reused everywhere).
// ---------------------------------------------------------------------------
__global__ __launch_bounds__(256) void split_rm(
    const float* __restrict__ in, unsigned short* __restrict__ hi,
    unsigned short* __restrict__ lo, int n4)
{
    int idx = blockIdx.x * 256 + threadIdx.x;
    if (idx >= n4) return;
    float4 v = ((const float4*)in)[idx];
    ushort4 hs, ls;
    split2(v.x, hs.x, ls.x); split2(v.y, hs.y, ls.y);
    split2(v.z, hs.z, ls.z); split2(v.w, hs.w, ls.w);
    ((ushort4*)hi)[idx] = hs;
    ((ushort4*)lo)[idx] = ls;
}

// Transposed split: in [T][1024] fp32 -> hi/lo [1024][T] u16 (row = global d).
__global__ __launch_bounds__(256) void split_tr(
    const float* __restrict__ in, unsigned short* __restrict__ hi,
    unsigned short* __restrict__ lo, int T)
{
    __shared__ float xs[64][65];   // [t][d]
    const int t0 = blockIdx.x * 64, d0 = blockIdx.y * 64;
    for (int idx = threadIdx.x; idx < 64 * 16; idx += 256) {
        int r = idx >> 4, c4 = (idx & 15) * 4;
        float4 v = *(const float4*)&in[(size_t)(t0 + r) * D_MODEL + d0 + c4];
        xs[r][c4] = v.x; xs[r][c4 + 1] = v.y; xs[r][c4 + 2] = v.z; xs[r][c4 + 3] = v.w;
    }
    __syncthreads();
    for (int idx = threadIdx.x; idx < 64 * 8; idx += 256) {
        int dd = idx >> 3, t8 = (idx & 7) * 8;
        u16x8 hs, ls;
#pragma unroll
        for (int j = 0; j < 8; ++j) {
            unsigned short hh, ll;
            split2(xs[t8 + j][dd], hh, ll);
            hs[j] = hh; ls[j] = ll;
        }
        *(u16x8*)&hi[(size_t)(d0 + dd) * T + t0 + t8] = hs;
        *(u16x8*)&lo[(size_t)(d0 + dd) * T + t0 + t8] = ls;
    }
}

// ---------------------------------------------------------------------------
// MFMA GEMM on PRE-SPLIT operands: C[M,N] (+)= s*(X[M,K] @ W[N,K]^T + bias).
// X, W given as u16 bf16-hi/lo arrays (element strides xrstride/wrstride).
// Staging = pure u16x8 copy (no split2, no scalar loads). 64x64 tile,
// 4 waves, register prefetch of next k-step. z-batched over up to 3 X's
// (W/bias/C advance by wz/bz/cz per z).
// ---------------------------------------------------------------------------
__global__ __launch_bounds__(256) void gemm_bf(
    const unsigned short* __restrict__ Xh0, const unsigned short* __restrict__ Xl0,
    const unsigned short* __restrict__ Xh1, const unsigned short* __restrict__ Xl1,
    const unsigned short* __restrict__ Xh2, const unsigned short* __restrict__ Xl2,
    int xrstride,
    const unsigned short* __restrict__ Whi, const unsigned short* __restrict__ Wlo,
    size_t wz, int wrstride,
    const float* __restrict__ bias, int bz,
    float* __restrict__ C, size_t cz, int M, int N, int K,
    const float* __restrict__ sptr, int sidx, int accum)
{
    const int z = blockIdx.z;
    const unsigned short* Xh_g = (z == 0) ? Xh0 : (z == 1 ? Xh1 : Xh2);
    const unsigned short* Xl_g = (z == 0) ? Xl0 : (z == 1 ? Xl1 : Xl2);
    Whi += (size_t)z * wz; Wlo += (size_t)z * wz;
    if (bias) bias += z * bz;
    C += (size_t)z * cz;

    __shared__ __align__(16) unsigned short Xh[64][40], Xl[64][40];
    __shared__ __align__(16) unsigned short Wh[64][40], Wl[64][40];
    const int tid = threadIdx.x;
    const int m0 = blockIdx.x * 64, n0 = blockIdx.y * 64;
    const int lane = tid & 63, wave = tid >> 6;
    const int c = lane & 15, quad = lane >> 4;
    const int mbase = wave * 16;

    f32x4 acc[4];
#pragma unroll
    for (int nt = 0; nt < 4; ++nt) acc[nt] = (f32x4){0.f, 0.f, 0.f, 0.f};

    // staging ownership: thread -> (row r_, 8-col chunk c8_) of the 64x32 tile
    const int r_ = tid >> 2, c8_ = (tid & 3) * 8;
    u16x8 xh, xl, wh, wl;
    auto ld = [&](int k0) {
        size_t xo = (size_t)(m0 + r_) * xrstride + k0 + c8_;
        xh = *(const u16x8*)&Xh_g[xo];
        xl = *(const u16x8*)&Xl_g[xo];
        size_t wo = (size_t)(n0 + r_) * wrstride + k0 + c8_;
        wh = *(const u16x8*)&Whi[wo];
        wl = *(const u16x8*)&Wlo[wo];
    };
    ld(0);

    for (int k0 = 0; k0 < K; k0 += 32) {
        __syncthreads();
        *(u16x8*)&Xh[r_][c8_] = xh;
        *(u16x8*)&Xl[r_][c8_] = xl;
        *(u16x8*)&Wh[r_][c8_] = wh;
        *(u16x8*)&Wl[r_][c8_] = wl;
        __syncthreads();
        if (k0 + 32 < K) ld(k0 + 32);
        bf16x8 ah = *(const bf16x8*)&Xh[mbase + c][quad * 8];
        bf16x8 al = *(const bf16x8*)&Xl[mbase + c][quad * 8];
#pragma unroll
        for (int nt = 0; nt < 4; ++nt) {
            bf16x8 bh = *(const bf16x8*)&Wh[nt * 16 + c][quad * 8];
            bf16x8 bl = *(const bf16x8*)&Wl[nt * 16 + c][quad * 8];
            acc[nt] = mfma3(ah, al, bh, bl, acc[nt]);
        }
    }
    const float s = (sptr != nullptr) ? sptr[sidx] : 1.0f;
#pragma unroll
    for (int nt = 0; nt < 4; ++nt) {
#pragma unroll
        for (int reg = 0; reg < 4; ++reg) {
            int row = m0 + mbase + quad * 4 + reg;
            int col = n0 + nt * 16 + c;
            float v = acc[nt][reg] + (bias ? bias[col] : 0.0f);
            v *= s;
            size_t gi = (size_t)row * N + col;
            if (accum) v += C[gi];
            C[gi] = v;
        }
    }
}

// ---------------------------------------------------------------------------
// MFMA flash attention, one block = (head, 64 query rows [, key-split z]).
//   HD=64: unpadded XOR-swizzled LDS (3 blocks/CU); split-K via gridDim.z.
//   Swapped QK^T (A=K, B=Q); lane owns one q-row; defer-max; cvt_pk P-pack.
//   Masked heads (amode 1, gate 0): P = constant registers, no LDS P.
// ---------------------------------------------------------------------------
template <int HD>
__global__ __launch_bounds__(256) void flash_mfma(
    const float* __restrict__ Q,
    const unsigned short* __restrict__ Khi, const unsigned short* __restrict__ Klo,
    const unsigned short* __restrict__ Vthi, const unsigned short* __restrict__ Vtlo,
    const float* __restrict__ aparam, int amode,
    float* __restrict__ O, float* __restrict__ O2,
    const float* __restrict__ strat, int o_sidx, int accum,
    float* __restrict__ mout, float* __restrict__ lout,
    int Tq, int Tk, float inv_scale)
{
    constexpr int ROWS = 64;
    constexpr int STILE = (HD == 64) ? 64 : 32;
    constexpr int MT   = STILE / 16;   // key m-tiles (swapped)
    constexpr int KS   = HD / 32;      // QK k-steps
    constexpr int NT_O = HD / 16;      // O n-tiles
    constexpr int KS_PV = STILE / 32;  // PV k-steps
    constexpr bool SWZ = (HD == 64);   // swizzled unpadded LDS
    constexpr int KPITCH = SWZ ? HD : HD + 8;
    constexpr int VPITCH = SWZ ? STILE : STILE + 8;
    constexpr int KIT = STILE * HD / 8 / 256;   // u16x8 items per thread (K)
    constexpr int VIT = STILE * HD / 8 / 256;   // u16x8 items per thread (V)

    __shared__ __align__(16) unsigned short Kh[STILE * KPITCH], Kl[STILE * KPITCH];
    __shared__ __align__(16) unsigned short Vh[HD * VPITCH],  Vl[HD * VPITCH];
    __shared__ __align__(16) unsigned short Ph[ROWS * VPITCH], Pl[ROWS * VPITCH];

    // index helpers: 16B-chunk XOR swizzle when SWZ (row length 64 u16, 8 chunks)
    auto KIX = [](int r, int cc) {
        return SWZ ? r * HD + ((cc & 7) | ((((cc >> 3) ^ r) & 7) << 3))
                   : r * KPITCH + cc;
    };
    auto VIX = [](int d, int s) {
        return SWZ ? d * STILE + ((s & 7) | ((((s >> 3) ^ d) & 7) << 3))
                   : d * VPITCH + s;
    };
    auto PIX = [](int r, int cc) {
        return SWZ ? r * STILE + ((cc & 7) | ((((cc >> 3) ^ r) & 7) << 3))
                   : r * VPITCH + cc;
    };

    const int tid = threadIdx.x;
    const int h = blockIdx.y;
    const int r0 = blockIdx.x * ROWS;
    const int lane = tid & 63, wave = tid >> 6;
    const int c = lane & 15, quad = lane >> 4;
    const int mbase = wave * 16;
    const int ZS = gridDim.z;
    const int tkloc = Tk / ZS;
    const int kv0 = blockIdx.z * tkloc;

    float gate = 1.0f;
    if (amode == 1) gate = (aparam[h] > 0.0f) ? 1.0f : 0.0f;
    if (amode == 2) gate = 1.0f / (1.0f + __expf(-aparam[h * 4]));
    const float ascale = gate * inv_scale;
    const bool masked = (amode == 1) && (gate == 0.0f);

    // Q B-fragments straight from global (key-loop invariant, wave-private)
    bf16x8 qah[KS], qal[KS];
    if (!masked) {
        const float* qrow = &Q[(size_t)(r0 + mbase + c) * D_MODEL + h * HD];
#pragma unroll
        for (int ks = 0; ks < KS; ++ks) {
            float4 a  = *(const float4*)(qrow + ks * 32 + quad * 8);
            float4 b2 = *(const float4*)(qrow + ks * 32 + quad * 8 + 4);
            unsigned short hh, ll;
            split2(a.x, hh, ll);  qah[ks][0] = (short)hh; qal[ks][0] = (short)ll;
            split2(a.y, hh, ll);  qah[ks][1] = (short)hh; qal[ks][1] = (short)ll;
            split2(a.z, hh, ll);  qah[ks][2] = (short)hh; qal[ks][2] = (short)ll;
            split2(a.w, hh, ll);  qah[ks][3] = (short)hh; qal[ks][3] = (short)ll;
            split2(b2.x, hh, ll); qah[ks][4] = (short)hh; qal[ks][4] = (short)ll;
            split2(b2.y, hh, ll); qah[ks][5] = (short)hh; qal[ks][5] = (short)ll;
            split2(b2.z, hh, ll); qah[ks][6] = (short)hh; qal[ks][6] = (short)ll;
            split2(b2.w, hh, ll); qah[ks][7] = (short)hh; qal[ks][7] = (short)ll;
        }
    }

    float mreg = -1e30f, lacc = 0.0f;   // per-lane: row q = mbase + c
    f32x4 oacc[NT_O];
#pragma unroll
    for (int nt = 0; nt < NT_O; ++nt) oacc[nt] = (f32x4){0.f, 0.f, 0.f, 0.f};

    // masked: P == 1.0 uniform, in registers only
    bf16x8 pone, pzero;
#pragma unroll
    for (int j = 0; j < 8; ++j) { pone[j] = (short)0x3F80; pzero[j] = 0; }

    u16x8 krh[KIT], krl[KIT], vrh[VIT], vrl[VIT];

    auto load_regs = [&](int s0) {
        if (!masked) {
#pragma unroll
            for (int it = 0; it < KIT; ++it) {
                int idx = tid + it * 256;
                int r = idx / (HD / 8), c8 = (idx % (HD / 8)) * 8;
                size_t go = (size_t)(s0 + r) * D_MODEL + h * HD + c8;
                krh[it] = *(const u16x8*)&Khi[go];
                krl[it] = *(const u16x8*)&Klo[go];
            }
        }
#pragma unroll
        for (int it = 0; it < VIT; ++it) {
            int idx = tid + it * 256;
            int d = idx % HD, s8 = (idx / HD) * 8;
            size_t go = (size_t)(h * HD + d) * Tk + s0 + s8;
            vrh[it] = *(const u16x8*)&Vthi[go];
            vrl[it] = *(const u16x8*)&Vtlo[go];
        }
    };
    auto write_bufs = [&]() {
        if (!masked) {
#pragma unroll
            for (int it = 0; it < KIT; ++it) {
                int idx = tid + it * 256;
                int r = idx / (HD / 8), c8 = (idx % (HD / 8)) * 8;
                *(u16x8*)&Kh[KIX(r, c8)] = krh[it];
                *(u16x8*)&Kl[KIX(r, c8)] = krl[it];
            }
        }
#pragma unroll
        for (int it = 0; it < VIT; ++it) {
            int idx = tid + it * 256;
            int d = idx % HD, s8 = (idx / HD) * 8;
            *(u16x8*)&Vh[VIX(d, s8)] = vrh[it];
            *(u16x8*)&Vl[VIX(d, s8)] = vrl[it];
        }
    };

    auto compute_tile = [&]() {
        if (!masked) {
            // swapped scores: sf[mt][reg] = S[key=mt*16+quad*4+reg][q=mbase+c]
            f32x4 sf[MT];
#pragma unroll
            for (int mt = 0; mt < MT; ++mt) {
                f32x4 s = (f32x4){0.f, 0.f, 0.f, 0.f};
#pragma unroll
                for (int ks = 0; ks < KS; ++ks) {
                    bf16x8 kh = *(const bf16x8*)&Kh[KIX(mt * 16 + c, ks * 32 + quad * 8)];
                    bf16x8 kl = *(const bf16x8*)&Kl[KIX(mt * 16 + c, ks * 32 + quad * 8)];
                    s = mfma3(kh, kl, qah[ks], qal[ks], s);
                }
                sf[mt] = s * ascale;
            }
            // per-lane local max over this quad's keys; rescale only on growth
            float tm = sf[0][0];
#pragma unroll
            for (int mt = 0; mt < MT; ++mt)
#pragma unroll
                for (int reg = 0; reg < 4; ++reg) tm = fmaxf(tm, sf[mt][reg]);
            if (__any(tm > mreg + 8.0f)) {
                tm = fmaxf(tm, __shfl_xor(tm, 16));
                tm = fmaxf(tm, __shfl_xor(tm, 32));
                float nm = fmaxf(mreg, tm);
                float al = __expf(mreg - nm);
                mreg = nm;
                lacc *= al;
                float ar[4];
#pragma unroll
                for (int reg = 0; reg < 4; ++reg)
                    ar[reg] = __shfl(al, (lane & 48) | (quad * 4 + reg));
#pragma unroll
                for (int nt = 0; nt < NT_O; ++nt)
#pragma unroll
                    for (int reg = 0; reg < 4; ++reg) oacc[nt][reg] *= ar[reg];
            }
            // p = exp(s - m) (bounded e^8); pack pairs, b64 write per mt
#pragma unroll
            for (int mt = 0; mt < MT; ++mt) {
                float p0 = __expf(sf[mt][0] - mreg);
                float p1 = __expf(sf[mt][1] - mreg);
                float p2 = __expf(sf[mt][2] - mreg);
                float p3 = __expf(sf[mt][3] - mreg);
                lacc += (p0 + p1) + (p2 + p3);
                unsigned h01 = cvtpk(p0, p1), h23 = cvtpk(p2, p3);
                float b0 = __uint_as_float(h01 << 16);
                float b1 = __uint_as_float(h01 & 0xffff0000u);
                float b2 = __uint_as_float(h23 << 16);
                float b3 = __uint_as_float(h23 & 0xffff0000u);
                unsigned l01 = cvtpk(p0 - b0, p1 - b1);
                unsigned l23 = cvtpk(p2 - b2, p3 - b3);
                uint2 hw; hw.x = h01; hw.y = h23;
                uint2 lw; lw.x = l01; lw.y = l23;
                *(uint2*)&Ph[PIX(mbase + c, mt * 16 + quad * 4)] = hw;
                *(uint2*)&Pl[PIX(mbase + c, mt * 16 + quad * 4)] = lw;
            }
        }
        // PV: A[m=q=lane&15][k=key=quad*8+j] = Ph[mbase+c][...] (same-wave LDS)
        bf16x8 pah[KS_PV], pal[KS_PV];
#pragma unroll
        for (int ks = 0; ks < KS_PV; ++ks) {
            if (masked) { pah[ks] = pone; pal[ks] = pzero; }
            else {
                pah[ks] = *(const bf16x8*)&Ph[PIX(mbase + c, ks * 32 + quad * 8)];
                pal[ks] = *(const bf16x8*)&Pl[PIX(mbase + c, ks * 32 + quad * 8)];
            }
        }
#pragma unroll
        for (int nt = 0; nt < NT_O; ++nt) {
            f32x4 o = oacc[nt];
#pragma unroll
            for (int ks = 0; ks < KS_PV; ++ks) {
                bf16x8 bh = *(const bf16x8*)&Vh[VIX(nt * 16 + c, ks * 32 + quad * 8)];
                bf16x8 bl = *(const bf16x8*)&Vl[VIX(nt * 16 + c, ks * 32 + quad * 8)];
                o = mfma3(pah[ks], pal[ks], bh, bl, o);
            }
            oacc[nt] = o;
        }
    };

    const int NTL = tkloc / STILE;
    load_regs(kv0);
    for (int t = 0; t < NTL; ++t) {
        __syncthreads();                 // prev tile consumed by all waves
        write_bufs();
        __syncthreads();
        if (t + 1 < NTL) load_regs(kv0 + (t + 1) * STILE);
        compute_tile();
    }

    // cross-quad l reduce (deferred from per-tile); row q = mbase + c
    lacc += __shfl_xor(lacc, 16);
    lacc += __shfl_xor(lacc, 32);

    if (ZS == 1) {
        const float osc = (o_sidx >= 0) ? strat[o_sidx] : 1.0f;
        if (quad == 0) {
            int row = r0 + mbase + c;
            mout[h * Tq + row] = masked ? 0.0f : mreg;
            lout[h * Tq + row] = masked ? (float)Tk : lacc;
        }
        float sc[4];
#pragma unroll
        for (int reg = 0; reg < 4; ++reg) {
            float lf = masked ? (float)Tk
                              : __shfl(lacc, (lane & 48) | (quad * 4 + reg));
            sc[reg] = osc / lf;
        }
#pragma unroll
        for (int reg = 0; reg < 4; ++reg) {
            int row = r0 + mbase + quad * 4 + reg;
#pragma unroll
            for (int nt = 0; nt < NT_O; ++nt) {
                size_t gi = (size_t)row * D_MODEL + h * HD + nt * 16 + c;
                float v = sc[reg] * oacc[nt][reg];
                if (accum) v += O[gi];
                O[gi] = v;
            }
        }
    } else {
        float* Op = (blockIdx.z == 0) ? O : O2;
        if (quad == 0) {
            int row = r0 + mbase + c;
            mout[(blockIdx.z * gridDim.y + h) * Tq + row] = masked ? 0.0f : mreg;
            lout[(blockIdx.z * gridDim.y + h) * Tq + row] = masked ? (float)tkloc : lacc;
        }
#pragma unroll
        for (int reg = 0; reg < 4; ++reg) {
            int row = r0 + mbase + quad * 4 + reg;
#pragma unroll
            for (int nt = 0; nt < NT_O; ++nt)
                Op[(size_t)row * D_MODEL + h * HD + nt * 16 + c] = oacc[nt][reg];
        }
    }
}

// ---------------------------------------------------------------------------
// Merge 2 split-K partials: O = osc*(O0*w0+O1*w1)/l (+accum); also emits the
// merged (m,l) per (head,row) for comb. hdshift = log2(HD).
// ---------------------------------------------------------------------------
__global__ __launch_bounds__(256) void combineK(
    const float* __restrict__ O0, const float* __restrict__ O1,
    const float* __restrict__ mp, const float* __restrict__ lp,
    float* __restrict__ O, float* __restrict__ mf, float* __restrict__ lf,
    const float* __restrict__ strat, int o_sidx, int accum, int Tq,
    int hdshift, int NH)
{
    const int row = blockIdx.x;
    const int c4 = threadIdx.x * 4;
    const int h = c4 >> hdshift;
    const float m0 = mp[h * Tq + row], m1 = mp[(NH + h) * Tq + row];
    const float l0 = lp[h * Tq + row], l1 = lp[(NH + h) * Tq + row];
    const float m = fmaxf(m0, m1);
    const float w0 = __expf(m0 - m), w1 = __expf(m1 - m);
    const float lsum = l0 * w0 + l1 * w1;
    if (mf && (c4 & ((1 << hdshift) - 1)) == 0) {
        mf[h * Tq + row] = m;
        lf[h * Tq + row] = lsum;
    }
    const float osc = (o_sidx >= 0) ? strat[o_sidx] : 1.0f;
    const float sc = osc / lsum;
    float4 a = *(const float4*)&O0[(size_t)row * D_MODEL + c4];
    float4 b = *(const float4*)&O1[(size_t)row * D_MODEL + c4];
    size_t gi = (size_t)row * D_MODEL + c4;
    float4 r;
    r.x = sc * (a.x * w0 + b.x * w1);
    r.y = sc * (a.y * w0 + b.y * w1);
    r.z = sc * (a.z * w0 + b.z * w1);
    r.w = sc * (a.w * w0 + b.w * w1);
    if (accum) {
        float4 o = *(const float4*)&O[gi];
        r.x += o.x; r.y += o.y; r.z += o.z; r.w += o.w;
    }
    *(float4*)&O[gi] = r;
}

// ---------------------------------------------------------------------------
// MFMA comb plane: comb[r][c] = csc * (sum_h exp(ascale_h*q_h.k_h - m)/l + unif/Tk)
// Block = 64 rows x 128 cols, loops active heads (HD=64). K and Q pre-split;
// next head's K prefetched; (m, 1/l) staged once in LDS.
// ---------------------------------------------------------------------------
__global__ __launch_bounds__(256) void comb_mfma(
    const unsigned short* __restrict__ Qhi, const unsigned short* __restrict__ Qlo,
    const unsigned short* __restrict__ Khi, const unsigned short* __restrict__ Klo,
    const float* __restrict__ mrow, const float* __restrict__ lrow,
    const float* __restrict__ aparam, int amode,
    const float* __restrict__ strat,
    float* __restrict__ comb, int Tq, int Tk, int nh, float inv_scale)
{
    __shared__ __align__(16) unsigned short Kh[128][72], Kl[128][72];
    __shared__ float msh[16 * 64], lsh[16 * 64];
    const int tid = threadIdx.x;
    const int r0 = blockIdx.x * 64, c0 = blockIdx.y * 128;
    const int lane = tid & 63, wave = tid >> 6;
    const int c = lane & 15, quad = lane >> 4;
    const int mbase = wave * 16;

    for (int idx = tid; idx < nh * 64; idx += 256) {
        int hh = idx >> 6, rr = idx & 63;
        msh[idx] = mrow[hh * Tq + r0 + rr];
        lsh[idx] = 1.0f / lrow[hh * Tq + r0 + rr];
    }

    f32x4 acc[8];
#pragma unroll
    for (int nt = 0; nt < 8; ++nt) acc[nt] = (f32x4){0.f, 0.f, 0.f, 0.f};

    int hlist[16]; float glist[16]; int nact = 0; float unif = 0.0f;
    for (int h = 0; h < nh; ++h) {
        float gate = 1.0f;
        if (amode == 1) gate = (aparam[h] > 0.0f) ? 1.0f : 0.0f;
        if (amode == 2) gate = 1.0f / (1.0f + __expf(-aparam[h * 4]));
        if (amode == 1 && gate == 0.0f) { unif += 1.0f; continue; }
        hlist[nact] = h; glist[nact] = gate * inv_scale; ++nact;
    }

    u16x8 krh[4], krl[4];
    auto loadK = [&](int h) {
#pragma unroll
        for (int it = 0; it < 4; ++it) {
            int idx = tid + it * 256;
            int r = idx >> 3, c8 = (idx & 7) * 8;
            size_t go = (size_t)(c0 + r) * D_MODEL + h * 64 + c8;
            krh[it] = *(const u16x8*)&Khi[go];
            krl[it] = *(const u16x8*)&Klo[go];
        }
    };
    if (nact > 0) loadK(hlist[0]);

    for (int i = 0; i < nact; ++i) {
        const int h = hlist[i];
        const float ascale = glist[i];
        __syncthreads();   // previous head's K fully consumed (+msh/lsh visible)
#pragma unroll
        for (int it = 0; it < 4; ++it) {
            int idx = tid + it * 256;
            int r = idx >> 3, c8 = (idx & 7) * 8;
            *(u16x8*)&Kh[r][c8] = krh[it];
            *(u16x8*)&Kl[r][c8] = krl[it];
        }
        __syncthreads();
        if (i + 1 < nact) loadK(hlist[i + 1]);   // prefetch next head

        // Q fragments: pure vector loads from pre-split
        bf16x8 qah[2], qal[2];
        const unsigned short* qh = &Qhi[(size_t)(r0 + mbase + c) * D_MODEL + h * 64];
        const unsigned short* ql = &Qlo[(size_t)(r0 + mbase + c) * D_MODEL + h * 64];
#pragma unroll
        for (int ks = 0; ks < 2; ++ks) {
            qah[ks] = *(const bf16x8*)(qh + ks * 32 + quad * 8);
            qal[ks] = *(const bf16x8*)(ql + ks * 32 + quad * 8);
        }

        float mr[4], li[4];
#pragma unroll
        for (int reg = 0; reg < 4; ++reg) {
            mr[reg] = msh[h * 64 + mbase + quad * 4 + reg];
            li[reg] = lsh[h * 64 + mbase + quad * 4 + reg];
        }
#pragma unroll
        for (int nt = 0; nt < 8; ++nt) {
            f32x4 s = (f32x4){0.f, 0.f, 0.f, 0.f};
#pragma unroll
            for (int ks = 0; ks < 2; ++ks) {
                bf16x8 bh = *(const bf16x8*)&Kh[nt * 16 + c][ks * 32 + quad * 8];
                bf16x8 bl = *(const bf16x8*)&Kl[nt * 16 + c][ks * 32 + quad * 8];
                s = mfma3(qah[ks], qal[ks], bh, bl, s);
            }
#pragma unroll
            for (int reg = 0; reg < 4; ++reg)
                acc[nt][reg] += __expf(s[reg] * ascale - mr[reg]) * li[reg];
        }
    }
    const float csc = (strat[0] + strat[1] + strat[3]) / (float)nh;
    const float uadd = unif / (float)Tk;
#pragma unroll
    for (int nt = 0; nt < 8; ++nt) {
#pragma unroll
        for (int reg = 0; reg < 4; ++reg) {
            int row = r0 + mbase + quad * 4 + reg;
            comb[(size_t)row * Tk + c0 + nt * 16 + c] = csc * (acc[nt][reg] + uadd);
        }
    }
}

// ---------------------------------------------------------------------------
// Per-head 64x64 rotation, z-batched over two inputs:
// Y[t][h*64+e] = sum_d X[t][h*64+d]*R[h][d][e]
// ---------------------------------------------------------------------------
__global__ __launch_bounds__(256) void rotate_heads(
    const float* __restrict__ X0, const float* __restrict__ X1,
    const float* __restrict__ R,
    float* __restrict__ Y0, float* __restrict__ Y1)
{
    const float* X = blockIdx.z ? X1 : X0;
    float* Y = blockIdx.z ? Y1 : Y0;
    __shared__ float Rt[64][68];
    __shared__ float xs[64][68];
    const int tid = threadIdx.x;
    const int h = blockIdx.y;
    const int t0 = blockIdx.x * 64;
    for (int idx = tid; idx < 4096; idx += 256) {
        int d = idx >> 6, e = idx & 63;
        Rt[e][d] = R[h * 4096 + idx];
        xs[d][e] = X[(size_t)(t0 + d) * D_MODEL + h * 64 + e];
    }
    __syncthreads();
    const int ty = tid >> 4, tx = tid & 15;
    float acc[4][4] = {};
#pragma unroll 4
    for (int d0 = 0; d0 < 64; d0 += 4) {
        float4 rv[4];
#pragma unroll
        for (int j = 0; j < 4; ++j) rv[j] = *(const float4*)&Rt[tx * 4 + j][d0];
#pragma unroll
        for (int i = 0; i < 4; ++i) {
            float4 a = *(const float4*)&xs[ty * 4 + i][d0];
#pragma unroll
            for (int j = 0; j < 4; ++j)
                acc[i][j] += a.x * rv[j].x + a.y * rv[j].y + a.z * rv[j].z + a.w * rv[j].w;
        }
    }
#pragma unroll
    for (int i = 0; i < 4; ++i)
#pragma unroll
        for (int j = 0; j < 4; ++j)
            Y[(size_t)(t0 + ty * 4 + i) * D_MODEL + h * 64 + tx * 4 + j] = acc[i][j];
}

// ---------------------------------------------------------------------------
// F.interpolate(mode='linear', align_corners=False): [256,1024] -> [2048,1024]
// ---------------------------------------------------------------------------
__global__ __launch_bounds__(256) void interp_lin(
    const float* __restrict__ G, float* __restrict__ out)
{
    const int t = blockIdx.x;
    float src = (t + 0.5f) * 0.125f - 0.5f;
    src = fminf(fmaxf(src, 0.0f), 255.0f);
    float fl = floorf(src);
    int i0 = (int)fl;
    int i1 = min(i0 + 1, 255);
    float w = src - fl;
    const float4* g0 = (const float4*)(G + (size_t)i0 * D_MODEL);
    const float4* g1 = (const float4*)(G + (size_t)i1 * D_MODEL);
    float4* o = (float4*)(out + (size_t)t * D_MODEL);
    int c = threadIdx.x;
    float4 a = g0[c], b = g1[c];
    float4 r;
    r.x = a.x * (1.0f - w) + b.x * w;
    r.y = a.y * (1.0f - w) + b.y * w;
    r.z = a.z * (1.0f - w) + b.z * w;
    r.w = a.w * (1.0f - w) + b.w * w;
    o[c] = r;
}

// ---------------------------------------------------------------------------
extern "C" void kernel_launch(void* const* d_in, const int* in_sizes, int n_in,
                              void* d_out, int out_size, void* d_ws, size_t ws_size,
                              hipStream_t stream)
{
    (void)in_sizes; (void)n_in; (void)ws_size; (void)out_size;
    const float* query    = (const float*)d_in[0];
    const float* key      = (const float*)d_in[1];
    const float* value    = (const float*)d_in[2];
    const float* strat    = (const float*)d_in[3];
    const float* Wqkv_lin = (const float*)d_in[4];
    const float* b_lin    = (const float*)d_in[5];
    const float* Wo_lin   = (const float*)d_in[6];
    const float* bo_lin   = (const float*)d_in[7];
    const float* spars    = (const float*)d_in[8];
    const float* Wqkv_loc = (const float*)d_in[9];
    const float* b_loc    = (const float*)d_in[10];
    const float* Wo_loc   = (const float*)d_in[11];
    const float* bo_loc   = (const float*)d_in[12];
    const float* Wqkv_glb = (const float*)d_in[13];
    const float* b_glb    = (const float*)d_in[14];
    const float* Wo_glb   = (const float*)d_in[15];
    const float* bo_glb   = (const float*)d_in[16];
    const float* Wf       = (const float*)d_in[17];
    const float* bf       = (const float*)d_in[18];
    const float* Rq       = (const float*)d_in[19];
    const float* ent      = (const float*)d_in[20];

    float* out = (float*)d_out;
    float* weighted = out;                        // [2048][1024]
    float* combined = out + (size_t)2048 * 1024;  // [3][2048][2048]
    const size_t PLANE = (size_t)2048 * 2048;

    float* ws   = (float*)d_ws;
    float* qkv  = ws;                   // 3 x 2048x1024
    float* AO   = qkv + 6291456;
    float* LO   = AO + 2097152;
    float* gqkv = LO + 2097152;
    float* gAO  = gqkv + 786432;
    float* gOUT = gAO + 262144;
    float* GI   = gOUT + 262144;
    float* mb   = GI + 2097152;         // [32][2048] partial m
    float* lb   = mb + 65536;           // [32][2048] partial l
    float* qrot = qkv;                  // alias: lin qkv dead by then
    float* krot = qkv + 2097152;
    // pre-split bf16 hi/lo buffers (u16)
    unsigned short* Ksp_h = (unsigned short*)(lb + 65536);  // [2048][1024]
    unsigned short* Ksp_l = Ksp_h + 2097152;
    unsigned short* Vtp_h = Ksp_l + 2097152;                // [1024][2048]
    unsigned short* Vtp_l = Vtp_h + 2097152;
    unsigned short* gKs_h = Vtp_l + 2097152;                // [256][1024]
    unsigned short* gKs_l = gKs_h + 262144;
    unsigned short* gVt_h = gKs_l + 262144;                 // [1024][256]
    unsigned short* gVt_l = gVt_h + 262144;
    float* mc = (float*)(gVt_l + 262144);                   // [16][2048] merged m
    float* lc = mc + 32768;                                 // [16][2048] merged l
    // pre-split inputs (persist whole launch)
    unsigned short* Iq_h = (unsigned short*)(lc + 32768);   // [2048][1024]
    unsigned short* Iq_l = Iq_h + 2097152;
    unsigned short* Ik_h = Iq_l + 2097152;
    unsigned short* Ik_l = Ik_h + 2097152;
    unsigned short* Iv_h = Ik_l + 2097152;
    unsigned short* Iv_l = Iv_h + 2097152;
    // weight split scratch (serially reused; max 3M elements)
    unsigned short* Wsp_h = Iv_l + 2097152;
    unsigned short* Wsp_l = Wsp_h + 3145728;
    // activation split scratch ALIASED into qkv (qkv is dead at every Asp
    // use site: LINEAR/LOCAL after flash+comb consumed projections; GLOBAL/
    // HIER qkv unused) — saves 8.4 MB of workspace
    unsigned short* Asp_h = (unsigned short*)qkv;
    unsigned short* Asp_l = Asp_h + 2097152;
    // Q pre-split for comb lives in GI (time-shared with flash partial O1)
    unsigned short* Qsp_h = (unsigned short*)GI;            // [2048][1024]
    unsigned short* Qsp_l = Qsp_h + 2097152;

    const float inv8   = 0.125f;
    const float inv128 = 1.0f / sqrtf(128.0f);

    hipMemsetAsync(weighted, 0, (size_t)2097152 * sizeof(float), stream);

    // one-time input splits (reused by QKV gemms x3, SPARSE flash/comb, GLOBAL)
    split_rm<<<dim3(2048), 256, 0, stream>>>(query, Iq_h, Iq_l, 524288);
    split_rm<<<dim3(2048), 256, 0, stream>>>(key,   Ik_h, Ik_l, 524288);
    split_rm<<<dim3(2048), 256, 0, stream>>>(value, Iv_h, Iv_l, 524288);

    // ---- LINEAR (proj'd MHA, 16 heads; combined plane 0) ----
    split_rm<<<dim3(3072), 256, 0, stream>>>(Wqkv_lin, Wsp_h, Wsp_l, 786432);
    gemm_bf<<<dim3(32, 16, 3), 256, 0, stream>>>(
        Iq_h, Iq_l, Ik_h, Ik_l, Iv_h, Iv_l, 1024,
        Wsp_h, Wsp_l, 1048576, 1024, b_lin, 1024,
        qkv, 2097152, 2048, 1024, 1024, nullptr, 0, 0);
    split_rm<<<dim3(2048), 256, 0, stream>>>(qkv + 2097152, Ksp_h, Ksp_l, 524288);
    split_tr<<<dim3(32, 16), 256, 0, stream>>>(qkv + 4194304, Vtp_h, Vtp_l, 2048);
    flash_mfma<64><<<dim3(32, 16, 2), 256, 0, stream>>>(
        qkv, Ksp_h, Ksp_l, Vtp_h, Vtp_l, nullptr, 0,
        AO, GI, strat, -1, 0, mb, lb, 2048, 2048, inv8);
    combineK<<<dim3(2048), 256, 0, stream>>>(
        AO, GI, mb, lb, AO, mc, lc, strat, -1, 0, 2048, 6, 16);
    split_rm<<<dim3(2048), 256, 0, stream>>>(qkv, Qsp_h, Qsp_l, 524288);
    comb_mfma<<<dim3(32, 16), 256, 0, stream>>>(
        Qsp_h, Qsp_l, Ksp_h, Ksp_l, mc, lc, nullptr, 0, strat,
        combined + 0 * PLANE, 2048, 2048, 16, inv8);
    split_rm<<<dim3(2048), 256, 0, stream>>>(AO, Asp_h, Asp_l, 524288);
    split_rm<<<dim3(1024), 256, 0, stream>>>(Wo_lin, Wsp_h, Wsp_l, 262144);
    gemm_bf<<<dim3(32, 16, 1), 256, 0, stream>>>(
        Asp_h, Asp_l, Asp_h, Asp_l, Asp_h, Asp_l, 1024,
        Wsp_h, Wsp_l, 0, 1024, bo_lin, 0,
        weighted, 0, 2048, 1024, 1024, strat, 0, 1);

    // ---- SPARSE (raw heads, per-head mask; combined plane 1) ----
    // K = Ik (pre-split key), Q for comb = Iq. Only V needs a transposed split.
    split_tr<<<dim3(32, 16), 256, 0, stream>>>(value, Vtp_h, Vtp_l, 2048);
    flash_mfma<64><<<dim3(32, 16, 2), 256, 0, stream>>>(
        query, Ik_h, Ik_l, Vtp_h, Vtp_l, spars, 1,
        AO, GI, strat, 1, 1, mb, lb, 2048, 2048, inv8);
    combineK<<<dim3(2048), 256, 0, stream>>>(
        AO, GI, mb, lb, weighted, mc, lc, strat, 1, 1, 2048, 6, 16);
    comb_mfma<<<dim3(32, 16), 256, 0, stream>>>(
        Iq_h, Iq_l, Ik_h, Ik_l, mc, lc, spars, 1, strat,
        combined + 1 * PLANE, 2048, 2048, 16, inv8);

    // ---- QUANTUM (rotated raw heads, per-head gate; combined plane 2) ----
    // Vtp still holds split raw value (shared with SPARSE).
    rotate_heads<<<dim3(32, 16, 2), 256, 0, stream>>>(query, key, Rq, qrot, krot);
    split_rm<<<dim3(2048), 256, 0, stream>>>(krot, Ksp_h, Ksp_l, 524288);
    flash_mfma<64><<<dim3(32, 16, 2), 256, 0, stream>>>(
        qrot, Ksp_h, Ksp_l, Vtp_h, Vtp_l, ent, 2,
        AO, GI, strat, 3, 1, mb, lb, 2048, 2048, inv8);
    combineK<<<dim3(2048), 256, 0, stream>>>(
        AO, GI, mb, lb, weighted, mc, lc, strat, 3, 1, 2048, 6, 16);
    split_rm<<<dim3(2048), 256, 0, stream>>>(qrot, Qsp_h, Qsp_l, 524288);
    comb_mfma<<<dim3(32, 16), 256, 0, stream>>>(
        Qsp_h, Qsp_l, Ksp_h, Ksp_l, mc, lc, ent, 2, strat,
        combined + 2 * PLANE, 2048, 2048, 16, inv8);

    // ---- LOCAL (proj'd MHA, 8 heads x 128), split-K x2 over keys ----
    split_rm<<<dim3(3072), 256, 0, stream>>>(Wqkv_loc, Wsp_h, Wsp_l, 786432);
    gemm_bf<<<dim3(32, 16, 3), 256, 0, stream>>>(
        Iq_h, Iq_l, Ik_h, Ik_l, Iv_h, Iv_l, 1024,
        Wsp_h, Wsp_l, 1048576, 1024, b_loc, 1024,
        qkv, 2097152, 2048, 1024, 1024, nullptr, 0, 0);
    split_rm<<<dim3(2048), 256, 0, stream>>>(qkv + 2097152, Ksp_h, Ksp_l, 524288);
    split_tr<<<dim3(32, 16), 256, 0, stream>>>(qkv + 4194304, Vtp_h, Vtp_l, 2048);
    flash_mfma<128><<<dim3(32, 8, 2), 256, 0, stream>>>(
        qkv, Ksp_h, Ksp_l, Vtp_h, Vtp_l, nullptr, 0,
        AO, GI, strat, -1, 0, mb, lb, 2048, 2048, inv128);
    combineK<<<dim3(2048), 256, 0, stream>>>(
        AO, GI, mb, lb, AO, nullptr, nullptr, strat, -1, 0, 2048, 7, 8);
    split_rm<<<dim3(2048), 256, 0, stream>>>(AO, Asp_h, Asp_l, 524288);
    split_rm<<<dim3(1024), 256, 0, stream>>>(Wo_loc, Wsp_h, Wsp_l, 262144);
    gemm_bf<<<dim3(32, 16, 1), 256, 0, stream>>>(
        Asp_h, Asp_l, Asp_h, Asp_l, Asp_h, Asp_l, 1024,
        Wsp_h, Wsp_l, 0, 1024, bo_loc, 0,
        LO, 0, 2048, 1024, 1024, nullptr, 0, 0);

    // ---- GLOBAL (strided pool to 256 tokens, 8 heads x 128, interp back) ----
    // pooled X rows = Iq/Ik/Iv rows at stride 8 -> element stride 8192
    split_rm<<<dim3(3072), 256, 0, stream>>>(Wqkv_glb, Wsp_h, Wsp_l, 786432);
    gemm_bf<<<dim3(4, 16, 3), 256, 0, stream>>>(
        Iq_h, Iq_l, Ik_h, Ik_l, Iv_h, Iv_l, 8192,
        Wsp_h, Wsp_l, 1048576, 1024, b_glb, 1024,
        gqkv, 262144, 256, 1024, 1024, nullptr, 0, 0);
    split_rm<<<dim3(256), 256, 0, stream>>>(gqkv + 262144, gKs_h, gKs_l, 65536);
    split_tr<<<dim3(4, 16), 256, 0, stream>>>(gqkv + 524288, gVt_h, gVt_l, 256);
    flash_mfma<128><<<dim3(4, 8, 1), 256, 0, stream>>>(
        gqkv, gKs_h, gKs_l, gVt_h, gVt_l, nullptr, 0,
        gAO, nullptr, strat, -1, 0, mb, lb, 256, 256, inv128);
    split_rm<<<dim3(256), 256, 0, stream>>>(gAO, Asp_h, Asp_l, 65536);
    split_rm<<<dim3(1024), 256, 0, stream>>>(Wo_glb, Wsp_h, Wsp_l, 262144);
    gemm_bf<<<dim3(4, 16, 1), 256, 0, stream>>>(
        Asp_h, Asp_l, Asp_h, Asp_l, Asp_h, Asp_l, 1024,
        Wsp_h, Wsp_l, 0, 1024, bo_glb, 0,
        gOUT, 0, 256, 1024, 1024, nullptr, 0, 0);
    interp_lin<<<dim3(2048), 256, 0, stream>>>(gOUT, GI);

    // ---- HIER: weighted += s2 * (LO @ WfL^T + GI @ WfR^T + bf) ----
    split_rm<<<dim3(2048), 256, 0, stream>>>(Wf, Wsp_h, Wsp_l, 524288);  // [1024][2048]
    split_rm<<<dim3(2048), 256, 0, stream>>>(LO, Asp_h, Asp_l, 524288);
    gemm_bf<<<dim3(32, 16, 1), 256, 0, stream>>>(
        Asp_h, Asp_l, Asp_h, Asp_l, Asp_h, Asp_l, 1024,
        Wsp_h, Wsp_l, 0, 2048, bf, 0,
        weighted, 0, 2048, 1024, 1024, strat, 2, 1);
    split_rm<<<dim3(2048), 256, 0, stream>>>(GI, Asp_h, Asp_l, 524288);
    gemm_bf<<<dim3(32, 16, 1), 256, 0, stream>>>(
        Asp_h, Asp_l, Asp_h, Asp_l, Asp_h, Asp_l, 1024,
        Wsp_h + 1024, Wsp_l + 1024, 0, 2048, nullptr, 0,
        weighted, 0, 2048, 1024, 1024, strat, 2, 1);
}